// Round 1
// baseline (1999.055 us; speedup 1.0000x reference)
//
#include <hip/hip_runtime.h>
#include <hip/hip_bf16.h>
#include <math.h>

#define NN 50000
#define NE 1000000
#define NIMAG 200000
#define NBLOCK 5000
#define HID 128

// ---------------- zero fill ----------------
__global__ void zero_k(int* __restrict__ p, int n) {
    int i = blockIdx.x * 256 + threadIdx.x;
    if (i < n) p[i] = 0;
}

// ---------------- CSR build ----------------
__global__ void count_k(const int* __restrict__ ei, int* __restrict__ counts) {
    int e = blockIdx.x * 256 + threadIdx.x;
    if (e < NE) atomicAdd(&counts[ei[NE + e]], 1);
}

__global__ void scan_k(const int* __restrict__ counts, int* __restrict__ offs) {
    __shared__ int ssum[256];
    int t = threadIdx.x;
    const int chunk = (NN + 255) / 256;
    int beg = t * chunk, end = min(beg + chunk, NN);
    int s = 0;
    for (int i = beg; i < end; ++i) s += counts[i];
    ssum[t] = s;
    __syncthreads();
    for (int off = 1; off < 256; off <<= 1) {
        int v = (t >= off) ? ssum[t - off] : 0;
        __syncthreads();
        if (t >= off) ssum[t] += v;
        __syncthreads();
    }
    int run = ssum[t] - s;  // exclusive prefix
    for (int i = beg; i < end; ++i) { offs[i] = run; run += counts[i]; }
    if (t == 255) offs[NN] = run;
}

__global__ void scatter_k(const int* __restrict__ ei, const int* __restrict__ offs,
                          int* __restrict__ cursor, int* __restrict__ csr_src,
                          int* __restrict__ csr_eid) {
    int e = blockIdx.x * 256 + threadIdx.x;
    if (e < NE) {
        int d = ei[NE + e];
        int pos = offs[d] + atomicAdd(&cursor[d], 1);
        csr_src[pos] = ei[e];
        csr_eid[pos] = e;
    }
}

// ---------------- GEMM: C[M,N] = act(A[M,K] @ W[K,N] + bias) ----------------
// A[row][k] = k < K0 ? P0[(idx0?idx0[row]:row)*ld0 + k]
//                    : P1[(idx1?idx1[row]:row)*ld1 + (k-K0)]
template <int N, bool RELU>
__global__ __launch_bounds__(256) void gemm_k(
    const float* __restrict__ P0, int ld0, int K0,
    const float* __restrict__ P1, int ld1,
    const int* __restrict__ idx0, const int* __restrict__ idx1,
    int K,
    const float* __restrict__ W, const float* __restrict__ bias,
    float* __restrict__ C, int M)
{
    constexpr int BM = 64, BK = 64;
    constexpr int CPT = N / 16;  // cols per thread (8 for N=128, 4 for N=64)
    __shared__ float As[BM][BK + 4];
    __shared__ float Ws[BK][N];
    const int t = threadIdx.x;
    const int tx = t & 15, ty = t >> 4;
    const int row0 = blockIdx.x * BM;

    float acc[4][CPT];
#pragma unroll
    for (int i = 0; i < 4; ++i)
#pragma unroll
        for (int c = 0; c < CPT; ++c) acc[i][c] = 0.f;

    for (int kb = 0; kb < K; kb += BK) {
        const float* base; int ld, koff; const int* idx;
        if (kb < K0) { base = P0; ld = ld0; koff = kb; idx = idx0; }
        else         { base = P1; ld = ld1; koff = kb - K0; idx = idx1; }
        // stage A tile (64 rows x 64 k), coalesced: 16 lanes cover one row chunk
#pragma unroll
        for (int j = 0; j < 4; ++j) {
            int f4 = j * 256 + t;
            int lr = f4 >> 4;      // local row 0..63
            int q  = f4 & 15;      // float4 index in row chunk
            int gr = row0 + lr; if (gr >= M) gr = M - 1;
            int srow = idx ? idx[gr] : gr;
            float4 v = *(const float4*)(base + (size_t)srow * ld + koff + q * 4);
            *(float4*)&As[lr][q * 4] = v;
        }
        // stage W tile (64 k x N)
#pragma unroll
        for (int j = 0; j < BK * (N / 4) / 256; ++j) {
            int f4 = j * 256 + t;
            int kr = f4 / (N / 4);
            int c4 = f4 % (N / 4);
            *(float4*)&Ws[kr][c4 * 4] = *(const float4*)(W + (size_t)(kb + kr) * N + c4 * 4);
        }
        __syncthreads();
#pragma unroll
        for (int k4 = 0; k4 < BK / 4; ++k4) {
            float4 a[4];
#pragma unroll
            for (int i = 0; i < 4; ++i) a[i] = *(float4*)&As[ty * 4 + i][k4 * 4];
#pragma unroll
            for (int kk = 0; kk < 4; ++kk) {
                float wv[CPT];
#pragma unroll
                for (int c4 = 0; c4 < CPT / 4; ++c4)
                    *(float4*)&wv[c4 * 4] = *(float4*)&Ws[k4 * 4 + kk][tx * CPT + c4 * 4];
#pragma unroll
                for (int i = 0; i < 4; ++i) {
                    float av = ((float*)&a[i])[kk];
#pragma unroll
                    for (int c = 0; c < CPT; ++c) acc[i][c] = fmaf(av, wv[c], acc[i][c]);
                }
            }
        }
        __syncthreads();
    }
#pragma unroll
    for (int i = 0; i < 4; ++i) {
        int gr = row0 + ty * 4 + i;
        if (gr < M) {
#pragma unroll
            for (int c4 = 0; c4 < CPT / 4; ++c4) {
                float4 o;
                float* op = (float*)&o;
#pragma unroll
                for (int u = 0; u < 4; ++u) {
                    int col = tx * CPT + c4 * 4 + u;
                    float v = acc[i][c4 * 4 + u] + bias[col];
                    if (RELU) v = v > 0.f ? v : 0.f;
                    op[u] = v;
                }
                *(float4*)(C + (size_t)gr * N + tx * CPT + c4 * 4) = o;
            }
        }
    }
}

// ---------------- attention logits: e = att . leaky_relu(xl[src]+xr[dst]) ----------------
__global__ __launch_bounds__(256) void edge_e_k(
    const float* __restrict__ xl, const float* __restrict__ xr,
    const int* __restrict__ ei, const float* __restrict__ att,
    float* __restrict__ e, float* __restrict__ eself)
{
    int wid = (blockIdx.x * 256 + threadIdx.x) >> 6;
    int lane = threadIdx.x & 63;
    if (wid >= NE + NN) return;
    int s, d;
    if (wid < NE) { s = ei[wid]; d = ei[NE + wid]; }
    else          { s = wid - NE; d = s; }
    float2 a = *(const float2*)(xl + (size_t)s * HID + lane * 2);
    float2 b = *(const float2*)(xr + (size_t)d * HID + lane * 2);
    float2 w = *(const float2*)(att + lane * 2);
    float mx = a.x + b.x; mx = mx > 0.f ? mx : 0.2f * mx;
    float my = a.y + b.y; my = my > 0.f ? my : 0.2f * my;
    float v = fmaf(mx, w.x, my * w.y);
#pragma unroll
    for (int off = 32; off > 0; off >>= 1) v += __shfl_down(v, off, 64);
    if (lane == 0) {
        if (wid < NE) e[wid] = v;
        else          eself[wid - NE] = v;
    }
}

// ---------------- segment softmax + weighted aggregation (block per node) ----------------
__global__ __launch_bounds__(128) void agg_k(
    const float* __restrict__ xl, const float* __restrict__ e,
    const float* __restrict__ eself, const int* __restrict__ offs,
    const int* __restrict__ csr_src, const int* __restrict__ csr_eid,
    const float* __restrict__ bias, float* __restrict__ hout)
{
    int n = blockIdx.x;
    int t = threadIdx.x;
    int beg = offs[n], deg = offs[n + 1] - beg;
    __shared__ float red[2];
    __shared__ float wsh[128];
    __shared__ int   ssh[128];
    float es = eself[n];
    // pass 1: segment max (self loop included)
    float m = es;
    for (int j = t; j < deg; j += 128) m = fmaxf(m, e[csr_eid[beg + j]]);
#pragma unroll
    for (int off = 32; off > 0; off >>= 1) m = fmaxf(m, __shfl_down(m, off, 64));
    if ((t & 63) == 0) red[t >> 6] = m;
    __syncthreads();
    m = fmaxf(red[0], red[1]);
    __syncthreads();
    // pass 2: denom
    float s = 0.f;
    for (int j = t; j < deg; j += 128) s += expf(e[csr_eid[beg + j]] - m);
#pragma unroll
    for (int off = 32; off > 0; off >>= 1) s += __shfl_down(s, off, 64);
    if ((t & 63) == 0) red[t >> 6] = s;
    __syncthreads();
    float wself = expf(es - m);
    float inv = 1.f / (red[0] + red[1] + wself);
    // pass 3: weighted sum, tiled over incident edges
    float accv = wself * inv * xl[(size_t)n * HID + t];
    for (int base = 0; base < deg; base += 128) {
        int cnt = min(128, deg - base);
        __syncthreads();
        if (t < cnt) {
            int id = beg + base + t;
            wsh[t] = expf(e[csr_eid[id]] - m) * inv;
            ssh[t] = csr_src[id];
        }
        __syncthreads();
        for (int j = 0; j < cnt; ++j)
            accv = fmaf(wsh[j], xl[(size_t)ssh[j] * HID + t], accv);
    }
    hout[(size_t)n * HID + t] = accv + bias[t];
}

// ---------------- edge decoder final: sigmoid(row . W2 + b2) ----------------
__global__ __launch_bounds__(256) void edec_out_k(
    const float* __restrict__ Ebuf, const float* __restrict__ W2,
    const float* __restrict__ b2, float* __restrict__ out, int Mc)
{
    int wid = (blockIdx.x * 256 + threadIdx.x) >> 6;
    int lane = threadIdx.x & 63;
    if (wid >= Mc) return;
    float2 v = *(const float2*)(Ebuf + (size_t)wid * HID + lane * 2);
    float2 w = *(const float2*)(W2 + lane * 2);
    float d = fmaf(v.x, w.x, v.y * w.y);
#pragma unroll
    for (int off = 32; off > 0; off >>= 1) d += __shfl_down(d, off, 64);
    if (lane == 0) out[wid] = 1.f / (1.f + expf(-(d + b2[0])));
}

extern "C" void kernel_launch(void* const* d_in, const int* in_sizes, int n_in,
                              void* d_out, int out_size, void* d_ws, size_t ws_size,
                              hipStream_t stream)
{
    const float* x    = (const float*)d_in[0];
    const float* emb  = (const float*)d_in[1];
    const int*   ei   = (const int*)d_in[2];
    const int*   bidx = (const int*)d_in[3];
    const int*   eim  = (const int*)d_in[4];
    const float* encW = (const float*)d_in[5];
    const float* encB = (const float*)d_in[6];
    const float* gWl  = (const float*)d_in[7];
    const float* gbl  = (const float*)d_in[8];
    const float* gWr  = (const float*)d_in[9];
    const float* gbr  = (const float*)d_in[10];
    const float* gatt = (const float*)d_in[11];
    const float* gb   = (const float*)d_in[12];
    const float* eW0  = (const float*)d_in[13];
    const float* eb0  = (const float*)d_in[14];
    const float* eW1  = (const float*)d_in[15];
    const float* eb1  = (const float*)d_in[16];
    const float* eW2  = (const float*)d_in[17];
    const float* eb2  = (const float*)d_in[18];
    const float* nW0  = (const float*)d_in[19];
    const float* nb0  = (const float*)d_in[20];
    const float* nW1  = (const float*)d_in[21];
    const float* nb1  = (const float*)d_in[22];
    const float* nW2  = (const float*)d_in[23];
    const float* nb2  = (const float*)d_in[24];
    float* out = (float*)d_out;

    char* wptr = (char*)d_ws;
    auto alloc = [&](size_t bytes) {
        char* p = wptr;
        wptr += (bytes + 255) & ~(size_t)255;
        return p;
    };
    float* h     = (float*)alloc((size_t)NN * HID * 4);
    float* xl    = (float*)alloc((size_t)NN * HID * 4);
    float* xr    = (float*)alloc((size_t)NN * HID * 4);
    float* e     = (float*)alloc((size_t)NE * 4);
    float* eself = (float*)alloc((size_t)NN * 4);
    int* counts  = (int*)alloc((size_t)NN * 4);
    int* offs    = (int*)alloc((size_t)(NN + 1) * 4);
    int* csrs    = (int*)alloc((size_t)NE * 4);
    int* csre    = (int*)alloc((size_t)NE * 4);
    // aliases (used only after the GAT layers are done with xl/xr)
    float* Ebuf = xl;                    // 50000*128 per edge-decoder chunk
    float* nb0t = xr;                    // 5000*128
    float* nb1t = xr + (size_t)NBLOCK * HID;

    // ---- CSR build (graph is static across the 3 layers) ----
    zero_k<<<(NN + 255) / 256, 256, 0, stream>>>(counts, NN);
    count_k<<<(NE + 255) / 256, 256, 0, stream>>>(ei, counts);
    scan_k<<<1, 256, 0, stream>>>(counts, offs);
    zero_k<<<(NN + 255) / 256, 256, 0, stream>>>(counts, NN);
    scatter_k<<<(NE + 255) / 256, 256, 0, stream>>>(ei, offs, counts, csrs, csre);

    const int gN = (NN + 63) / 64;
    // ---- encoder MLP: concat(x, emb) -> relu -> relu -> linear ----
    gemm_k<128, true ><<<gN, 256, 0, stream>>>(x, 64, 64, emb, 64, nullptr, nullptr, 128,
                                               encW, encB, xl, NN);
    gemm_k<128, true ><<<gN, 256, 0, stream>>>(xl, 128, 128, nullptr, 0, nullptr, nullptr, 128,
                                               encW + 128 * 128, encB + 128, xr, NN);
    gemm_k<128, false><<<gN, 256, 0, stream>>>(xr, 128, 128, nullptr, 0, nullptr, nullptr, 128,
                                               encW + 2 * 128 * 128, encB + 256, h, NN);

    // ---- 3 GATv2 layers ----
    const int gE = (NE + NN + 3) / 4;  // 4 waves / 256-thread block
    for (int l = 0; l < 3; ++l) {
        const float* Wl  = gWl + (size_t)l * HID * HID;
        const float* bl  = gbl + (size_t)l * HID;
        const float* Wr  = gWr + (size_t)l * HID * HID;
        const float* br  = gbr + (size_t)l * HID;
        const float* att = gatt + (size_t)l * HID;
        const float* bb  = gb + (size_t)l * HID;
        gemm_k<128, false><<<gN, 256, 0, stream>>>(h, 128, 128, nullptr, 0, nullptr, nullptr, 128,
                                                   Wl, bl, xl, NN);
        gemm_k<128, false><<<gN, 256, 0, stream>>>(h, 128, 128, nullptr, 0, nullptr, nullptr, 128,
                                                   Wr, br, xr, NN);
        edge_e_k<<<gE, 256, 0, stream>>>(xl, xr, ei, att, e, eself);
        agg_k<<<NN, 128, 0, stream>>>(xl, e, eself, offs, csrs, csre, bb, h);
    }

    // ---- edge decoder on imaginary edges, 4 chunks of 50000 rows ----
    for (int c = 0; c < 4; ++c) {
        const int Mc = 50000;
        const int* i0 = eim + (size_t)c * Mc;
        const int* i1 = eim + NIMAG + (size_t)c * Mc;
        gemm_k<128, true ><<<(Mc + 63) / 64, 256, 0, stream>>>(h, 128, 128, h, 128, i0, i1, 256,
                                                               eW0, eb0, Ebuf, Mc);
        gemm_k<128, true ><<<(Mc + 63) / 64, 256, 0, stream>>>(Ebuf, 128, 128, nullptr, 0,
                                                               nullptr, nullptr, 128,
                                                               eW1, eb1, Ebuf, Mc);
        edec_out_k<<<(Mc + 3) / 4, 256, 0, stream>>>(Ebuf, eW2, eb2,
                                                     out + (size_t)NBLOCK * 64 + (size_t)c * Mc, Mc);
    }

    // ---- node decoder ----
    const int gB = (NBLOCK + 63) / 64;
    gemm_k<128, true ><<<gB, 256, 0, stream>>>(h, 128, 128, nullptr, 0, bidx, nullptr, 128,
                                               nW0, nb0, nb0t, NBLOCK);
    gemm_k<128, true ><<<gB, 256, 0, stream>>>(nb0t, 128, 128, nullptr, 0, nullptr, nullptr, 128,
                                               nW1, nb1, nb1t, NBLOCK);
    gemm_k<64, false><<<gB, 256, 0, stream>>>(nb1t, 128, 128, nullptr, 0, nullptr, nullptr, 128,
                                              nW2, nb2, out, NBLOCK);
}

// Round 2
// 1627.566 us; speedup vs baseline: 1.2282x; 1.2282x over previous
//
#include <hip/hip_runtime.h>
#include <hip/hip_bf16.h>
#include <math.h>

#define NN 50000
#define NE 1000000
#define NIMAG 200000
#define NBLOCK 5000
#define HID 128

// ---------------- zero fill ----------------
__global__ void zero_k(int* __restrict__ p, int n) {
    int i = blockIdx.x * 256 + threadIdx.x;
    if (i < n) p[i] = 0;
}

// ---------------- CSR build ----------------
__global__ void count_k(const int* __restrict__ ei, int* __restrict__ counts) {
    int e = blockIdx.x * 256 + threadIdx.x;
    if (e < NE) atomicAdd(&counts[ei[NE + e]], 1);
}

__global__ void scan_k(const int* __restrict__ counts, int* __restrict__ offs) {
    __shared__ int ssum[256];
    int t = threadIdx.x;
    const int chunk = (NN + 255) / 256;
    int beg = t * chunk, end = min(beg + chunk, NN);
    int s = 0;
    for (int i = beg; i < end; ++i) s += counts[i];
    ssum[t] = s;
    __syncthreads();
    for (int off = 1; off < 256; off <<= 1) {
        int v = (t >= off) ? ssum[t - off] : 0;
        __syncthreads();
        if (t >= off) ssum[t] += v;
        __syncthreads();
    }
    int run = ssum[t] - s;  // exclusive prefix
    for (int i = beg; i < end; ++i) { offs[i] = run; run += counts[i]; }
    if (t == 255) offs[NN] = run;
}

__global__ void scatter_k(const int* __restrict__ ei, const int* __restrict__ offs,
                          int* __restrict__ cursor, int* __restrict__ csr_src) {
    int e = blockIdx.x * 256 + threadIdx.x;
    if (e < NE) {
        int d = ei[NE + e];
        int pos = offs[d] + atomicAdd(&cursor[d], 1);
        csr_src[pos] = ei[e];
    }
}

// ---------------- GEMM: C[M,N] = act(A[M,K] @ W[K,N] + bias) ----------------
template <int N, bool RELU>
__global__ __launch_bounds__(256) void gemm_k(
    const float* __restrict__ P0, int ld0, int K0,
    const float* __restrict__ P1, int ld1,
    const int* __restrict__ idx0, const int* __restrict__ idx1,
    int K,
    const float* __restrict__ W, const float* __restrict__ bias,
    float* __restrict__ C, int M)
{
    constexpr int BM = 64, BK = 64;
    constexpr int CPT = N / 16;
    __shared__ float As[BM][BK + 4];
    __shared__ float Ws[BK][N];
    const int t = threadIdx.x;
    const int tx = t & 15, ty = t >> 4;
    const int row0 = blockIdx.x * BM;

    float acc[4][CPT];
#pragma unroll
    for (int i = 0; i < 4; ++i)
#pragma unroll
        for (int c = 0; c < CPT; ++c) acc[i][c] = 0.f;

    for (int kb = 0; kb < K; kb += BK) {
        const float* base; int ld, koff; const int* idx;
        if (kb < K0) { base = P0; ld = ld0; koff = kb; idx = idx0; }
        else         { base = P1; ld = ld1; koff = kb - K0; idx = idx1; }
#pragma unroll
        for (int j = 0; j < 4; ++j) {
            int f4 = j * 256 + t;
            int lr = f4 >> 4;
            int q  = f4 & 15;
            int gr = row0 + lr; if (gr >= M) gr = M - 1;
            int srow = idx ? idx[gr] : gr;
            float4 v = *(const float4*)(base + (size_t)srow * ld + koff + q * 4);
            *(float4*)&As[lr][q * 4] = v;
        }
#pragma unroll
        for (int j = 0; j < BK * (N / 4) / 256; ++j) {
            int f4 = j * 256 + t;
            int kr = f4 / (N / 4);
            int c4 = f4 % (N / 4);
            *(float4*)&Ws[kr][c4 * 4] = *(const float4*)(W + (size_t)(kb + kr) * N + c4 * 4);
        }
        __syncthreads();
#pragma unroll
        for (int k4 = 0; k4 < BK / 4; ++k4) {
            float4 a[4];
#pragma unroll
            for (int i = 0; i < 4; ++i) a[i] = *(float4*)&As[ty * 4 + i][k4 * 4];
#pragma unroll
            for (int kk = 0; kk < 4; ++kk) {
                float wv[CPT];
#pragma unroll
                for (int c4 = 0; c4 < CPT / 4; ++c4)
                    *(float4*)&wv[c4 * 4] = *(float4*)&Ws[k4 * 4 + kk][tx * CPT + c4 * 4];
#pragma unroll
                for (int i = 0; i < 4; ++i) {
                    float av = ((float*)&a[i])[kk];
#pragma unroll
                    for (int c = 0; c < CPT; ++c) acc[i][c] = fmaf(av, wv[c], acc[i][c]);
                }
            }
        }
        __syncthreads();
    }
#pragma unroll
    for (int i = 0; i < 4; ++i) {
        int gr = row0 + ty * 4 + i;
        if (gr < M) {
#pragma unroll
            for (int c4 = 0; c4 < CPT / 4; ++c4) {
                float4 o;
                float* op = (float*)&o;
#pragma unroll
                for (int u = 0; u < 4; ++u) {
                    int col = tx * CPT + c4 * 4 + u;
                    float v = acc[i][c4 * 4 + u] + bias[col];
                    if (RELU) v = v > 0.f ? v : 0.f;
                    op[u] = v;
                }
                *(float4*)(C + (size_t)gr * N + tx * CPT + c4 * 4) = o;
            }
        }
    }
}

// ---------------- fused GATv2: logits + online segment softmax + aggregation ----------------
// One block (128 threads) per dst node. Virtual edge 0 = self loop.
// Per tile of T edges: stage xl[src] rows in LDS, 2 waves compute logits via
// shuffle-reduce, then thread-per-feature online-softmax accumulate from LDS.
#define TILE 32
__global__ __launch_bounds__(128) void gat_fused_k(
    const float* __restrict__ xl, const float* __restrict__ xr,
    const float* __restrict__ att, const int* __restrict__ offs,
    const int* __restrict__ csrs, const float* __restrict__ bias,
    float* __restrict__ hout)
{
    const int n = blockIdx.x;
    const int t = threadIdx.x;        // feature id 0..127
    const int lane = t & 63, w = t >> 6;
    const int beg = offs[n];
    const int total = (offs[n + 1] - beg) + 1;  // + self loop

    __shared__ float rows[TILE][HID];   // 16 KB
    __shared__ float esh[TILE];
    __shared__ float wsh[TILE];
    __shared__ int   srcsh[TILE];
    __shared__ float xrsh[HID];

    xrsh[t] = xr[(size_t)n * HID + t];
    // per-lane constants for the logit phase (features lane and lane+64)
    const float at0 = att[lane], at1 = att[lane + 64];
    __syncthreads();
    const float xr0 = xrsh[lane], xr1 = xrsh[lane + 64];

    float m = -INFINITY, s = 0.f, acc = 0.f;

    for (int base = 0; base < total; base += TILE) {
        const int cnt = min(TILE, total - base);
        __syncthreads();  // protect rows/esh/srcsh from previous tile's readers
        if (t < cnt) {
            int i = base + t;
            srcsh[t] = (i == 0) ? n : csrs[beg + i - 1];
        }
        __syncthreads();
        // stage rows (coalesced 512B per row)
        for (int j = 0; j < cnt; ++j)
            rows[j][t] = xl[(size_t)srcsh[j] * HID + t];
        __syncthreads();
        // logits: wave w handles edges w, w+2, ...
        for (int j = w; j < cnt; j += 2) {
            float a0 = rows[j][lane], a1 = rows[j][lane + 64];
            float m0 = a0 + xr0; m0 = m0 > 0.f ? m0 : 0.2f * m0;
            float m1 = a1 + xr1; m1 = m1 > 0.f ? m1 : 0.2f * m1;
            float v = fmaf(m0, at0, m1 * at1);
#pragma unroll
            for (int off = 32; off > 0; off >>= 1) v += __shfl_down(v, off, 64);
            if (lane == 0) esh[j] = v;
        }
        __syncthreads();
        // online softmax update (all threads track identical m,s arithmetic)
        float mnew = m;
        for (int j = 0; j < cnt; ++j) mnew = fmaxf(mnew, esh[j]);
        if (t < cnt) wsh[t] = expf(esh[t] - mnew);
        __syncthreads();
        float scale = expf(m - mnew);  // expf(-inf)=0 handles first tile
        s *= scale; acc *= scale;
        for (int j = 0; j < cnt; ++j) {
            float wj = wsh[j];
            s += wj;
            acc = fmaf(wj, rows[j][t], acc);
        }
        m = mnew;
    }
    hout[(size_t)n * HID + t] = acc / s + bias[t];
}

// ---------------- edge decoder final: sigmoid(row . W2 + b2) ----------------
__global__ __launch_bounds__(256) void edec_out_k(
    const float* __restrict__ Ebuf, const float* __restrict__ W2,
    const float* __restrict__ b2, float* __restrict__ out, int Mc)
{
    int wid = (blockIdx.x * 256 + threadIdx.x) >> 6;
    int lane = threadIdx.x & 63;
    if (wid >= Mc) return;
    float2 v = *(const float2*)(Ebuf + (size_t)wid * HID + lane * 2);
    float2 w = *(const float2*)(W2 + lane * 2);
    float d = fmaf(v.x, w.x, v.y * w.y);
#pragma unroll
    for (int off = 32; off > 0; off >>= 1) d += __shfl_down(d, off, 64);
    if (lane == 0) out[wid] = 1.f / (1.f + expf(-(d + b2[0])));
}

extern "C" void kernel_launch(void* const* d_in, const int* in_sizes, int n_in,
                              void* d_out, int out_size, void* d_ws, size_t ws_size,
                              hipStream_t stream)
{
    const float* x    = (const float*)d_in[0];
    const float* emb  = (const float*)d_in[1];
    const int*   ei   = (const int*)d_in[2];
    const int*   bidx = (const int*)d_in[3];
    const int*   eim  = (const int*)d_in[4];
    const float* encW = (const float*)d_in[5];
    const float* encB = (const float*)d_in[6];
    const float* gWl  = (const float*)d_in[7];
    const float* gbl  = (const float*)d_in[8];
    const float* gWr  = (const float*)d_in[9];
    const float* gbr  = (const float*)d_in[10];
    const float* gatt = (const float*)d_in[11];
    const float* gb   = (const float*)d_in[12];
    const float* eW0  = (const float*)d_in[13];
    const float* eb0  = (const float*)d_in[14];
    const float* eW1  = (const float*)d_in[15];
    const float* eb1  = (const float*)d_in[16];
    const float* eW2  = (const float*)d_in[17];
    const float* eb2  = (const float*)d_in[18];
    const float* nW0  = (const float*)d_in[19];
    const float* nb0  = (const float*)d_in[20];
    const float* nW1  = (const float*)d_in[21];
    const float* nb1  = (const float*)d_in[22];
    const float* nW2  = (const float*)d_in[23];
    const float* nb2  = (const float*)d_in[24];
    float* out = (float*)d_out;

    char* wptr = (char*)d_ws;
    auto alloc = [&](size_t bytes) {
        char* p = wptr;
        wptr += (bytes + 255) & ~(size_t)255;
        return p;
    };
    float* h     = (float*)alloc((size_t)NN * HID * 4);
    float* xl    = (float*)alloc((size_t)NN * HID * 4);
    float* xr    = (float*)alloc((size_t)NN * HID * 4);
    int* counts  = (int*)alloc((size_t)NN * 4);
    int* offs    = (int*)alloc((size_t)(NN + 1) * 4);
    int* csrs    = (int*)alloc((size_t)NE * 4);
    // aliases (used only after the GAT layers are done with xl/xr)
    float* Ebuf = xl;                    // 50000*128 per edge-decoder chunk
    float* nb0t = xr;                    // 5000*128
    float* nb1t = xr + (size_t)NBLOCK * HID;

    // ---- CSR build (graph is static across the 3 layers) ----
    zero_k<<<(NN + 255) / 256, 256, 0, stream>>>(counts, NN);
    count_k<<<(NE + 255) / 256, 256, 0, stream>>>(ei, counts);
    scan_k<<<1, 256, 0, stream>>>(counts, offs);
    zero_k<<<(NN + 255) / 256, 256, 0, stream>>>(counts, NN);
    scatter_k<<<(NE + 255) / 256, 256, 0, stream>>>(ei, offs, counts, csrs);

    const int gN = (NN + 63) / 64;
    // ---- encoder MLP: concat(x, emb) -> relu -> relu -> linear ----
    gemm_k<128, true ><<<gN, 256, 0, stream>>>(x, 64, 64, emb, 64, nullptr, nullptr, 128,
                                               encW, encB, xl, NN);
    gemm_k<128, true ><<<gN, 256, 0, stream>>>(xl, 128, 128, nullptr, 0, nullptr, nullptr, 128,
                                               encW + 128 * 128, encB + 128, xr, NN);
    gemm_k<128, false><<<gN, 256, 0, stream>>>(xr, 128, 128, nullptr, 0, nullptr, nullptr, 128,
                                               encW + 2 * 128 * 128, encB + 256, h, NN);

    // ---- 3 GATv2 layers ----
    for (int l = 0; l < 3; ++l) {
        const float* Wl  = gWl + (size_t)l * HID * HID;
        const float* bl  = gbl + (size_t)l * HID;
        const float* Wr  = gWr + (size_t)l * HID * HID;
        const float* br  = gbr + (size_t)l * HID;
        const float* att = gatt + (size_t)l * HID;
        const float* bb  = gb + (size_t)l * HID;
        gemm_k<128, false><<<gN, 256, 0, stream>>>(h, 128, 128, nullptr, 0, nullptr, nullptr, 128,
                                                   Wl, bl, xl, NN);
        gemm_k<128, false><<<gN, 256, 0, stream>>>(h, 128, 128, nullptr, 0, nullptr, nullptr, 128,
                                                   Wr, br, xr, NN);
        gat_fused_k<<<NN, 128, 0, stream>>>(xl, xr, att, offs, csrs, bb, h);
    }

    // ---- edge decoder on imaginary edges, 4 chunks of 50000 rows ----
    for (int c = 0; c < 4; ++c) {
        const int Mc = 50000;
        const int* i0 = eim + (size_t)c * Mc;
        const int* i1 = eim + NIMAG + (size_t)c * Mc;
        gemm_k<128, true ><<<(Mc + 63) / 64, 256, 0, stream>>>(h, 128, 128, h, 128, i0, i1, 256,
                                                               eW0, eb0, Ebuf, Mc);
        gemm_k<128, true ><<<(Mc + 63) / 64, 256, 0, stream>>>(Ebuf, 128, 128, nullptr, 0,
                                                               nullptr, nullptr, 128,
                                                               eW1, eb1, Ebuf, Mc);
        edec_out_k<<<(Mc + 3) / 4, 256, 0, stream>>>(Ebuf, eW2, eb2,
                                                     out + (size_t)NBLOCK * 64 + (size_t)c * Mc, Mc);
    }

    // ---- node decoder ----
    const int gB = (NBLOCK + 63) / 64;
    gemm_k<128, true ><<<gB, 256, 0, stream>>>(h, 128, 128, nullptr, 0, bidx, nullptr, 128,
                                               nW0, nb0, nb0t, NBLOCK);
    gemm_k<128, true ><<<gB, 256, 0, stream>>>(nb0t, 128, 128, nullptr, 0, nullptr, nullptr, 128,
                                               nW1, nb1, nb1t, NBLOCK);
    gemm_k<64, false><<<gB, 256, 0, stream>>>(nb1t, 128, 128, nullptr, 0, nullptr, nullptr, 128,
                                              nW2, nb2, out, NBLOCK);
}

// Round 3
// 1340.844 us; speedup vs baseline: 1.4909x; 1.2138x over previous
//
#include <hip/hip_runtime.h>
#include <hip/hip_bf16.h>
#include <math.h>

#define NN 50000
#define NE 1000000
#define NIMAG 200000
#define NBLOCK 5000
#define HID 128

typedef __attribute__((ext_vector_type(8))) short bf16x8;
typedef __attribute__((ext_vector_type(4))) float f32x4;

__device__ inline unsigned short f2bf(float x) {
    unsigned u = __float_as_uint(x);
    unsigned r = u + 0x7fff + ((u >> 16) & 1);   // RNE
    return (unsigned short)(r >> 16);
}
__device__ inline float bf2f(unsigned short b) {
    return __uint_as_float((unsigned)b << 16);
}

// ---------------- zero fill ----------------
__global__ void zero_k(int* __restrict__ p, int n) {
    int i = blockIdx.x * 256 + threadIdx.x;
    if (i < n) p[i] = 0;
}

// ---------------- CSR build ----------------
__global__ void count_k(const int* __restrict__ ei, int* __restrict__ counts) {
    int e = blockIdx.x * 256 + threadIdx.x;
    if (e < NE) atomicAdd(&counts[ei[NE + e]], 1);
}

__global__ void scan_k(const int* __restrict__ counts, int* __restrict__ offs) {
    __shared__ int ssum[256];
    int t = threadIdx.x;
    const int chunk = (NN + 255) / 256;
    int beg = t * chunk, end = min(beg + chunk, NN);
    int s = 0;
    for (int i = beg; i < end; ++i) s += counts[i];
    ssum[t] = s;
    __syncthreads();
    for (int off = 1; off < 256; off <<= 1) {
        int v = (t >= off) ? ssum[t - off] : 0;
        __syncthreads();
        if (t >= off) ssum[t] += v;
        __syncthreads();
    }
    int run = ssum[t] - s;  // exclusive prefix
    for (int i = beg; i < end; ++i) { offs[i] = run; run += counts[i]; }
    if (t == 255) offs[NN] = run;
}

__global__ void scatter_k(const int* __restrict__ ei, const int* __restrict__ offs,
                          int* __restrict__ cursor, int* __restrict__ csr_src) {
    int e = blockIdx.x * 256 + threadIdx.x;
    if (e < NE) {
        int d = ei[NE + e];
        int pos = offs[d] + atomicAdd(&cursor[d], 1);
        csr_src[pos] = ei[e];
    }
}

// ---------------- split-bf16 MFMA GEMM: C[M,N] = act(A[M,K] @ W[K,N] + bias) ----
// A[row][k] = k < K0 ? P0[(idx0?idx0[row]:row)*ld0 + k] : P1[(idx1?idx1[row]:row)*ld1 + k-K0]
// fp32 in/out; internally a = a_hi + a_lo (bf16 each), 3 MFMA products (hh, hl, lh)
// give ~fp32 accuracy on the matrix pipe. Operand roles swapped (Aop=W^T, Bop=A)
// so both fragments are k-contiguous ds_read_b128 from LDS.
template <int N, bool RELU>
__global__ __launch_bounds__(256) void gemm_mfma_k(
    const float* __restrict__ P0, int ld0, int K0,
    const float* __restrict__ P1, int ld1,
    const int* __restrict__ idx0, const int* __restrict__ idx1,
    int K,
    const float* __restrict__ W, const float* __restrict__ bias,
    float* __restrict__ C, int M)
{
    constexpr int KC = 64;          // K chunk
    constexpr int NTW = N / 64;     // n-tiles (of 16) per wave
    constexpr int LDP = 72;         // LDS row stride in shorts (144B: 16B-aligned, 2-way bank alias)
    __shared__ __align__(16) short As_h[64][LDP];
    __shared__ __align__(16) short As_l[64][LDP];
    __shared__ __align__(16) short Wt_h[N][LDP];
    __shared__ __align__(16) short Wt_l[N][LDP];

    const int t = threadIdx.x;
    const int w = t >> 6, lane = t & 63;
    const int llo = lane & 15, lhi = lane >> 4;
    const int row0 = blockIdx.x * 64;

    f32x4 acc[4][NTW];
#pragma unroll
    for (int mt = 0; mt < 4; ++mt)
#pragma unroll
        for (int nt = 0; nt < NTW; ++nt) {
            f32x4 z = {0.f, 0.f, 0.f, 0.f};
            acc[mt][nt] = z;
        }

    for (int kb = 0; kb < K; kb += KC) {
        const float* base; int ld, koff; const int* idx;
        if (kb < K0) { base = P0; ld = ld0; koff = kb; idx = idx0; }
        else         { base = P1; ld = ld1; koff = kb - K0; idx = idx1; }

        // ---- stage A chunk [64 rows x 64 k] with hi/lo split ----
#pragma unroll
        for (int j = 0; j < 4; ++j) {
            int u = j * 256 + t;
            int lr = u >> 4;          // local row 0..63
            int q  = u & 15;          // float4 index within 64 floats
            int gr = row0 + lr; if (gr >= M) gr = M - 1;
            int sr = idx ? idx[gr] : gr;
            float4 v = *(const float4*)(base + (size_t)sr * ld + koff + q * 4);
            float xs[4] = {v.x, v.y, v.z, v.w};
            short4 h4, l4;
            short* hp = (short*)&h4; short* lp = (short*)&l4;
#pragma unroll
            for (int i = 0; i < 4; ++i) {
                unsigned short h = f2bf(xs[i]);
                hp[i] = (short)h;
                lp[i] = (short)f2bf(xs[i] - bf2f(h));
            }
            *(short4*)&As_h[lr][q * 4] = h4;
            *(short4*)&As_l[lr][q * 4] = l4;
        }
        // ---- stage W chunk transposed: Wt[n][k], hi/lo split ----
        {
            constexpr int GP  = 256 / N;   // thread groups over n
            constexpr int OPT = 8 / GP;    // k-octets per thread
            int n = t & (N - 1);
            int g = t / N;
#pragma unroll
            for (int oo = 0; oo < OPT; ++oo) {
                int oct = g * OPT + oo;
                float v[8];
#pragma unroll
                for (int i = 0; i < 8; ++i)
                    v[i] = W[(size_t)(kb + oct * 8 + i) * N + n];
                union { short s[8]; bf16x8 v8; } h8, l8;
#pragma unroll
                for (int i = 0; i < 8; ++i) {
                    unsigned short h = f2bf(v[i]);
                    h8.s[i] = (short)h;
                    l8.s[i] = (short)f2bf(v[i] - bf2f(h));
                }
                *(bf16x8*)&Wt_h[n][oct * 8] = h8.v8;
                *(bf16x8*)&Wt_l[n][oct * 8] = l8.v8;
            }
        }
        __syncthreads();
        // ---- compute: per k-step, wave covers NTW n-tiles x 4 m-tiles ----
#pragma unroll
        for (int ks = 0; ks < KC; ks += 32) {
            bf16x8 aw_h[NTW], aw_l[NTW], ba_h[4], ba_l[4];
#pragma unroll
            for (int nt = 0; nt < NTW; ++nt) {
                int n = (w * NTW + nt) * 16 + llo;
                aw_h[nt] = *(const bf16x8*)&Wt_h[n][ks + lhi * 8];
                aw_l[nt] = *(const bf16x8*)&Wt_l[n][ks + lhi * 8];
            }
#pragma unroll
            for (int mt = 0; mt < 4; ++mt) {
                int m = mt * 16 + llo;
                ba_h[mt] = *(const bf16x8*)&As_h[m][ks + lhi * 8];
                ba_l[mt] = *(const bf16x8*)&As_l[m][ks + lhi * 8];
            }
#pragma unroll
            for (int mt = 0; mt < 4; ++mt)
#pragma unroll
                for (int nt = 0; nt < NTW; ++nt) {
                    acc[mt][nt] = __builtin_amdgcn_mfma_f32_16x16x32_bf16(
                        aw_h[nt], ba_h[mt], acc[mt][nt], 0, 0, 0);
                    acc[mt][nt] = __builtin_amdgcn_mfma_f32_16x16x32_bf16(
                        aw_h[nt], ba_l[mt], acc[mt][nt], 0, 0, 0);
                    acc[mt][nt] = __builtin_amdgcn_mfma_f32_16x16x32_bf16(
                        aw_l[nt], ba_h[mt], acc[mt][nt], 0, 0, 0);
                }
        }
        __syncthreads();
    }
    // ---- epilogue: D row index = output col, D col index = output row ----
#pragma unroll
    for (int mt = 0; mt < 4; ++mt) {
        int r = row0 + mt * 16 + llo;
        if (r < M) {
#pragma unroll
            for (int nt = 0; nt < NTW; ++nt) {
                int c0 = (w * NTW + nt) * 16 + lhi * 4;
                float4 o;
                float* op = (float*)&o;
#pragma unroll
                for (int u = 0; u < 4; ++u) {
                    float v = acc[mt][nt][u] + bias[c0 + u];
                    if (RELU) v = v > 0.f ? v : 0.f;
                    op[u] = v;
                }
                *(float4*)(C + (size_t)r * N + c0) = o;
            }
        }
    }
}

// ---------------- fused GATv2: logits + online segment softmax + aggregation ----------------
#define TILE 32
__global__ __launch_bounds__(128) void gat_fused_k(
    const float* __restrict__ xl, const float* __restrict__ xr,
    const float* __restrict__ att, const int* __restrict__ offs,
    const int* __restrict__ csrs, const float* __restrict__ bias,
    float* __restrict__ hout)
{
    const int n = blockIdx.x;
    const int t = threadIdx.x;        // feature id 0..127
    const int lane = t & 63, w = t >> 6;
    const int beg = offs[n];
    const int total = (offs[n + 1] - beg) + 1;  // + self loop

    __shared__ float rows[TILE][HID];   // 16 KB
    __shared__ float esh[TILE];
    __shared__ float wsh[TILE];
    __shared__ int   srcsh[TILE];
    __shared__ float xrsh[HID];

    xrsh[t] = xr[(size_t)n * HID + t];
    const float at0 = att[lane], at1 = att[lane + 64];
    __syncthreads();
    const float xr0 = xrsh[lane], xr1 = xrsh[lane + 64];

    float m = -INFINITY, s = 0.f, acc = 0.f;

    for (int base = 0; base < total; base += TILE) {
        const int cnt = min(TILE, total - base);
        __syncthreads();
        if (t < cnt) {
            int i = base + t;
            srcsh[t] = (i == 0) ? n : csrs[beg + i - 1];
        }
        __syncthreads();
        for (int j = 0; j < cnt; ++j)
            rows[j][t] = xl[(size_t)srcsh[j] * HID + t];
        __syncthreads();
        for (int j = w; j < cnt; j += 2) {
            float a0 = rows[j][lane], a1 = rows[j][lane + 64];
            float m0 = a0 + xr0; m0 = m0 > 0.f ? m0 : 0.2f * m0;
            float m1 = a1 + xr1; m1 = m1 > 0.f ? m1 : 0.2f * m1;
            float v = fmaf(m0, at0, m1 * at1);
#pragma unroll
            for (int off = 32; off > 0; off >>= 1) v += __shfl_down(v, off, 64);
            if (lane == 0) esh[j] = v;
        }
        __syncthreads();
        float mnew = m;
        for (int j = 0; j < cnt; ++j) mnew = fmaxf(mnew, esh[j]);
        if (t < cnt) wsh[t] = expf(esh[t] - mnew);
        __syncthreads();
        float scale = expf(m - mnew);
        s *= scale; acc *= scale;
        for (int j = 0; j < cnt; ++j) {
            float wj = wsh[j];
            s += wj;
            acc = fmaf(wj, rows[j][t], acc);
        }
        m = mnew;
    }
    hout[(size_t)n * HID + t] = acc / s + bias[t];
}

// ---------------- edge decoder final: sigmoid(row . W2 + b2) ----------------
__global__ __launch_bounds__(256) void edec_out_k(
    const float* __restrict__ Ebuf, const float* __restrict__ W2,
    const float* __restrict__ b2, float* __restrict__ out, int Mc)
{
    int wid = (blockIdx.x * 256 + threadIdx.x) >> 6;
    int lane = threadIdx.x & 63;
    if (wid >= Mc) return;
    float2 v = *(const float2*)(Ebuf + (size_t)wid * HID + lane * 2);
    float2 w = *(const float2*)(W2 + lane * 2);
    float d = fmaf(v.x, w.x, v.y * w.y);
#pragma unroll
    for (int off = 32; off > 0; off >>= 1) d += __shfl_down(d, off, 64);
    if (lane == 0) out[wid] = 1.f / (1.f + expf(-(d + b2[0])));
}

extern "C" void kernel_launch(void* const* d_in, const int* in_sizes, int n_in,
                              void* d_out, int out_size, void* d_ws, size_t ws_size,
                              hipStream_t stream)
{
    const float* x    = (const float*)d_in[0];
    const float* emb  = (const float*)d_in[1];
    const int*   ei   = (const int*)d_in[2];
    const int*   bidx = (const int*)d_in[3];
    const int*   eim  = (const int*)d_in[4];
    const float* encW = (const float*)d_in[5];
    const float* encB = (const float*)d_in[6];
    const float* gWl  = (const float*)d_in[7];
    const float* gbl  = (const float*)d_in[8];
    const float* gWr  = (const float*)d_in[9];
    const float* gbr  = (const float*)d_in[10];
    const float* gatt = (const float*)d_in[11];
    const float* gb   = (const float*)d_in[12];
    const float* eW0  = (const float*)d_in[13];
    const float* eb0  = (const float*)d_in[14];
    const float* eW1  = (const float*)d_in[15];
    const float* eb1  = (const float*)d_in[16];
    const float* eW2  = (const float*)d_in[17];
    const float* eb2  = (const float*)d_in[18];
    const float* nW0  = (const float*)d_in[19];
    const float* nb0  = (const float*)d_in[20];
    const float* nW1  = (const float*)d_in[21];
    const float* nb1  = (const float*)d_in[22];
    const float* nW2  = (const float*)d_in[23];
    const float* nb2  = (const float*)d_in[24];
    float* out = (float*)d_out;

    char* wptr = (char*)d_ws;
    auto alloc = [&](size_t bytes) {
        char* p = wptr;
        wptr += (bytes + 255) & ~(size_t)255;
        return p;
    };
    float* h     = (float*)alloc((size_t)NN * HID * 4);
    float* xl    = (float*)alloc((size_t)NN * HID * 4);
    float* xr    = (float*)alloc((size_t)NN * HID * 4);
    int* counts  = (int*)alloc((size_t)NN * 4);
    int* offs    = (int*)alloc((size_t)(NN + 1) * 4);
    int* csrs    = (int*)alloc((size_t)NE * 4);
    // aliases (used only after the GAT layers are done with xl/xr)
    float* Ebuf = xl;                    // 50000*128 per edge-decoder chunk
    float* nb0t = xr;                    // 5000*128
    float* nb1t = xr + (size_t)NBLOCK * HID;

    // ---- CSR build (graph is static across the 3 layers) ----
    zero_k<<<(NN + 255) / 256, 256, 0, stream>>>(counts, NN);
    count_k<<<(NE + 255) / 256, 256, 0, stream>>>(ei, counts);
    scan_k<<<1, 256, 0, stream>>>(counts, offs);
    zero_k<<<(NN + 255) / 256, 256, 0, stream>>>(counts, NN);
    scatter_k<<<(NE + 255) / 256, 256, 0, stream>>>(ei, offs, counts, csrs);

    const int gN = (NN + 63) / 64;
    // ---- encoder MLP: concat(x, emb) -> relu -> relu -> linear ----
    gemm_mfma_k<128, true ><<<gN, 256, 0, stream>>>(x, 64, 64, emb, 64, nullptr, nullptr, 128,
                                                    encW, encB, xl, NN);
    gemm_mfma_k<128, true ><<<gN, 256, 0, stream>>>(xl, 128, 128, nullptr, 0, nullptr, nullptr, 128,
                                                    encW + 128 * 128, encB + 128, xr, NN);
    gemm_mfma_k<128, false><<<gN, 256, 0, stream>>>(xr, 128, 128, nullptr, 0, nullptr, nullptr, 128,
                                                    encW + 2 * 128 * 128, encB + 256, h, NN);

    // ---- 3 GATv2 layers ----
    for (int l = 0; l < 3; ++l) {
        const float* Wl  = gWl + (size_t)l * HID * HID;
        const float* bl  = gbl + (size_t)l * HID;
        const float* Wr  = gWr + (size_t)l * HID * HID;
        const float* br  = gbr + (size_t)l * HID;
        const float* att = gatt + (size_t)l * HID;
        const float* bb  = gb + (size_t)l * HID;
        gemm_mfma_k<128, false><<<gN, 256, 0, stream>>>(h, 128, 128, nullptr, 0, nullptr, nullptr, 128,
                                                        Wl, bl, xl, NN);
        gemm_mfma_k<128, false><<<gN, 256, 0, stream>>>(h, 128, 128, nullptr, 0, nullptr, nullptr, 128,
                                                        Wr, br, xr, NN);
        gat_fused_k<<<NN, 128, 0, stream>>>(xl, xr, att, offs, csrs, bb, h);
    }

    // ---- edge decoder on imaginary edges, 4 chunks of 50000 rows ----
    for (int c = 0; c < 4; ++c) {
        const int Mc = 50000;
        const int* i0 = eim + (size_t)c * Mc;
        const int* i1 = eim + NIMAG + (size_t)c * Mc;
        gemm_mfma_k<128, true ><<<(Mc + 63) / 64, 256, 0, stream>>>(h, 128, 128, h, 128, i0, i1, 256,
                                                                    eW0, eb0, Ebuf, Mc);
        gemm_mfma_k<128, true ><<<(Mc + 63) / 64, 256, 0, stream>>>(Ebuf, 128, 128, nullptr, 0,
                                                                    nullptr, nullptr, 128,
                                                                    eW1, eb1, Ebuf, Mc);
        edec_out_k<<<(Mc + 3) / 4, 256, 0, stream>>>(Ebuf, eW2, eb2,
                                                     out + (size_t)NBLOCK * 64 + (size_t)c * Mc, Mc);
    }

    // ---- node decoder ----
    const int gB = (NBLOCK + 63) / 64;
    gemm_mfma_k<128, true ><<<gB, 256, 0, stream>>>(h, 128, 128, nullptr, 0, bidx, nullptr, 128,
                                                    nW0, nb0, nb0t, NBLOCK);
    gemm_mfma_k<128, true ><<<gB, 256, 0, stream>>>(nb0t, 128, 128, nullptr, 0, nullptr, nullptr, 128,
                                                    nW1, nb1, nb1t, NBLOCK);
    gemm_mfma_k<64, false><<<gB, 256, 0, stream>>>(nb1t, 128, 128, nullptr, 0, nullptr, nullptr, 128,
                                                   nW2, nb2, out, NBLOCK);
}

// Round 4
// 1190.013 us; speedup vs baseline: 1.6799x; 1.1267x over previous
//
#include <hip/hip_runtime.h>
#include <hip/hip_bf16.h>
#include <math.h>

#define NN 50000
#define NE 1000000
#define NIMAG 200000
#define NBLOCK 5000
#define HID 128

typedef __attribute__((ext_vector_type(8))) short bf16x8;
typedef __attribute__((ext_vector_type(4))) float f32x4;

__device__ inline unsigned short f2bf(float x) {
    unsigned u = __float_as_uint(x);
    unsigned r = u + 0x7fff + ((u >> 16) & 1);   // RNE
    return (unsigned short)(r >> 16);
}
__device__ inline float bf2f(unsigned short b) {
    return __uint_as_float((unsigned)b << 16);
}

// ---------------- zero fill ----------------
__global__ void zero_k(int* __restrict__ p, int n) {
    int i = blockIdx.x * 256 + threadIdx.x;
    if (i < n) p[i] = 0;
}

// ---------------- CSR build ----------------
__global__ void count_k(const int* __restrict__ ei, int* __restrict__ counts) {
    int e = blockIdx.x * 256 + threadIdx.x;
    if (e < NE) atomicAdd(&counts[ei[NE + e]], 1);
}

__global__ void scan_k(const int* __restrict__ counts, int* __restrict__ offs) {
    __shared__ int ssum[256];
    int t = threadIdx.x;
    const int chunk = (NN + 255) / 256;
    int beg = t * chunk, end = min(beg + chunk, NN);
    int s = 0;
    for (int i = beg; i < end; ++i) s += counts[i];
    ssum[t] = s;
    __syncthreads();
    for (int off = 1; off < 256; off <<= 1) {
        int v = (t >= off) ? ssum[t - off] : 0;
        __syncthreads();
        if (t >= off) ssum[t] += v;
        __syncthreads();
    }
    int run = ssum[t] - s;  // exclusive prefix
    for (int i = beg; i < end; ++i) { offs[i] = run; run += counts[i]; }
    if (t == 255) offs[NN] = run;
}

__global__ void scatter_k(const int* __restrict__ ei, const int* __restrict__ offs,
                          int* __restrict__ cursor, int* __restrict__ csr_src) {
    int e = blockIdx.x * 256 + threadIdx.x;
    if (e < NE) {
        int d = ei[NE + e];
        int pos = offs[d] + atomicAdd(&cursor[d], 1);
        csr_src[pos] = ei[e];
    }
}

// ---------------- split-bf16 MFMA GEMM: C[M,N] = act(A[M,K] @ W[K,N] + bias) ----
template <int N, bool RELU>
__global__ __launch_bounds__(256) void gemm_mfma_k(
    const float* __restrict__ P0, int ld0, int K0,
    const float* __restrict__ P1, int ld1,
    const int* __restrict__ idx0, const int* __restrict__ idx1,
    int K,
    const float* __restrict__ W, const float* __restrict__ bias,
    float* __restrict__ C, int M)
{
    constexpr int KC = 64;
    constexpr int NTW = N / 64;
    constexpr int LDP = 72;
    __shared__ __align__(16) short As_h[64][LDP];
    __shared__ __align__(16) short As_l[64][LDP];
    __shared__ __align__(16) short Wt_h[N][LDP];
    __shared__ __align__(16) short Wt_l[N][LDP];

    const int t = threadIdx.x;
    const int w = t >> 6, lane = t & 63;
    const int llo = lane & 15, lhi = lane >> 4;
    const int row0 = blockIdx.x * 64;

    f32x4 acc[4][NTW];
#pragma unroll
    for (int mt = 0; mt < 4; ++mt)
#pragma unroll
        for (int nt = 0; nt < NTW; ++nt) {
            f32x4 z = {0.f, 0.f, 0.f, 0.f};
            acc[mt][nt] = z;
        }

    for (int kb = 0; kb < K; kb += KC) {
        const float* base; int ld, koff; const int* idx;
        if (kb < K0) { base = P0; ld = ld0; koff = kb; idx = idx0; }
        else         { base = P1; ld = ld1; koff = kb - K0; idx = idx1; }

#pragma unroll
        for (int j = 0; j < 4; ++j) {
            int u = j * 256 + t;
            int lr = u >> 4;
            int q  = u & 15;
            int gr = row0 + lr; if (gr >= M) gr = M - 1;
            int sr = idx ? idx[gr] : gr;
            float4 v = *(const float4*)(base + (size_t)sr * ld + koff + q * 4);
            float xs[4] = {v.x, v.y, v.z, v.w};
            short4 h4, l4;
            short* hp = (short*)&h4; short* lp = (short*)&l4;
#pragma unroll
            for (int i = 0; i < 4; ++i) {
                unsigned short h = f2bf(xs[i]);
                hp[i] = (short)h;
                lp[i] = (short)f2bf(xs[i] - bf2f(h));
            }
            *(short4*)&As_h[lr][q * 4] = h4;
            *(short4*)&As_l[lr][q * 4] = l4;
        }
        {
            constexpr int GP  = 256 / N;
            constexpr int OPT = 8 / GP;
            int n = t & (N - 1);
            int g = t / N;
#pragma unroll
            for (int oo = 0; oo < OPT; ++oo) {
                int oct = g * OPT + oo;
                float v[8];
#pragma unroll
                for (int i = 0; i < 8; ++i)
                    v[i] = W[(size_t)(kb + oct * 8 + i) * N + n];
                union { short s[8]; bf16x8 v8; } h8, l8;
#pragma unroll
                for (int i = 0; i < 8; ++i) {
                    unsigned short h = f2bf(v[i]);
                    h8.s[i] = (short)h;
                    l8.s[i] = (short)f2bf(v[i] - bf2f(h));
                }
                *(bf16x8*)&Wt_h[n][oct * 8] = h8.v8;
                *(bf16x8*)&Wt_l[n][oct * 8] = l8.v8;
            }
        }
        __syncthreads();
#pragma unroll
        for (int ks = 0; ks < KC; ks += 32) {
            bf16x8 aw_h[NTW], aw_l[NTW], ba_h[4], ba_l[4];
#pragma unroll
            for (int nt = 0; nt < NTW; ++nt) {
                int n = (w * NTW + nt) * 16 + llo;
                aw_h[nt] = *(const bf16x8*)&Wt_h[n][ks + lhi * 8];
                aw_l[nt] = *(const bf16x8*)&Wt_l[n][ks + lhi * 8];
            }
#pragma unroll
            for (int mt = 0; mt < 4; ++mt) {
                int m = mt * 16 + llo;
                ba_h[mt] = *(const bf16x8*)&As_h[m][ks + lhi * 8];
                ba_l[mt] = *(const bf16x8*)&As_l[m][ks + lhi * 8];
            }
#pragma unroll
            for (int mt = 0; mt < 4; ++mt)
#pragma unroll
                for (int nt = 0; nt < NTW; ++nt) {
                    acc[mt][nt] = __builtin_amdgcn_mfma_f32_16x16x32_bf16(
                        aw_h[nt], ba_h[mt], acc[mt][nt], 0, 0, 0);
                    acc[mt][nt] = __builtin_amdgcn_mfma_f32_16x16x32_bf16(
                        aw_h[nt], ba_l[mt], acc[mt][nt], 0, 0, 0);
                    acc[mt][nt] = __builtin_amdgcn_mfma_f32_16x16x32_bf16(
                        aw_l[nt], ba_h[mt], acc[mt][nt], 0, 0, 0);
                }
        }
        __syncthreads();
    }
#pragma unroll
    for (int mt = 0; mt < 4; ++mt) {
        int r = row0 + mt * 16 + llo;
        if (r < M) {
#pragma unroll
            for (int nt = 0; nt < NTW; ++nt) {
                int c0 = (w * NTW + nt) * 16 + lhi * 4;
                float4 o;
                float* op = (float*)&o;
#pragma unroll
                for (int u = 0; u < 4; ++u) {
                    float v = acc[mt][nt][u] + bias[c0 + u];
                    if (RELU) v = v > 0.f ? v : 0.f;
                    op[u] = v;
                }
                *(float4*)(C + (size_t)r * N + c0) = o;
            }
        }
    }
}

// ---------------- GATv2, wave-per-node, register-resident online softmax ----------------
// One 64-lane wave per dst node; lane owns features 2*lane, 2*lane+1.
// Per edge: one coalesced 512B row load -> leaky+dot -> butterfly reduce ->
// uniform-branch online softmax update. Rows read once; no LDS.
#define GP 8
__global__ __launch_bounds__(256) void gat_wave_k(
    const float* __restrict__ xl, const float* __restrict__ xr,
    const float* __restrict__ att, const int* __restrict__ offs,
    const int* __restrict__ csrs, const float* __restrict__ bias,
    float* __restrict__ hout)
{
    const int wid = (blockIdx.x * 256 + threadIdx.x) >> 6;
    const int lane = threadIdx.x & 63;
    if (wid >= NN) return;
    const int n = wid;
    const int beg = offs[n];
    const int total = (offs[n + 1] - beg) + 1;   // + self loop at slot 0

    const float2 attv = *(const float2*)(att + lane * 2);
    const float2 xrv  = *(const float2*)(xr + (size_t)n * HID + lane * 2);

    float m = -INFINITY, s = 0.f;
    float2 acc = {0.f, 0.f};

    int cs[GP];
    {
        const int c0 = min(GP, total);
#pragma unroll
        for (int p = 0; p < GP; ++p)
            cs[p] = (p < c0) ? ((p == 0) ? n : csrs[beg + p - 1]) : 0;
    }

    for (int base = 0; base < total; base += GP) {
        const int cnt = min(GP, total - base);
        // 1) issue up to GP independent row loads
        float2 r[GP];
#pragma unroll
        for (int p = 0; p < GP; ++p)
            if (p < cnt) r[p] = *(const float2*)(xl + (size_t)cs[p] * HID + lane * 2);
        // 2) prefetch next group's src indices (independent of processing)
        const int nbase = base + GP;
        const int ncnt = min(GP, total - nbase);
        int ns[GP];
#pragma unroll
        for (int p = 0; p < GP; ++p)
            ns[p] = (p < ncnt) ? csrs[beg + nbase + p - 1] : 0;
        // 3) logits (independent across group -> ILP)
        float e[GP];
#pragma unroll
        for (int p = 0; p < GP; ++p) {
            if (p < cnt) {
                float mx = r[p].x + xrv.x; mx = mx > 0.f ? mx : 0.2f * mx;
                float my = r[p].y + xrv.y; my = my > 0.f ? my : 0.2f * my;
                float v = fmaf(mx, attv.x, my * attv.y);
#pragma unroll
                for (int off = 1; off < 64; off <<= 1)
                    v += __shfl_xor(v, off, 64);
                e[p] = v;   // all lanes hold the full dot
            }
        }
        // 4) serial online update (lane-uniform branches)
#pragma unroll
        for (int p = 0; p < GP; ++p) {
            if (p < cnt) {
                if (e[p] > m) {
                    float sc = __expf(m - e[p]);   // exp(-inf)=0 on first edge
                    s *= sc; acc.x *= sc; acc.y *= sc;
                    m = e[p];
                }
                float wj = __expf(e[p] - m);
                s += wj;
                acc.x = fmaf(wj, r[p].x, acc.x);
                acc.y = fmaf(wj, r[p].y, acc.y);
            }
        }
#pragma unroll
        for (int p = 0; p < GP; ++p) cs[p] = ns[p];
    }
    const float inv = 1.f / s;
    float2 o;
    o.x = fmaf(acc.x, inv, bias[lane * 2]);
    o.y = fmaf(acc.y, inv, bias[lane * 2 + 1]);
    *(float2*)(hout + (size_t)n * HID + lane * 2) = o;
}

// ---------------- edge decoder final: sigmoid(row . W2 + b2) ----------------
__global__ __launch_bounds__(256) void edec_out_k(
    const float* __restrict__ Ebuf, const float* __restrict__ W2,
    const float* __restrict__ b2, float* __restrict__ out, int Mc)
{
    int wid = (blockIdx.x * 256 + threadIdx.x) >> 6;
    int lane = threadIdx.x & 63;
    if (wid >= Mc) return;
    float2 v = *(const float2*)(Ebuf + (size_t)wid * HID + lane * 2);
    float2 w = *(const float2*)(W2 + lane * 2);
    float d = fmaf(v.x, w.x, v.y * w.y);
#pragma unroll
    for (int off = 32; off > 0; off >>= 1) d += __shfl_down(d, off, 64);
    if (lane == 0) out[wid] = 1.f / (1.f + expf(-(d + b2[0])));
}

extern "C" void kernel_launch(void* const* d_in, const int* in_sizes, int n_in,
                              void* d_out, int out_size, void* d_ws, size_t ws_size,
                              hipStream_t stream)
{
    const float* x    = (const float*)d_in[0];
    const float* emb  = (const float*)d_in[1];
    const int*   ei   = (const int*)d_in[2];
    const int*   bidx = (const int*)d_in[3];
    const int*   eim  = (const int*)d_in[4];
    const float* encW = (const float*)d_in[5];
    const float* encB = (const float*)d_in[6];
    const float* gWl  = (const float*)d_in[7];
    const float* gbl  = (const float*)d_in[8];
    const float* gWr  = (const float*)d_in[9];
    const float* gbr  = (const float*)d_in[10];
    const float* gatt = (const float*)d_in[11];
    const float* gb   = (const float*)d_in[12];
    const float* eW0  = (const float*)d_in[13];
    const float* eb0  = (const float*)d_in[14];
    const float* eW1  = (const float*)d_in[15];
    const float* eb1  = (const float*)d_in[16];
    const float* eW2  = (const float*)d_in[17];
    const float* eb2  = (const float*)d_in[18];
    const float* nW0  = (const float*)d_in[19];
    const float* nb0  = (const float*)d_in[20];
    const float* nW1  = (const float*)d_in[21];
    const float* nb1  = (const float*)d_in[22];
    const float* nW2  = (const float*)d_in[23];
    const float* nb2  = (const float*)d_in[24];
    float* out = (float*)d_out;

    char* wptr = (char*)d_ws;
    auto alloc = [&](size_t bytes) {
        char* p = wptr;
        wptr += (bytes + 255) & ~(size_t)255;
        return p;
    };
    float* h     = (float*)alloc((size_t)NN * HID * 4);
    float* xl    = (float*)alloc((size_t)NN * HID * 4);
    float* xr    = (float*)alloc((size_t)NN * HID * 4);
    int* counts  = (int*)alloc((size_t)NN * 4);
    int* offs    = (int*)alloc((size_t)(NN + 1) * 4);
    int* csrs    = (int*)alloc((size_t)NE * 4);
    // aliases (used only after the GAT layers are done with xl/xr)
    float* Ebuf = xl;
    float* nb0t = xr;
    float* nb1t = xr + (size_t)NBLOCK * HID;

    // ---- CSR build (graph is static across the 3 layers) ----
    zero_k<<<(NN + 255) / 256, 256, 0, stream>>>(counts, NN);
    count_k<<<(NE + 255) / 256, 256, 0, stream>>>(ei, counts);
    scan_k<<<1, 256, 0, stream>>>(counts, offs);
    zero_k<<<(NN + 255) / 256, 256, 0, stream>>>(counts, NN);
    scatter_k<<<(NE + 255) / 256, 256, 0, stream>>>(ei, offs, counts, csrs);

    const int gN = (NN + 63) / 64;
    // ---- encoder MLP ----
    gemm_mfma_k<128, true ><<<gN, 256, 0, stream>>>(x, 64, 64, emb, 64, nullptr, nullptr, 128,
                                                    encW, encB, xl, NN);
    gemm_mfma_k<128, true ><<<gN, 256, 0, stream>>>(xl, 128, 128, nullptr, 0, nullptr, nullptr, 128,
                                                    encW + 128 * 128, encB + 128, xr, NN);
    gemm_mfma_k<128, false><<<gN, 256, 0, stream>>>(xr, 128, 128, nullptr, 0, nullptr, nullptr, 128,
                                                    encW + 2 * 128 * 128, encB + 256, h, NN);

    // ---- 3 GATv2 layers ----
    const int gGAT = (NN * 64 + 255) / 256;
    for (int l = 0; l < 3; ++l) {
        const float* Wl  = gWl + (size_t)l * HID * HID;
        const float* bl  = gbl + (size_t)l * HID;
        const float* Wr  = gWr + (size_t)l * HID * HID;
        const float* br  = gbr + (size_t)l * HID;
        const float* att = gatt + (size_t)l * HID;
        const float* bb  = gb + (size_t)l * HID;
        gemm_mfma_k<128, false><<<gN, 256, 0, stream>>>(h, 128, 128, nullptr, 0, nullptr, nullptr, 128,
                                                        Wl, bl, xl, NN);
        gemm_mfma_k<128, false><<<gN, 256, 0, stream>>>(h, 128, 128, nullptr, 0, nullptr, nullptr, 128,
                                                        Wr, br, xr, NN);
        gat_wave_k<<<gGAT, 256, 0, stream>>>(xl, xr, att, offs, csrs, bb, h);
    }

    // ---- edge decoder on imaginary edges, 4 chunks of 50000 rows ----
    for (int c = 0; c < 4; ++c) {
        const int Mc = 50000;
        const int* i0 = eim + (size_t)c * Mc;
        const int* i1 = eim + NIMAG + (size_t)c * Mc;
        gemm_mfma_k<128, true ><<<(Mc + 63) / 64, 256, 0, stream>>>(h, 128, 128, h, 128, i0, i1, 256,
                                                                    eW0, eb0, Ebuf, Mc);
        gemm_mfma_k<128, true ><<<(Mc + 63) / 64, 256, 0, stream>>>(Ebuf, 128, 128, nullptr, 0,
                                                                    nullptr, nullptr, 128,
                                                                    eW1, eb1, Ebuf, Mc);
        edec_out_k<<<(Mc + 3) / 4, 256, 0, stream>>>(Ebuf, eW2, eb2,
                                                     out + (size_t)NBLOCK * 64 + (size_t)c * Mc, Mc);
    }

    // ---- node decoder ----
    const int gB = (NBLOCK + 63) / 64;
    gemm_mfma_k<128, true ><<<gB, 256, 0, stream>>>(h, 128, 128, nullptr, 0, bidx, nullptr, 128,
                                                    nW0, nb0, nb0t, NBLOCK);
    gemm_mfma_k<128, true ><<<gB, 256, 0, stream>>>(nb0t, 128, 128, nullptr, 0, nullptr, nullptr, 128,
                                                    nW1, nb1, nb1t, NBLOCK);
    gemm_mfma_k<64, false><<<gB, 256, 0, stream>>>(nb1t, 128, 128, nullptr, 0, nullptr, nullptr, 128,
                                                   nW2, nb2, out, NBLOCK);
}

// Round 5
// 1098.625 us; speedup vs baseline: 1.8196x; 1.0832x over previous
//
#include <hip/hip_runtime.h>
#include <hip/hip_bf16.h>
#include <math.h>

#define NN 50000
#define NE 1000000
#define NIMAG 200000
#define NBLOCK 5000
#define HID 128

typedef __attribute__((ext_vector_type(8))) short bf16x8;
typedef __attribute__((ext_vector_type(4))) float f32x4;

__device__ inline unsigned short f2bf(float x) {
    unsigned u = __float_as_uint(x);
    unsigned r = u + 0x7fff + ((u >> 16) & 1);   // RNE
    return (unsigned short)(r >> 16);
}
__device__ inline float bf2f(unsigned short b) {
    return __uint_as_float((unsigned)b << 16);
}

// ---------------- zero fill ----------------
__global__ void zero_k(int* __restrict__ p, int n) {
    int i = blockIdx.x * 256 + threadIdx.x;
    if (i < n) p[i] = 0;
}

// ---------------- CSR build ----------------
__global__ void count_k(const int* __restrict__ ei, int* __restrict__ counts) {
    int e = blockIdx.x * 256 + threadIdx.x;
    if (e < NE) atomicAdd(&counts[ei[NE + e]], 1);
}

__global__ void scan_k(const int* __restrict__ counts, int* __restrict__ offs) {
    __shared__ int ssum[256];
    int t = threadIdx.x;
    const int chunk = (NN + 255) / 256;
    int beg = t * chunk, end = min(beg + chunk, NN);
    int s = 0;
    for (int i = beg; i < end; ++i) s += counts[i];
    ssum[t] = s;
    __syncthreads();
    for (int off = 1; off < 256; off <<= 1) {
        int v = (t >= off) ? ssum[t - off] : 0;
        __syncthreads();
        if (t >= off) ssum[t] += v;
        __syncthreads();
    }
    int run = ssum[t] - s;
    for (int i = beg; i < end; ++i) { offs[i] = run; run += counts[i]; }
    if (t == 255) offs[NN] = run;
}

__global__ void scatter_k(const int* __restrict__ ei, const int* __restrict__ offs,
                          int* __restrict__ cursor, int* __restrict__ csr_src) {
    int e = blockIdx.x * 256 + threadIdx.x;
    if (e < NE) {
        int d = ei[NE + e];
        int pos = offs[d] + atomicAdd(&cursor[d], 1);
        csr_src[pos] = ei[e];
    }
}

// ---------------- batched W pre-convert: fp32 [K][N] -> split-bf16 [N][K] ----
struct WDesc { const float* src; short* dh; short* dl; int K; int N; };
struct WDescs { WDesc d[14]; };
__global__ __launch_bounds__(256) void wconv_k(WDescs ds) {
    int m = blockIdx.x >> 7;            // 128 blocks per matrix (<= 32768 elts)
    int i = (blockIdx.x & 127) * 256 + threadIdx.x;
    WDesc w = ds.d[m];
    int tot = w.K * w.N;
    if (i < tot) {
        int k = i / w.N, n = i - k * w.N;
        float v = w.src[i];
        unsigned short h = f2bf(v);
        w.dh[(size_t)n * w.K + k] = (short)h;
        w.dl[(size_t)n * w.K + k] = (short)f2bf(v - bf2f(h));
    }
}

// ---------------- split-bf16 MFMA GEMM ----------------
// C = act(A @ W + bias); W pre-converted/transposed planes Wth/Wtl [N][K].
// INSPLIT: A given as hi/lo bf16 planes (no hot-loop conversion);
// else A fp32 (converted during staging; enc layer 0 only).
// OUTSPLIT: write C as hi/lo bf16 planes; else fp32.
template <int N, bool RELU, bool INSPLIT, bool OUTSPLIT>
__global__ __launch_bounds__(256) void gemm2_k(
    const void* __restrict__ A0h, const void* __restrict__ A0l, int ld0, int K0,
    const void* __restrict__ A1h, const void* __restrict__ A1l, int ld1,
    const int* __restrict__ idx0, const int* __restrict__ idx1,
    int K,
    const short* __restrict__ Wth, const short* __restrict__ Wtl,
    const float* __restrict__ bias,
    float* __restrict__ Cf, short* __restrict__ Ch, short* __restrict__ Cl,
    int M)
{
    constexpr int KC = 64;
    constexpr int NTW = N / 64;
    constexpr int LDP = 72;
    __shared__ __align__(16) short As_h[64][LDP];
    __shared__ __align__(16) short As_l[64][LDP];
    __shared__ __align__(16) short Ws_h[N][LDP];
    __shared__ __align__(16) short Ws_l[N][LDP];

    const int t = threadIdx.x;
    const int w = t >> 6, lane = t & 63;
    const int llo = lane & 15, lhi = lane >> 4;
    const int row0 = blockIdx.x * 64;

    f32x4 acc[4][NTW];
#pragma unroll
    for (int mt = 0; mt < 4; ++mt)
#pragma unroll
        for (int nt = 0; nt < NTW; ++nt) {
            f32x4 z = {0.f, 0.f, 0.f, 0.f};
            acc[mt][nt] = z;
        }

    for (int kb = 0; kb < K; kb += KC) {
        const void *bh, *bl; int ld, koff; const int* idx;
        if (kb < K0) { bh = A0h; bl = A0l; ld = ld0; koff = kb; idx = idx0; }
        else         { bh = A1h; bl = A1l; ld = ld1; koff = kb - K0; idx = idx1; }

        if (INSPLIT) {
            // pure vector copy: 2 chunks of 16B per plane per thread
#pragma unroll
            for (int j = 0; j < 2; ++j) {
                int u = j * 256 + t;
                int lr = u >> 3;      // row 0..63
                int q  = u & 7;       // 16B chunk (8 shorts)
                int gr = row0 + lr; if (gr >= M) gr = M - 1;
                int sr = idx ? idx[gr] : gr;
                size_t off = (size_t)sr * ld + koff + q * 8;
                *(bf16x8*)&As_h[lr][q * 8] = *(const bf16x8*)((const short*)bh + off);
                *(bf16x8*)&As_l[lr][q * 8] = *(const bf16x8*)((const short*)bl + off);
            }
        } else {
            // fp32 A: convert during staging (enc layer 0 only)
#pragma unroll
            for (int j = 0; j < 4; ++j) {
                int u = j * 256 + t;
                int lr = u >> 4;
                int q  = u & 15;
                int gr = row0 + lr; if (gr >= M) gr = M - 1;
                int sr = idx ? idx[gr] : gr;
                float4 v = *(const float4*)((const float*)bh + (size_t)sr * ld + koff + q * 4);
                float xs[4] = {v.x, v.y, v.z, v.w};
                short4 h4, l4;
                short* hp = (short*)&h4; short* lp = (short*)&l4;
#pragma unroll
                for (int i = 0; i < 4; ++i) {
                    unsigned short h = f2bf(xs[i]);
                    hp[i] = (short)h;
                    lp[i] = (short)f2bf(xs[i] - bf2f(h));
                }
                *(short4*)&As_h[lr][q * 4] = h4;
                *(short4*)&As_l[lr][q * 4] = l4;
            }
        }
        // W staging: pure vector copy from pre-transposed planes
        {
            constexpr int WCH = N * 8 / 256;   // 16B chunks per thread
#pragma unroll
            for (int j = 0; j < WCH; ++j) {
                int u = j * 256 + t;
                int n = u >> 3;
                int q = u & 7;
                size_t off = (size_t)n * K + kb + q * 8;
                *(bf16x8*)&Ws_h[n][q * 8] = *(const bf16x8*)(Wth + off);
                *(bf16x8*)&Ws_l[n][q * 8] = *(const bf16x8*)(Wtl + off);
            }
        }
        __syncthreads();
#pragma unroll
        for (int ks = 0; ks < KC; ks += 32) {
            bf16x8 aw_h[NTW], aw_l[NTW], ba_h[4], ba_l[4];
#pragma unroll
            for (int nt = 0; nt < NTW; ++nt) {
                int n = (w * NTW + nt) * 16 + llo;
                aw_h[nt] = *(const bf16x8*)&Ws_h[n][ks + lhi * 8];
                aw_l[nt] = *(const bf16x8*)&Ws_l[n][ks + lhi * 8];
            }
#pragma unroll
            for (int mt = 0; mt < 4; ++mt) {
                int m = mt * 16 + llo;
                ba_h[mt] = *(const bf16x8*)&As_h[m][ks + lhi * 8];
                ba_l[mt] = *(const bf16x8*)&As_l[m][ks + lhi * 8];
            }
#pragma unroll
            for (int mt = 0; mt < 4; ++mt)
#pragma unroll
                for (int nt = 0; nt < NTW; ++nt) {
                    acc[mt][nt] = __builtin_amdgcn_mfma_f32_16x16x32_bf16(
                        aw_h[nt], ba_h[mt], acc[mt][nt], 0, 0, 0);
                    acc[mt][nt] = __builtin_amdgcn_mfma_f32_16x16x32_bf16(
                        aw_h[nt], ba_l[mt], acc[mt][nt], 0, 0, 0);
                    acc[mt][nt] = __builtin_amdgcn_mfma_f32_16x16x32_bf16(
                        aw_l[nt], ba_h[mt], acc[mt][nt], 0, 0, 0);
                }
        }
        __syncthreads();
    }
#pragma unroll
    for (int mt = 0; mt < 4; ++mt) {
        int r = row0 + mt * 16 + llo;
        if (r < M) {
#pragma unroll
            for (int nt = 0; nt < NTW; ++nt) {
                int c0 = (w * NTW + nt) * 16 + lhi * 4;
                float v[4];
#pragma unroll
                for (int u = 0; u < 4; ++u) {
                    float z = acc[mt][nt][u] + bias[c0 + u];
                    if (RELU) z = z > 0.f ? z : 0.f;
                    v[u] = z;
                }
                if (OUTSPLIT) {
                    short4 h4, l4;
                    short* hp = (short*)&h4; short* lp = (short*)&l4;
#pragma unroll
                    for (int u = 0; u < 4; ++u) {
                        unsigned short h = f2bf(v[u]);
                        hp[u] = (short)h;
                        lp[u] = (short)f2bf(v[u] - bf2f(h));
                    }
                    *(short4*)(Ch + (size_t)r * N + c0) = h4;
                    *(short4*)(Cl + (size_t)r * N + c0) = l4;
                } else {
                    float4 o = {v[0], v[1], v[2], v[3]};
                    *(float4*)(Cf + (size_t)r * N + c0) = o;
                }
            }
        }
    }
}

// ---------------- GATv2, wave-per-node, register online softmax; split-bf16 out ----
#define GP 8
__global__ __launch_bounds__(256) void gat_wave_k(
    const float* __restrict__ xl, const float* __restrict__ xr,
    const float* __restrict__ att, const int* __restrict__ offs,
    const int* __restrict__ csrs, const float* __restrict__ bias,
    short* __restrict__ houth, short* __restrict__ houtl)
{
    const int wid = (blockIdx.x * 256 + threadIdx.x) >> 6;
    const int lane = threadIdx.x & 63;
    if (wid >= NN) return;
    const int n = wid;
    const int beg = offs[n];
    const int total = (offs[n + 1] - beg) + 1;

    const float2 attv = *(const float2*)(att + lane * 2);
    const float2 xrv  = *(const float2*)(xr + (size_t)n * HID + lane * 2);

    float m = -INFINITY, s = 0.f;
    float2 acc = {0.f, 0.f};

    int cs[GP];
    {
        const int c0 = min(GP, total);
#pragma unroll
        for (int p = 0; p < GP; ++p)
            cs[p] = (p < c0) ? ((p == 0) ? n : csrs[beg + p - 1]) : 0;
    }

    for (int base = 0; base < total; base += GP) {
        const int cnt = min(GP, total - base);
        float2 r[GP];
#pragma unroll
        for (int p = 0; p < GP; ++p)
            if (p < cnt) r[p] = *(const float2*)(xl + (size_t)cs[p] * HID + lane * 2);
        const int nbase = base + GP;
        const int ncnt = min(GP, total - nbase);
        int ns[GP];
#pragma unroll
        for (int p = 0; p < GP; ++p)
            ns[p] = (p < ncnt) ? csrs[beg + nbase + p - 1] : 0;
        float e[GP];
#pragma unroll
        for (int p = 0; p < GP; ++p) {
            if (p < cnt) {
                float mx = r[p].x + xrv.x; mx = mx > 0.f ? mx : 0.2f * mx;
                float my = r[p].y + xrv.y; my = my > 0.f ? my : 0.2f * my;
                float v = fmaf(mx, attv.x, my * attv.y);
#pragma unroll
                for (int off = 1; off < 64; off <<= 1)
                    v += __shfl_xor(v, off, 64);
                e[p] = v;
            }
        }
#pragma unroll
        for (int p = 0; p < GP; ++p) {
            if (p < cnt) {
                if (e[p] > m) {
                    float sc = __expf(m - e[p]);
                    s *= sc; acc.x *= sc; acc.y *= sc;
                    m = e[p];
                }
                float wj = __expf(e[p] - m);
                s += wj;
                acc.x = fmaf(wj, r[p].x, acc.x);
                acc.y = fmaf(wj, r[p].y, acc.y);
            }
        }
#pragma unroll
        for (int p = 0; p < GP; ++p) cs[p] = ns[p];
    }
    const float inv = 1.f / s;
    float ox = fmaf(acc.x, inv, bias[lane * 2]);
    float oy = fmaf(acc.y, inv, bias[lane * 2 + 1]);
    unsigned short hx = f2bf(ox), hy = f2bf(oy);
    short2 hv, lv;
    hv.x = (short)hx; hv.y = (short)hy;
    lv.x = (short)f2bf(ox - bf2f(hx)); lv.y = (short)f2bf(oy - bf2f(hy));
    *(short2*)(houth + (size_t)n * HID + lane * 2) = hv;
    *(short2*)(houtl + (size_t)n * HID + lane * 2) = lv;
}

// ---------------- edge decoder final: sigmoid(row . W2 + b2) ----------------
__global__ __launch_bounds__(256) void edec_out_k(
    const float* __restrict__ Ebuf, const float* __restrict__ W2,
    const float* __restrict__ b2, float* __restrict__ out, int Mc)
{
    int wid = (blockIdx.x * 256 + threadIdx.x) >> 6;
    int lane = threadIdx.x & 63;
    if (wid >= Mc) return;
    float2 v = *(const float2*)(Ebuf + (size_t)wid * HID + lane * 2);
    float2 w = *(const float2*)(W2 + lane * 2);
    float d = fmaf(v.x, w.x, v.y * w.y);
#pragma unroll
    for (int off = 32; off > 0; off >>= 1) d += __shfl_down(d, off, 64);
    if (lane == 0) out[wid] = 1.f / (1.f + expf(-(d + b2[0])));
}

extern "C" void kernel_launch(void* const* d_in, const int* in_sizes, int n_in,
                              void* d_out, int out_size, void* d_ws, size_t ws_size,
                              hipStream_t stream)
{
    const float* x    = (const float*)d_in[0];
    const float* emb  = (const float*)d_in[1];
    const int*   ei   = (const int*)d_in[2];
    const int*   bidx = (const int*)d_in[3];
    const int*   eim  = (const int*)d_in[4];
    const float* encW = (const float*)d_in[5];
    const float* encB = (const float*)d_in[6];
    const float* gWl  = (const float*)d_in[7];
    const float* gbl  = (const float*)d_in[8];
    const float* gWr  = (const float*)d_in[9];
    const float* gbr  = (const float*)d_in[10];
    const float* gatt = (const float*)d_in[11];
    const float* gb   = (const float*)d_in[12];
    const float* eW0  = (const float*)d_in[13];
    const float* eb0  = (const float*)d_in[14];
    const float* eW1  = (const float*)d_in[15];
    const float* eb1  = (const float*)d_in[16];
    const float* eW2  = (const float*)d_in[17];
    const float* eb2  = (const float*)d_in[18];
    const float* nW0  = (const float*)d_in[19];
    const float* nb0  = (const float*)d_in[20];
    const float* nW1  = (const float*)d_in[21];
    const float* nb1  = (const float*)d_in[22];
    const float* nW2  = (const float*)d_in[23];
    const float* nb2  = (const float*)d_in[24];
    float* out = (float*)d_out;

    char* wptr = (char*)d_ws;
    auto alloc = [&](size_t bytes) {
        char* p = wptr;
        wptr += (bytes + 255) & ~(size_t)255;
        return p;
    };
    // persistent split-bf16 h
    short* hh = (short*)alloc((size_t)NN * HID * 2);
    short* hl = (short*)alloc((size_t)NN * HID * 2);
    float* xl = (float*)alloc((size_t)NN * HID * 4);
    float* xr = (float*)alloc((size_t)NN * HID * 4);
    int* counts = (int*)alloc((size_t)NN * 4);
    int* offs   = (int*)alloc((size_t)(NN + 1) * 4);
    int* csrs   = (int*)alloc((size_t)NE * 4);
    // pre-converted weight planes [N][K]
    auto wplane = [&](int elems, short*& ph, short*& pl) {
        ph = (short*)alloc((size_t)elems * 2);
        pl = (short*)alloc((size_t)elems * 2);
    };
    short *encWt_h[3], *encWt_l[3];
    for (int i = 0; i < 3; ++i) wplane(HID * HID, encWt_h[i], encWt_l[i]);
    short *gWlt_h[3], *gWlt_l[3], *gWrt_h[3], *gWrt_l[3];
    for (int i = 0; i < 3; ++i) { wplane(HID * HID, gWlt_h[i], gWlt_l[i]);
                                  wplane(HID * HID, gWrt_h[i], gWrt_l[i]); }
    short *eW0t_h, *eW0t_l, *eW1t_h, *eW1t_l;
    wplane(2 * HID * HID, eW0t_h, eW0t_l);
    wplane(HID * HID, eW1t_h, eW1t_l);
    short *nW0t_h, *nW0t_l, *nW1t_h, *nW1t_l, *nW2t_h, *nW2t_l;
    wplane(HID * HID, nW0t_h, nW0t_l);
    wplane(HID * HID, nW1t_h, nW1t_l);
    wplane(HID * 64, nW2t_h, nW2t_l);
    // aliases: enc temps + edec/ndec buffers live in xl/xr (free at those times)
    short* t1h = (short*)xl;  short* t1l = t1h + (size_t)NN * HID;
    short* t2h = (short*)xr;  short* t2l = t2h + (size_t)NN * HID;
    short* Ebh = (short*)xl;  short* Ebl = Ebh + (size_t)50000 * HID;
    float* Eb2 = xr;                          // 50000*128 fp32
    short* nb0h = (short*)xl; short* nb0l = nb0h + (size_t)NBLOCK * HID;
    short* nb1h = nb0l + (size_t)NBLOCK * HID;
    short* nb1l = nb1h + (size_t)NBLOCK * HID;

    // ---- W pre-conversion (one batched launch) ----
    WDescs ds;
    int di = 0;
    for (int i = 0; i < 3; ++i)
        ds.d[di++] = {encW + (size_t)i * HID * HID, encWt_h[i], encWt_l[i], HID, HID};
    for (int i = 0; i < 3; ++i) {
        ds.d[di++] = {gWl + (size_t)i * HID * HID, gWlt_h[i], gWlt_l[i], HID, HID};
        ds.d[di++] = {gWr + (size_t)i * HID * HID, gWrt_h[i], gWrt_l[i], HID, HID};
    }
    ds.d[di++] = {eW0, eW0t_h, eW0t_l, 2 * HID, HID};
    ds.d[di++] = {eW1, eW1t_h, eW1t_l, HID, HID};
    ds.d[di++] = {nW0, nW0t_h, nW0t_l, HID, HID};
    ds.d[di++] = {nW1, nW1t_h, nW1t_l, HID, HID};
    ds.d[di++] = {nW2, nW2t_h, nW2t_l, HID, 64};
    wconv_k<<<14 * 128, 256, 0, stream>>>(ds);

    // ---- CSR build ----
    zero_k<<<(NN + 255) / 256, 256, 0, stream>>>(counts, NN);
    count_k<<<(NE + 255) / 256, 256, 0, stream>>>(ei, counts);
    scan_k<<<1, 256, 0, stream>>>(counts, offs);
    zero_k<<<(NN + 255) / 256, 256, 0, stream>>>(counts, NN);
    scatter_k<<<(NE + 255) / 256, 256, 0, stream>>>(ei, offs, counts, csrs);

    const int gN = (NN + 63) / 64;
    // ---- encoder MLP: fp32 concat in, split out ----
    gemm2_k<128, true, false, true><<<gN, 256, 0, stream>>>(
        x, nullptr, 64, 64, emb, nullptr, 64, nullptr, nullptr, 128,
        encWt_h[0], encWt_l[0], encB, nullptr, t1h, t1l, NN);
    gemm2_k<128, true, true, true><<<gN, 256, 0, stream>>>(
        t1h, t1l, 128, 128, nullptr, nullptr, 0, nullptr, nullptr, 128,
        encWt_h[1], encWt_l[1], encB + 128, nullptr, t2h, t2l, NN);
    gemm2_k<128, false, true, true><<<gN, 256, 0, stream>>>(
        t2h, t2l, 128, 128, nullptr, nullptr, 0, nullptr, nullptr, 128,
        encWt_h[2], encWt_l[2], encB + 256, nullptr, hh, hl, NN);

    // ---- 3 GATv2 layers ----
    const int gGAT = (NN * 64 + 255) / 256;
    for (int l = 0; l < 3; ++l) {
        gemm2_k<128, false, true, false><<<gN, 256, 0, stream>>>(
            hh, hl, 128, 128, nullptr, nullptr, 0, nullptr, nullptr, 128,
            gWlt_h[l], gWlt_l[l], gbl + (size_t)l * HID, xl, nullptr, nullptr, NN);
        gemm2_k<128, false, true, false><<<gN, 256, 0, stream>>>(
            hh, hl, 128, 128, nullptr, nullptr, 0, nullptr, nullptr, 128,
            gWrt_h[l], gWrt_l[l], gbr + (size_t)l * HID, xr, nullptr, nullptr, NN);
        gat_wave_k<<<gGAT, 256, 0, stream>>>(xl, xr, gatt + (size_t)l * HID,
                                             offs, csrs, gb + (size_t)l * HID, hh, hl);
    }

    // ---- edge decoder, 4 chunks of 50000 rows ----
    for (int c = 0; c < 4; ++c) {
        const int Mc = 50000;
        const int* i0 = eim + (size_t)c * Mc;
        const int* i1 = eim + NIMAG + (size_t)c * Mc;
        gemm2_k<128, true, true, true><<<(Mc + 63) / 64, 256, 0, stream>>>(
            hh, hl, 128, 128, hh, hl, 128, i0, i1, 256,
            eW0t_h, eW0t_l, eb0, nullptr, Ebh, Ebl, Mc);
        gemm2_k<128, true, true, false><<<(Mc + 63) / 64, 256, 0, stream>>>(
            Ebh, Ebl, 128, 128, nullptr, nullptr, 0, nullptr, nullptr, 128,
            eW1t_h, eW1t_l, eb1, Eb2, nullptr, nullptr, Mc);
        edec_out_k<<<(Mc + 3) / 4, 256, 0, stream>>>(Eb2, eW2, eb2,
                                                     out + (size_t)NBLOCK * 64 + (size_t)c * Mc, Mc);
    }

    // ---- node decoder ----
    const int gB = (NBLOCK + 63) / 64;
    gemm2_k<128, true, true, true><<<gB, 256, 0, stream>>>(
        hh, hl, 128, 128, nullptr, nullptr, 0, bidx, nullptr, 128,
        nW0t_h, nW0t_l, nb0, nullptr, nb0h, nb0l, NBLOCK);
    gemm2_k<128, true, true, true><<<gB, 256, 0, stream>>>(
        nb0h, nb0l, 128, 128, nullptr, nullptr, 0, nullptr, nullptr, 128,
        nW1t_h, nW1t_l, nb1, nullptr, nb1h, nb1l, NBLOCK);
    gemm2_k<64, false, true, false><<<gB, 256, 0, stream>>>(
        nb1h, nb1l, 128, 128, nullptr, nullptr, 0, nullptr, nullptr, 128,
        nW2t_h, nW2t_l, nb2, out, nullptr, nullptr, NBLOCK);
}

// Round 6
// 1021.219 us; speedup vs baseline: 1.9575x; 1.0758x over previous
//
#include <hip/hip_runtime.h>
#include <hip/hip_bf16.h>
#include <math.h>

#define NN 50000
#define NE 1000000
#define NIMAG 200000
#define NBLOCK 5000
#define HID 128

typedef __attribute__((ext_vector_type(8))) short bf16x8;
typedef __attribute__((ext_vector_type(4))) float f32x4;

__device__ inline unsigned short f2bf(float x) {
    unsigned u = __float_as_uint(x);
    unsigned r = u + 0x7fff + ((u >> 16) & 1);   // RNE
    return (unsigned short)(r >> 16);
}
__device__ inline float bf2f(unsigned short b) {
    return __uint_as_float((unsigned)b << 16);
}

// ---------------- zero fill ----------------
__global__ void zero_k(int* __restrict__ p, int n) {
    int i = blockIdx.x * 256 + threadIdx.x;
    if (i < n) p[i] = 0;
}

// ---------------- CSR build ----------------
__global__ void count_k(const int* __restrict__ ei, int* __restrict__ counts) {
    int e = blockIdx.x * 256 + threadIdx.x;
    if (e < NE) atomicAdd(&counts[ei[NE + e]], 1);
}

__global__ void scan_k(const int* __restrict__ counts, int* __restrict__ offs) {
    __shared__ int ssum[256];
    int t = threadIdx.x;
    const int chunk = (NN + 255) / 256;
    int beg = t * chunk, end = min(beg + chunk, NN);
    int s = 0;
    for (int i = beg; i < end; ++i) s += counts[i];
    ssum[t] = s;
    __syncthreads();
    for (int off = 1; off < 256; off <<= 1) {
        int v = (t >= off) ? ssum[t - off] : 0;
        __syncthreads();
        if (t >= off) ssum[t] += v;
        __syncthreads();
    }
    int run = ssum[t] - s;
    for (int i = beg; i < end; ++i) { offs[i] = run; run += counts[i]; }
    if (t == 255) offs[NN] = run;
}

__global__ void scatter_k(const int* __restrict__ ei, const int* __restrict__ offs,
                          int* __restrict__ cursor, int* __restrict__ csr_src) {
    int e = blockIdx.x * 256 + threadIdx.x;
    if (e < NE) {
        int d = ei[NE + e];
        int pos = offs[d] + atomicAdd(&cursor[d], 1);
        csr_src[pos] = ei[e];
    }
}

// ---------------- batched W pre-convert: fp32 [K][N] -> split-bf16 [N][K] ----
struct WDesc { const float* src; short* dh; short* dl; int K; int N; };
struct WDescs { WDesc d[14]; };
__global__ __launch_bounds__(256) void wconv_k(WDescs ds) {
    int m = blockIdx.x >> 7;
    int i = (blockIdx.x & 127) * 256 + threadIdx.x;
    WDesc w = ds.d[m];
    int tot = w.K * w.N;
    if (i < tot) {
        int k = i / w.N, n = i - k * w.N;
        float v = w.src[i];
        unsigned short h = f2bf(v);
        w.dh[(size_t)n * w.K + k] = (short)h;
        w.dl[(size_t)n * w.K + k] = (short)f2bf(v - bf2f(h));
    }
}

// ---------------- split-bf16 MFMA GEMM, W-in-registers, A-only LDS ----------
// C = act(A @ W + bias). W planes pre-transposed [N][K]. KC=128 per iteration:
// one barrier per chunk; W fragments live in VGPRs (loaded straight from L2).
template <int N, bool RELU, bool INSPLIT, bool OUTSPLIT>
__global__ __launch_bounds__(256, 3) void gemm3_k(
    const void* __restrict__ A0h, const void* __restrict__ A0l, int ld0, int K0,
    const void* __restrict__ A1h, const void* __restrict__ A1l, int ld1,
    const int* __restrict__ idx0, const int* __restrict__ idx1,
    int K,
    const short* __restrict__ Wth, const short* __restrict__ Wtl,
    const float* __restrict__ bias,
    float* __restrict__ Cf, short* __restrict__ Ch, short* __restrict__ Cl,
    int M)
{
    constexpr int KC = 128;
    constexpr int NTW = N / 64;      // n-tiles (16 wide) per wave
    constexpr int LDP = 136;         // shorts; 272B row stride, 16B-aligned
    __shared__ __align__(16) short As_h[64][LDP];
    __shared__ __align__(16) short As_l[64][LDP];

    const int t = threadIdx.x;
    const int w = t >> 6, lane = t & 63;
    const int llo = lane & 15, lhi = lane >> 4;
    const int row0 = blockIdx.x * 64;

    f32x4 acc[4][NTW];
#pragma unroll
    for (int mt = 0; mt < 4; ++mt)
#pragma unroll
        for (int nt = 0; nt < NTW; ++nt) {
            f32x4 z = {0.f, 0.f, 0.f, 0.f};
            acc[mt][nt] = z;
        }

    for (int kb = 0; kb < K; kb += KC) {
        // ---- W fragments -> registers (no LDS, no barrier dependency) ----
        bf16x8 wf_h[NTW][4], wf_l[NTW][4];
#pragma unroll
        for (int nt = 0; nt < NTW; ++nt) {
#pragma unroll
            for (int ks = 0; ks < 4; ++ks) {
                int n = (w * NTW + nt) * 16 + llo;
                size_t off = (size_t)n * K + kb + ks * 32 + lhi * 8;
                wf_h[nt][ks] = *(const bf16x8*)(Wth + off);
                wf_l[nt][ks] = *(const bf16x8*)(Wtl + off);
            }
        }
        if (kb != 0) __syncthreads();   // LDS WAR guard between chunks
        // ---- stage A chunk [64 rows x 128 k] into LDS ----
        if (INSPLIT) {
#pragma unroll
            for (int j = 0; j < 4; ++j) {
                int u = j * 256 + t;
                int lr = u >> 4;          // row 0..63
                int q  = u & 15;          // octet of shorts
                int gr = row0 + lr; if (gr >= M) gr = M - 1;
                int kk = kb + q * 8;
                const short *bh, *bl; int ld, lk; const int* idx;
                if (kk < K0) { bh = (const short*)A0h; bl = (const short*)A0l;
                               ld = ld0; lk = kk; idx = idx0; }
                else         { bh = (const short*)A1h; bl = (const short*)A1l;
                               ld = ld1; lk = kk - K0; idx = idx1; }
                int sr = idx ? idx[gr] : gr;
                size_t off = (size_t)sr * ld + lk;
                *(bf16x8*)&As_h[lr][q * 8] = *(const bf16x8*)(bh + off);
                *(bf16x8*)&As_l[lr][q * 8] = *(const bf16x8*)(bl + off);
            }
        } else {
            // fp32 A (encoder layer 0 only): convert during staging
#pragma unroll
            for (int j = 0; j < 8; ++j) {
                int u = j * 256 + t;
                int lr = u >> 5;
                int q  = u & 31;          // float4 index
                int gr = row0 + lr; if (gr >= M) gr = M - 1;
                int kk = kb + q * 4;
                const float* src; int ld, lk; const int* idx;
                if (kk < K0) { src = (const float*)A0h; ld = ld0; lk = kk; idx = idx0; }
                else         { src = (const float*)A1h; ld = ld1; lk = kk - K0; idx = idx1; }
                int sr = idx ? idx[gr] : gr;
                float4 v = *(const float4*)(src + (size_t)sr * ld + lk);
                float xs[4] = {v.x, v.y, v.z, v.w};
                short4 h4, l4;
                short* hp = (short*)&h4; short* lp = (short*)&l4;
#pragma unroll
                for (int i = 0; i < 4; ++i) {
                    unsigned short hb = f2bf(xs[i]);
                    hp[i] = (short)hb;
                    lp[i] = (short)f2bf(xs[i] - bf2f(hb));
                }
                *(short4*)&As_h[lr][q * 4] = h4;
                *(short4*)&As_l[lr][q * 4] = l4;
            }
        }
        __syncthreads();
        // ---- MFMA over the whole 128-k chunk ----
#pragma unroll
        for (int ks = 0; ks < 4; ++ks) {
            bf16x8 ba_h[4], ba_l[4];
#pragma unroll
            for (int mt = 0; mt < 4; ++mt) {
                int m = mt * 16 + llo;
                ba_h[mt] = *(const bf16x8*)&As_h[m][ks * 32 + lhi * 8];
                ba_l[mt] = *(const bf16x8*)&As_l[m][ks * 32 + lhi * 8];
            }
#pragma unroll
            for (int mt = 0; mt < 4; ++mt)
#pragma unroll
                for (int nt = 0; nt < NTW; ++nt) {
                    acc[mt][nt] = __builtin_amdgcn_mfma_f32_16x16x32_bf16(
                        wf_h[nt][ks], ba_h[mt], acc[mt][nt], 0, 0, 0);
                    acc[mt][nt] = __builtin_amdgcn_mfma_f32_16x16x32_bf16(
                        wf_h[nt][ks], ba_l[mt], acc[mt][nt], 0, 0, 0);
                    acc[mt][nt] = __builtin_amdgcn_mfma_f32_16x16x32_bf16(
                        wf_l[nt][ks], ba_h[mt], acc[mt][nt], 0, 0, 0);
                }
        }
    }
    // ---- epilogue ----
#pragma unroll
    for (int mt = 0; mt < 4; ++mt) {
        int r = row0 + mt * 16 + llo;
        if (r < M) {
#pragma unroll
            for (int nt = 0; nt < NTW; ++nt) {
                int c0 = (w * NTW + nt) * 16 + lhi * 4;
                float v[4];
#pragma unroll
                for (int u = 0; u < 4; ++u) {
                    float z = acc[mt][nt][u] + bias[c0 + u];
                    if (RELU) z = z > 0.f ? z : 0.f;
                    v[u] = z;
                }
                if (OUTSPLIT) {
                    short4 h4, l4;
                    short* hp = (short*)&h4; short* lp = (short*)&l4;
#pragma unroll
                    for (int u = 0; u < 4; ++u) {
                        unsigned short hb = f2bf(v[u]);
                        hp[u] = (short)hb;
                        lp[u] = (short)f2bf(v[u] - bf2f(hb));
                    }
                    *(short4*)(Ch + (size_t)r * N + c0) = h4;
                    *(short4*)(Cl + (size_t)r * N + c0) = l4;
                } else {
                    float4 o = {v[0], v[1], v[2], v[3]};
                    *(float4*)(Cf + (size_t)r * N + c0) = o;
                }
            }
        }
    }
}

// ---------------- GATv2: half-wave per edge (2 edges/wave), online softmax ----
// Lanes 0-31 process even slots, 32-63 odd slots; lane owns 4 features.
// 5-stage ds_swizzle butterfly within 32 lanes; halves merged at the end.
#define GPH 4
__global__ __launch_bounds__(256) void gat_half_k(
    const float* __restrict__ xl, const float* __restrict__ xr,
    const float* __restrict__ att, const int* __restrict__ offs,
    const int* __restrict__ csrs, const float* __restrict__ bias,
    short* __restrict__ houth, short* __restrict__ houtl)
{
    const int wid = (blockIdx.x * 256 + threadIdx.x) >> 6;
    const int lane = threadIdx.x & 63;
    const int h = lane >> 5, sub = lane & 31;
    if (wid >= NN) return;
    const int n = wid;
    const int beg = offs[n];
    const int total = (offs[n + 1] - beg) + 1;   // + self loop at slot 0

    const float4 attv = *(const float4*)(att + sub * 4);
    const float4 xrv  = *(const float4*)(xr + (size_t)n * HID + sub * 4);

    float m = -INFINITY, s = 0.f;
    float4 acc = {0.f, 0.f, 0.f, 0.f};

    int cs[GPH];
#pragma unroll
    for (int p = 0; p < GPH; ++p) {
        int slot = p * 2 + h;
        cs[p] = (slot < total) ? ((slot == 0) ? n : csrs[beg + slot - 1]) : 0;
    }

    for (int base = 0; base < total; base += 2 * GPH) {
        float4 r[GPH];
        bool val[GPH];
#pragma unroll
        for (int p = 0; p < GPH; ++p) {
            int slot = base + p * 2 + h;
            val[p] = slot < total;
            if (val[p]) r[p] = *(const float4*)(xl + (size_t)cs[p] * HID + sub * 4);
        }
        // prefetch next group's indices
        int ns[GPH];
#pragma unroll
        for (int p = 0; p < GPH; ++p) {
            int nslot = base + 2 * GPH + p * 2 + h;
            ns[p] = (nslot < total) ? csrs[beg + nslot - 1] : 0;
        }
        float e[GPH];
#pragma unroll
        for (int p = 0; p < GPH; ++p) {
            if (val[p]) {
                float v = 0.f;
#pragma unroll
                for (int j = 0; j < 4; ++j) {
                    float mj = ((const float*)&r[p])[j] + ((const float*)&xrv)[j];
                    mj = mj > 0.f ? mj : 0.2f * mj;
                    v = fmaf(mj, ((const float*)&attv)[j], v);
                }
                v += __int_as_float(__builtin_amdgcn_ds_swizzle(__float_as_int(v), 0x041F));
                v += __int_as_float(__builtin_amdgcn_ds_swizzle(__float_as_int(v), 0x081F));
                v += __int_as_float(__builtin_amdgcn_ds_swizzle(__float_as_int(v), 0x101F));
                v += __int_as_float(__builtin_amdgcn_ds_swizzle(__float_as_int(v), 0x201F));
                v += __int_as_float(__builtin_amdgcn_ds_swizzle(__float_as_int(v), 0x401F));
                e[p] = v;
            }
        }
#pragma unroll
        for (int p = 0; p < GPH; ++p) {
            if (val[p]) {
                float mnew = fmaxf(m, e[p]);
                float sc = __expf(m - mnew);       // exp(-inf)=0 on first edge
                float wj = __expf(e[p] - mnew);
                s = fmaf(s, sc, wj);
                acc.x = fmaf(acc.x, sc, wj * r[p].x);
                acc.y = fmaf(acc.y, sc, wj * r[p].y);
                acc.z = fmaf(acc.z, sc, wj * r[p].z);
                acc.w = fmaf(acc.w, sc, wj * r[p].w);
                m = mnew;
            }
        }
#pragma unroll
        for (int p = 0; p < GPH; ++p) cs[p] = ns[p];
    }
    // ---- merge the two half-wave online states ----
    float om = __shfl_xor(m, 32, 64);
    float os = __shfl_xor(s, 32, 64);
    float4 oacc;
    oacc.x = __shfl_xor(acc.x, 32, 64);
    oacc.y = __shfl_xor(acc.y, 32, 64);
    oacc.z = __shfl_xor(acc.z, 32, 64);
    oacc.w = __shfl_xor(acc.w, 32, 64);
    float M = fmaxf(m, om);
    float a = __expf(m - M), b = __expf(om - M);
    float st = s * a + os * b;
    float inv = 1.f / st;
    float o0 = (acc.x * a + oacc.x * b) * inv + bias[sub * 4 + 0];
    float o1 = (acc.y * a + oacc.y * b) * inv + bias[sub * 4 + 1];
    float o2 = (acc.z * a + oacc.z * b) * inv + bias[sub * 4 + 2];
    float o3 = (acc.w * a + oacc.w * b) * inv + bias[sub * 4 + 3];
    if (h == 0) {
        float ov[4] = {o0, o1, o2, o3};
        short4 h4, l4;
        short* hp = (short*)&h4; short* lp = (short*)&l4;
#pragma unroll
        for (int u = 0; u < 4; ++u) {
            unsigned short hb = f2bf(ov[u]);
            hp[u] = (short)hb;
            lp[u] = (short)f2bf(ov[u] - bf2f(hb));
        }
        *(short4*)(houth + (size_t)n * HID + sub * 4) = h4;
        *(short4*)(houtl + (size_t)n * HID + sub * 4) = l4;
    }
}

// ---------------- edge decoder final: sigmoid(row . W2 + b2) ----------------
__global__ __launch_bounds__(256) void edec_out_k(
    const float* __restrict__ Ebuf, const float* __restrict__ W2,
    const float* __restrict__ b2, float* __restrict__ out, int Mc)
{
    int wid = (blockIdx.x * 256 + threadIdx.x) >> 6;
    int lane = threadIdx.x & 63;
    if (wid >= Mc) return;
    float2 v = *(const float2*)(Ebuf + (size_t)wid * HID + lane * 2);
    float2 w = *(const float2*)(W2 + lane * 2);
    float d = fmaf(v.x, w.x, v.y * w.y);
#pragma unroll
    for (int off = 32; off > 0; off >>= 1) d += __shfl_down(d, off, 64);
    if (lane == 0) out[wid] = 1.f / (1.f + expf(-(d + b2[0])));
}

extern "C" void kernel_launch(void* const* d_in, const int* in_sizes, int n_in,
                              void* d_out, int out_size, void* d_ws, size_t ws_size,
                              hipStream_t stream)
{
    const float* x    = (const float*)d_in[0];
    const float* emb  = (const float*)d_in[1];
    const int*   ei   = (const int*)d_in[2];
    const int*   bidx = (const int*)d_in[3];
    const int*   eim  = (const int*)d_in[4];
    const float* encW = (const float*)d_in[5];
    const float* encB = (const float*)d_in[6];
    const float* gWl  = (const float*)d_in[7];
    const float* gbl  = (const float*)d_in[8];
    const float* gWr  = (const float*)d_in[9];
    const float* gbr  = (const float*)d_in[10];
    const float* gatt = (const float*)d_in[11];
    const float* gb   = (const float*)d_in[12];
    const float* eW0  = (const float*)d_in[13];
    const float* eb0  = (const float*)d_in[14];
    const float* eW1  = (const float*)d_in[15];
    const float* eb1  = (const float*)d_in[16];
    const float* eW2  = (const float*)d_in[17];
    const float* eb2  = (const float*)d_in[18];
    const float* nW0  = (const float*)d_in[19];
    const float* nb0  = (const float*)d_in[20];
    const float* nW1  = (const float*)d_in[21];
    const float* nb1  = (const float*)d_in[22];
    const float* nW2  = (const float*)d_in[23];
    const float* nb2  = (const float*)d_in[24];
    float* out = (float*)d_out;

    char* wptr = (char*)d_ws;
    auto alloc = [&](size_t bytes) {
        char* p = wptr;
        wptr += (bytes + 255) & ~(size_t)255;
        return p;
    };
    short* hh = (short*)alloc((size_t)NN * HID * 2);
    short* hl = (short*)alloc((size_t)NN * HID * 2);
    float* xl = (float*)alloc((size_t)NN * HID * 4);
    float* xr = (float*)alloc((size_t)NN * HID * 4);
    int* counts = (int*)alloc((size_t)NN * 4);
    int* offs   = (int*)alloc((size_t)(NN + 1) * 4);
    int* csrs   = (int*)alloc((size_t)NE * 4);
    auto wplane = [&](int elems, short*& ph, short*& pl) {
        ph = (short*)alloc((size_t)elems * 2);
        pl = (short*)alloc((size_t)elems * 2);
    };
    short *encWt_h[3], *encWt_l[3];
    for (int i = 0; i < 3; ++i) wplane(HID * HID, encWt_h[i], encWt_l[i]);
    short *gWlt_h[3], *gWlt_l[3], *gWrt_h[3], *gWrt_l[3];
    for (int i = 0; i < 3; ++i) { wplane(HID * HID, gWlt_h[i], gWlt_l[i]);
                                  wplane(HID * HID, gWrt_h[i], gWrt_l[i]); }
    short *eW0t_h, *eW0t_l, *eW1t_h, *eW1t_l;
    wplane(2 * HID * HID, eW0t_h, eW0t_l);
    wplane(HID * HID, eW1t_h, eW1t_l);
    short *nW0t_h, *nW0t_l, *nW1t_h, *nW1t_l, *nW2t_h, *nW2t_l;
    wplane(HID * HID, nW0t_h, nW0t_l);
    wplane(HID * HID, nW1t_h, nW1t_l);
    wplane(HID * 64, nW2t_h, nW2t_l);
    // aliases (xl/xr free during decode phases)
    short* t1h = (short*)xl;  short* t1l = t1h + (size_t)NN * HID;
    short* t2h = (short*)xr;  short* t2l = t2h + (size_t)NN * HID;
    short* Ebh = (short*)xl;  short* Ebl = Ebh + (size_t)50000 * HID;
    float* Eb2 = xr;
    short* nb0h = (short*)xl; short* nb0l = nb0h + (size_t)NBLOCK * HID;
    short* nb1h = nb0l + (size_t)NBLOCK * HID;
    short* nb1l = nb1h + (size_t)NBLOCK * HID;

    // ---- W pre-conversion ----
    WDescs ds;
    int di = 0;
    for (int i = 0; i < 3; ++i)
        ds.d[di++] = {encW + (size_t)i * HID * HID, encWt_h[i], encWt_l[i], HID, HID};
    for (int i = 0; i < 3; ++i) {
        ds.d[di++] = {gWl + (size_t)i * HID * HID, gWlt_h[i], gWlt_l[i], HID, HID};
        ds.d[di++] = {gWr + (size_t)i * HID * HID, gWrt_h[i], gWrt_l[i], HID, HID};
    }
    ds.d[di++] = {eW0, eW0t_h, eW0t_l, 2 * HID, HID};
    ds.d[di++] = {eW1, eW1t_h, eW1t_l, HID, HID};
    ds.d[di++] = {nW0, nW0t_h, nW0t_l, HID, HID};
    ds.d[di++] = {nW1, nW1t_h, nW1t_l, HID, HID};
    ds.d[di++] = {nW2, nW2t_h, nW2t_l, HID, 64};
    wconv_k<<<14 * 128, 256, 0, stream>>>(ds);

    // ---- CSR build ----
    zero_k<<<(NN + 255) / 256, 256, 0, stream>>>(counts, NN);
    count_k<<<(NE + 255) / 256, 256, 0, stream>>>(ei, counts);
    scan_k<<<1, 256, 0, stream>>>(counts, offs);
    zero_k<<<(NN + 255) / 256, 256, 0, stream>>>(counts, NN);
    scatter_k<<<(NE + 255) / 256, 256, 0, stream>>>(ei, offs, counts, csrs);

    const int gN = (NN + 63) / 64;
    // ---- encoder MLP ----
    gemm3_k<128, true, false, true><<<gN, 256, 0, stream>>>(
        x, nullptr, 64, 64, emb, nullptr, 64, nullptr, nullptr, 128,
        encWt_h[0], encWt_l[0], encB, nullptr, t1h, t1l, NN);
    gemm3_k<128, true, true, true><<<gN, 256, 0, stream>>>(
        t1h, t1l, 128, 128, nullptr, nullptr, 0, nullptr, nullptr, 128,
        encWt_h[1], encWt_l[1], encB + 128, nullptr, t2h, t2l, NN);
    gemm3_k<128, false, true, true><<<gN, 256, 0, stream>>>(
        t2h, t2l, 128, 128, nullptr, nullptr, 0, nullptr, nullptr, 128,
        encWt_h[2], encWt_l[2], encB + 256, nullptr, hh, hl, NN);

    // ---- 3 GATv2 layers ----
    const int gGAT = (NN * 64 + 255) / 256;
    for (int l = 0; l < 3; ++l) {
        gemm3_k<128, false, true, false><<<gN, 256, 0, stream>>>(
            hh, hl, 128, 128, nullptr, nullptr, 0, nullptr, nullptr, 128,
            gWlt_h[l], gWlt_l[l], gbl + (size_t)l * HID, xl, nullptr, nullptr, NN);
        gemm3_k<128, false, true, false><<<gN, 256, 0, stream>>>(
            hh, hl, 128, 128, nullptr, nullptr, 0, nullptr, nullptr, 128,
            gWrt_h[l], gWrt_l[l], gbr + (size_t)l * HID, xr, nullptr, nullptr, NN);
        gat_half_k<<<gGAT, 256, 0, stream>>>(xl, xr, gatt + (size_t)l * HID,
                                             offs, csrs, gb + (size_t)l * HID, hh, hl);
    }

    // ---- edge decoder, 4 chunks of 50000 rows ----
    for (int c = 0; c < 4; ++c) {
        const int Mc = 50000;
        const int* i0 = eim + (size_t)c * Mc;
        const int* i1 = eim + NIMAG + (size_t)c * Mc;
        gemm3_k<128, true, true, true><<<(Mc + 63) / 64, 256, 0, stream>>>(
            hh, hl, 128, 128, hh, hl, 128, i0, i1, 256,
            eW0t_h, eW0t_l, eb0, nullptr, Ebh, Ebl, Mc);
        gemm3_k<128, true, true, false><<<(Mc + 63) / 64, 256, 0, stream>>>(
            Ebh, Ebl, 128, 128, nullptr, nullptr, 0, nullptr, nullptr, 128,
            eW1t_h, eW1t_l, eb1, Eb2, nullptr, nullptr, Mc);
        edec_out_k<<<(Mc + 3) / 4, 256, 0, stream>>>(Eb2, eW2, eb2,
                                                     out + (size_t)NBLOCK * 64 + (size_t)c * Mc, Mc);
    }

    // ---- node decoder ----
    const int gB = (NBLOCK + 63) / 64;
    gemm3_k<128, true, true, true><<<gB, 256, 0, stream>>>(
        hh, hl, 128, 128, nullptr, nullptr, 0, bidx, nullptr, 128,
        nW0t_h, nW0t_l, nb0, nullptr, nb0h, nb0l, NBLOCK);
    gemm3_k<128, true, true, true><<<gB, 256, 0, stream>>>(
        nb0h, nb0l, 128, 128, nullptr, nullptr, 0, nullptr, nullptr, 128,
        nW1t_h, nW1t_l, nb1, nullptr, nb1h, nb1l, NBLOCK);
    gemm3_k<64, false, true, false><<<gB, 256, 0, stream>>>(
        nb1h, nb1l, 128, 128, nullptr, nullptr, 0, nullptr, nullptr, 128,
        nW2t_h, nW2t_l, nb2, out, nullptr, nullptr, NBLOCK);
}

// Round 7
// 813.134 us; speedup vs baseline: 2.4585x; 1.2559x over previous
//
#include <hip/hip_runtime.h>
#include <hip/hip_bf16.h>
#include <math.h>

#define NN 50000
#define NE 1000000
#define NIMAG 200000
#define NBLOCK 5000
#define HID 128
#define NB_SCAN ((NN + 255) / 256)   // 196

typedef __attribute__((ext_vector_type(8))) short bf16x8;
typedef __attribute__((ext_vector_type(4))) float f32x4;

__device__ inline unsigned short f2bf(float x) {
    unsigned u = __float_as_uint(x);
    unsigned r = u + 0x7fff + ((u >> 16) & 1);   // RNE
    return (unsigned short)(r >> 16);
}
__device__ inline float bf2f(unsigned short b) {
    return __uint_as_float((unsigned)b << 16);
}

// ---------------- zero fill ----------------
__global__ void zero_k(int* __restrict__ p, int n) {
    int i = blockIdx.x * 256 + threadIdx.x;
    if (i < n) p[i] = 0;
}

// ---------------- CSR build ----------------
__global__ void count_k(const int* __restrict__ ei, int* __restrict__ counts) {
    int e = blockIdx.x * 256 + threadIdx.x;
    if (e < NE) atomicAdd(&counts[ei[NE + e]], 1);
}

// hierarchical exclusive scan of counts[NN] -> offs[NN+1]
__global__ void scan1_k(const int* __restrict__ counts, int* __restrict__ offs,
                        int* __restrict__ bsum) {
    __shared__ int sh[256];
    int t = threadIdx.x;
    int i = blockIdx.x * 256 + t;
    int v = (i < NN) ? counts[i] : 0;
    sh[t] = v;
    __syncthreads();
    for (int off = 1; off < 256; off <<= 1) {
        int a = (t >= off) ? sh[t - off] : 0;
        __syncthreads();
        sh[t] += a;
        __syncthreads();
    }
    if (i < NN) offs[i] = sh[t] - v;        // block-local exclusive
    if (t == 255) bsum[blockIdx.x] = sh[255];
}

__global__ void scan2_k(const int* __restrict__ bsum, int* __restrict__ bscan,
                        int* __restrict__ offs) {
    __shared__ int sh[256];
    int t = threadIdx.x;
    int v = (t < NB_SCAN) ? bsum[t] : 0;
    sh[t] = v;
    __syncthreads();
    for (int off = 1; off < 256; off <<= 1) {
        int a = (t >= off) ? sh[t - off] : 0;
        __syncthreads();
        sh[t] += a;
        __syncthreads();
    }
    if (t < NB_SCAN) bscan[t] = sh[t] - v;
    if (t == NB_SCAN - 1) offs[NN] = sh[t];
}

__global__ void scan3_k(int* __restrict__ offs, const int* __restrict__ bscan) {
    int i = blockIdx.x * 256 + threadIdx.x;
    if (i < NN) offs[i] += bscan[blockIdx.x];
}

// scatter using counts as a decrementing cursor (order within segment arbitrary)
__global__ void scatter_k(const int* __restrict__ ei, const int* __restrict__ offs,
                          int* __restrict__ counts, int* __restrict__ csr_src) {
    int e = blockIdx.x * 256 + threadIdx.x;
    if (e < NE) {
        int d = ei[NE + e];
        int pos = offs[d] + atomicSub(&counts[d], 1) - 1;
        csr_src[pos] = ei[e];
    }
}

// ---------------- batched W pre-convert: fp32 [K][N] -> split-bf16 [N][K] ----
struct WDesc { const float* src; short* dh; short* dl; int K; int N; };
struct WDescs { WDesc d[14]; };
__global__ __launch_bounds__(256) void wconv_k(WDescs ds) {
    int m = blockIdx.x >> 7;
    int i = (blockIdx.x & 127) * 256 + threadIdx.x;
    WDesc w = ds.d[m];
    int tot = w.K * w.N;
    if (i < tot) {
        int k = i / w.N, n = i - k * w.N;
        float v = w.src[i];
        unsigned short h = f2bf(v);
        w.dh[(size_t)n * w.K + k] = (short)h;
        w.dl[(size_t)n * w.K + k] = (short)f2bf(v - bf2f(h));
    }
}

// concat gbl/gbr -> [3][256]
__global__ void biascat_k(const float* __restrict__ bl, const float* __restrict__ br,
                          float* __restrict__ o) {
    int l = blockIdx.x, t = threadIdx.x;
    o[l * 256 + t] = (t < 128) ? bl[l * 128 + t] : br[l * 128 + (t - 128)];
}

// ---------------- split-bf16 MFMA GEMM, W-in-registers, A-only LDS ----------
// FDOT: fuse out[r] = sigmoid(act_row . W2 + b2) instead of storing C.
template <int N, bool RELU, bool INSPLIT, bool OUTSPLIT, bool FDOT, int MINW>
__global__ __launch_bounds__(256, MINW) void gemm3_k(
    const void* __restrict__ A0h, const void* __restrict__ A0l, int ld0, int K0,
    const void* __restrict__ A1h, const void* __restrict__ A1l, int ld1,
    const int* __restrict__ idx0, const int* __restrict__ idx1,
    int K,
    const short* __restrict__ Wth, const short* __restrict__ Wtl,
    const float* __restrict__ bias,
    float* __restrict__ Cf, short* __restrict__ Ch, short* __restrict__ Cl,
    const float* __restrict__ W2p, const float* __restrict__ b2p,
    float* __restrict__ outd,
    int M)
{
    constexpr int KC = 128;
    constexpr int NTW = N / 64;
    constexpr int LDP = 136;
    __shared__ __align__(16) short As_h[64][LDP];
    __shared__ __align__(16) short As_l[64][LDP];

    const int t = threadIdx.x;
    const int w = t >> 6, lane = t & 63;
    const int llo = lane & 15, lhi = lane >> 4;
    const int row0 = blockIdx.x * 64;

    f32x4 acc[4][NTW];
#pragma unroll
    for (int mt = 0; mt < 4; ++mt)
#pragma unroll
        for (int nt = 0; nt < NTW; ++nt) {
            f32x4 z = {0.f, 0.f, 0.f, 0.f};
            acc[mt][nt] = z;
        }

    for (int kb = 0; kb < K; kb += KC) {
        bf16x8 wf_h[NTW][4], wf_l[NTW][4];
#pragma unroll
        for (int nt = 0; nt < NTW; ++nt) {
#pragma unroll
            for (int ks = 0; ks < 4; ++ks) {
                int n = (w * NTW + nt) * 16 + llo;
                size_t off = (size_t)n * K + kb + ks * 32 + lhi * 8;
                wf_h[nt][ks] = *(const bf16x8*)(Wth + off);
                wf_l[nt][ks] = *(const bf16x8*)(Wtl + off);
            }
        }
        if (kb != 0) __syncthreads();
        if (INSPLIT) {
#pragma unroll
            for (int j = 0; j < 4; ++j) {
                int u = j * 256 + t;
                int lr = u >> 4;
                int q  = u & 15;
                int gr = row0 + lr; if (gr >= M) gr = M - 1;
                int kk = kb + q * 8;
                const short *bh, *bl; int ld, lk; const int* idx;
                if (kk < K0) { bh = (const short*)A0h; bl = (const short*)A0l;
                               ld = ld0; lk = kk; idx = idx0; }
                else         { bh = (const short*)A1h; bl = (const short*)A1l;
                               ld = ld1; lk = kk - K0; idx = idx1; }
                int sr = idx ? idx[gr] : gr;
                size_t off = (size_t)sr * ld + lk;
                *(bf16x8*)&As_h[lr][q * 8] = *(const bf16x8*)(bh + off);
                *(bf16x8*)&As_l[lr][q * 8] = *(const bf16x8*)(bl + off);
            }
        } else {
#pragma unroll
            for (int j = 0; j < 8; ++j) {
                int u = j * 256 + t;
                int lr = u >> 5;
                int q  = u & 31;
                int gr = row0 + lr; if (gr >= M) gr = M - 1;
                int kk = kb + q * 4;
                const float* src; int ld, lk; const int* idx;
                if (kk < K0) { src = (const float*)A0h; ld = ld0; lk = kk; idx = idx0; }
                else         { src = (const float*)A1h; ld = ld1; lk = kk - K0; idx = idx1; }
                int sr = idx ? idx[gr] : gr;
                float4 v = *(const float4*)(src + (size_t)sr * ld + lk);
                float xs[4] = {v.x, v.y, v.z, v.w};
                short4 h4, l4;
                short* hp = (short*)&h4; short* lp = (short*)&l4;
#pragma unroll
                for (int i = 0; i < 4; ++i) {
                    unsigned short hb = f2bf(xs[i]);
                    hp[i] = (short)hb;
                    lp[i] = (short)f2bf(xs[i] - bf2f(hb));
                }
                *(short4*)&As_h[lr][q * 4] = h4;
                *(short4*)&As_l[lr][q * 4] = l4;
            }
        }
        __syncthreads();
#pragma unroll
        for (int ks = 0; ks < 4; ++ks) {
            bf16x8 ba_h[4], ba_l[4];
#pragma unroll
            for (int mt = 0; mt < 4; ++mt) {
                int m = mt * 16 + llo;
                ba_h[mt] = *(const bf16x8*)&As_h[m][ks * 32 + lhi * 8];
                ba_l[mt] = *(const bf16x8*)&As_l[m][ks * 32 + lhi * 8];
            }
#pragma unroll
            for (int mt = 0; mt < 4; ++mt)
#pragma unroll
                for (int nt = 0; nt < NTW; ++nt) {
                    acc[mt][nt] = __builtin_amdgcn_mfma_f32_16x16x32_bf16(
                        wf_h[nt][ks], ba_h[mt], acc[mt][nt], 0, 0, 0);
                    acc[mt][nt] = __builtin_amdgcn_mfma_f32_16x16x32_bf16(
                        wf_h[nt][ks], ba_l[mt], acc[mt][nt], 0, 0, 0);
                    acc[mt][nt] = __builtin_amdgcn_mfma_f32_16x16x32_bf16(
                        wf_l[nt][ks], ba_h[mt], acc[mt][nt], 0, 0, 0);
                }
        }
    }
    // ---- epilogue ----
    if (FDOT) {
        __shared__ float redf[4][64];
        const float b2d = b2p[0];
        float pd[4] = {0.f, 0.f, 0.f, 0.f};
#pragma unroll
        for (int mt = 0; mt < 4; ++mt)
#pragma unroll
            for (int nt = 0; nt < NTW; ++nt) {
                int c0 = (w * NTW + nt) * 16 + lhi * 4;
#pragma unroll
                for (int u = 0; u < 4; ++u) {
                    float z = acc[mt][nt][u] + bias[c0 + u];
                    if (RELU) z = z > 0.f ? z : 0.f;
                    pd[mt] = fmaf(z, W2p[c0 + u], pd[mt]);
                }
            }
#pragma unroll
        for (int mt = 0; mt < 4; ++mt) {
            pd[mt] += __shfl_xor(pd[mt], 16, 64);
            pd[mt] += __shfl_xor(pd[mt], 32, 64);
        }
        if (lhi == 0) {
#pragma unroll
            for (int mt = 0; mt < 4; ++mt) redf[w][mt * 16 + llo] = pd[mt];
        }
        __syncthreads();
        if (w == 0 && lhi == 0) {
#pragma unroll
            for (int mt = 0; mt < 4; ++mt) {
                int r = row0 + mt * 16 + llo;
                if (r < M) {
                    float d = redf[0][mt * 16 + llo] + redf[1][mt * 16 + llo]
                            + redf[2][mt * 16 + llo] + redf[3][mt * 16 + llo] + b2d;
                    outd[r] = 1.f / (1.f + __expf(-d));
                }
            }
        }
    } else {
#pragma unroll
        for (int mt = 0; mt < 4; ++mt) {
            int r = row0 + mt * 16 + llo;
            if (r < M) {
#pragma unroll
                for (int nt = 0; nt < NTW; ++nt) {
                    int c0 = (w * NTW + nt) * 16 + lhi * 4;
                    float v[4];
#pragma unroll
                    for (int u = 0; u < 4; ++u) {
                        float z = acc[mt][nt][u] + bias[c0 + u];
                        if (RELU) z = z > 0.f ? z : 0.f;
                        v[u] = z;
                    }
                    if (OUTSPLIT) {
                        short4 h4, l4;
                        short* hp = (short*)&h4; short* lp = (short*)&l4;
#pragma unroll
                        for (int u = 0; u < 4; ++u) {
                            unsigned short hb = f2bf(v[u]);
                            hp[u] = (short)hb;
                            lp[u] = (short)f2bf(v[u] - bf2f(hb));
                        }
                        *(short4*)(Ch + (size_t)r * N + c0) = h4;
                        *(short4*)(Cl + (size_t)r * N + c0) = l4;
                    } else {
                        float4 o = {v[0], v[1], v[2], v[3]};
                        *(float4*)(Cf + (size_t)r * N + c0) = o;
                    }
                }
            }
        }
    }
}

// ---------------- GATv2: half-wave per edge, online softmax; xlr[N][256] ----
#define GPH 4
__global__ __launch_bounds__(256) void gat_half_k(
    const float* __restrict__ xlr, const float* __restrict__ att,
    const int* __restrict__ offs, const int* __restrict__ csrs,
    const float* __restrict__ bias,
    short* __restrict__ houth, short* __restrict__ houtl)
{
    const int wid = (blockIdx.x * 256 + threadIdx.x) >> 6;
    const int lane = threadIdx.x & 63;
    const int h = lane >> 5, sub = lane & 31;
    if (wid >= NN) return;
    const int n = wid;
    const int beg = offs[n];
    const int total = (offs[n + 1] - beg) + 1;

    const float4 attv = *(const float4*)(att + sub * 4);
    const float4 xrv  = *(const float4*)(xlr + (size_t)n * 256 + 128 + sub * 4);

    float m = -INFINITY, s = 0.f;
    float4 acc = {0.f, 0.f, 0.f, 0.f};

    int cs[GPH];
#pragma unroll
    for (int p = 0; p < GPH; ++p) {
        int slot = p * 2 + h;
        cs[p] = (slot < total) ? ((slot == 0) ? n : csrs[beg + slot - 1]) : 0;
    }

    for (int base = 0; base < total; base += 2 * GPH) {
        float4 r[GPH];
        bool val[GPH];
#pragma unroll
        for (int p = 0; p < GPH; ++p) {
            int slot = base + p * 2 + h;
            val[p] = slot < total;
            if (val[p]) r[p] = *(const float4*)(xlr + (size_t)cs[p] * 256 + sub * 4);
        }
        int ns[GPH];
#pragma unroll
        for (int p = 0; p < GPH; ++p) {
            int nslot = base + 2 * GPH + p * 2 + h;
            ns[p] = (nslot < total) ? csrs[beg + nslot - 1] : 0;
        }
        float e[GPH];
#pragma unroll
        for (int p = 0; p < GPH; ++p) {
            if (val[p]) {
                float v = 0.f;
#pragma unroll
                for (int j = 0; j < 4; ++j) {
                    float mj = ((const float*)&r[p])[j] + ((const float*)&xrv)[j];
                    mj = mj > 0.f ? mj : 0.2f * mj;
                    v = fmaf(mj, ((const float*)&attv)[j], v);
                }
                v += __int_as_float(__builtin_amdgcn_ds_swizzle(__float_as_int(v), 0x041F));
                v += __int_as_float(__builtin_amdgcn_ds_swizzle(__float_as_int(v), 0x081F));
                v += __int_as_float(__builtin_amdgcn_ds_swizzle(__float_as_int(v), 0x101F));
                v += __int_as_float(__builtin_amdgcn_ds_swizzle(__float_as_int(v), 0x201F));
                v += __int_as_float(__builtin_amdgcn_ds_swizzle(__float_as_int(v), 0x401F));
                e[p] = v;
            }
        }
#pragma unroll
        for (int p = 0; p < GPH; ++p) {
            if (val[p]) {
                float mnew = fmaxf(m, e[p]);
                float sc = __expf(m - mnew);
                float wj = __expf(e[p] - mnew);
                s = fmaf(s, sc, wj);
                acc.x = fmaf(acc.x, sc, wj * r[p].x);
                acc.y = fmaf(acc.y, sc, wj * r[p].y);
                acc.z = fmaf(acc.z, sc, wj * r[p].z);
                acc.w = fmaf(acc.w, sc, wj * r[p].w);
                m = mnew;
            }
        }
#pragma unroll
        for (int p = 0; p < GPH; ++p) cs[p] = ns[p];
    }
    float om = __shfl_xor(m, 32, 64);
    float os = __shfl_xor(s, 32, 64);
    float4 oacc;
    oacc.x = __shfl_xor(acc.x, 32, 64);
    oacc.y = __shfl_xor(acc.y, 32, 64);
    oacc.z = __shfl_xor(acc.z, 32, 64);
    oacc.w = __shfl_xor(acc.w, 32, 64);
    float M = fmaxf(m, om);
    float a = __expf(m - M), b = __expf(om - M);
    float st = s * a + os * b;
    float inv = 1.f / st;
    float o0 = (acc.x * a + oacc.x * b) * inv + bias[sub * 4 + 0];
    float o1 = (acc.y * a + oacc.y * b) * inv + bias[sub * 4 + 1];
    float o2 = (acc.z * a + oacc.z * b) * inv + bias[sub * 4 + 2];
    float o3 = (acc.w * a + oacc.w * b) * inv + bias[sub * 4 + 3];
    if (h == 0) {
        float ov[4] = {o0, o1, o2, o3};
        short4 h4, l4;
        short* hp = (short*)&h4; short* lp = (short*)&l4;
#pragma unroll
        for (int u = 0; u < 4; ++u) {
            unsigned short hb = f2bf(ov[u]);
            hp[u] = (short)hb;
            lp[u] = (short)f2bf(ov[u] - bf2f(hb));
        }
        *(short4*)(houth + (size_t)n * HID + sub * 4) = h4;
        *(short4*)(houtl + (size_t)n * HID + sub * 4) = l4;
    }
}

extern "C" void kernel_launch(void* const* d_in, const int* in_sizes, int n_in,
                              void* d_out, int out_size, void* d_ws, size_t ws_size,
                              hipStream_t stream)
{
    const float* x    = (const float*)d_in[0];
    const float* emb  = (const float*)d_in[1];
    const int*   ei   = (const int*)d_in[2];
    const int*   bidx = (const int*)d_in[3];
    const int*   eim  = (const int*)d_in[4];
    const float* encW = (const float*)d_in[5];
    const float* encB = (const float*)d_in[6];
    const float* gWl  = (const float*)d_in[7];
    const float* gbl  = (const float*)d_in[8];
    const float* gWr  = (const float*)d_in[9];
    const float* gbr  = (const float*)d_in[10];
    const float* gatt = (const float*)d_in[11];
    const float* gb   = (const float*)d_in[12];
    const float* eW0  = (const float*)d_in[13];
    const float* eb0  = (const float*)d_in[14];
    const float* eW1  = (const float*)d_in[15];
    const float* eb1  = (const float*)d_in[16];
    const float* eW2  = (const float*)d_in[17];
    const float* eb2  = (const float*)d_in[18];
    const float* nW0  = (const float*)d_in[19];
    const float* nb0  = (const float*)d_in[20];
    const float* nW1  = (const float*)d_in[21];
    const float* nb1  = (const float*)d_in[22];
    const float* nW2  = (const float*)d_in[23];
    const float* nb2  = (const float*)d_in[24];
    float* out = (float*)d_out;

    char* wptr = (char*)d_ws;
    auto alloc = [&](size_t bytes) {
        char* p = wptr;
        wptr += (bytes + 255) & ~(size_t)255;
        return p;
    };
    short* hh = (short*)alloc((size_t)NN * HID * 2);
    short* hl = (short*)alloc((size_t)NN * HID * 2);
    float* xl = (float*)alloc((size_t)NN * HID * 4);   // first half of xlr
    float* xr = (float*)alloc((size_t)NN * HID * 4);   // second half (contiguous)
    float* xlr = xl;                                    // [NN][256] fp32
    int* counts = (int*)alloc((size_t)NN * 4);
    int* offs   = (int*)alloc((size_t)(NN + 1) * 4);
    int* csrs   = (int*)alloc((size_t)NE * 4);
    int* bsum   = (int*)alloc(256 * 4);
    int* bscan  = (int*)alloc(256 * 4);
    auto wplane = [&](int elems, short*& ph, short*& pl) {
        ph = (short*)alloc((size_t)elems * 2);
        pl = (short*)alloc((size_t)elems * 2);
    };
    short *encWt_h[3], *encWt_l[3];
    for (int i = 0; i < 3; ++i) wplane(HID * HID, encWt_h[i], encWt_l[i]);
    short *glrt_h[3], *glrt_l[3];                       // fused Wl||Wr [256][128]
    for (int i = 0; i < 3; ++i) wplane(256 * HID, glrt_h[i], glrt_l[i]);
    short *eW0t_h, *eW0t_l, *eW1t_h, *eW1t_l;
    wplane(2 * HID * HID, eW0t_h, eW0t_l);
    wplane(HID * HID, eW1t_h, eW1t_l);
    short *nW0t_h, *nW0t_l, *nW1t_h, *nW1t_l, *nW2t_h, *nW2t_l;
    wplane(HID * HID, nW0t_h, nW0t_l);
    wplane(HID * HID, nW1t_h, nW1t_l);
    wplane(HID * 64, nW2t_h, nW2t_l);
    float* gblr = (float*)alloc(3 * 256 * 4);
    // aliases (phases sequential)
    short* t1h = (short*)xl;  short* t1l = t1h + (size_t)NN * HID;
    short* t2h = (short*)xr;  short* t2l = t2h + (size_t)NN * HID;
    short* Ebh = (short*)xl;                            // 100000x128 shorts = 25.6MB
    short* Ebl = (short*)xr;
    short* nb0h = (short*)xl; short* nb0l = nb0h + (size_t)NBLOCK * HID;
    short* nb1h = nb0l + (size_t)NBLOCK * HID;
    short* nb1l = nb1h + (size_t)NBLOCK * HID;

    // ---- W pre-conversion ----
    WDescs ds;
    int di = 0;
    for (int i = 0; i < 3; ++i)
        ds.d[di++] = {encW + (size_t)i * HID * HID, encWt_h[i], encWt_l[i], HID, HID};
    for (int i = 0; i < 3; ++i) {
        ds.d[di++] = {gWl + (size_t)i * HID * HID, glrt_h[i], glrt_l[i], HID, HID};
        ds.d[di++] = {gWr + (size_t)i * HID * HID, glrt_h[i] + HID * HID,
                      glrt_l[i] + HID * HID, HID, HID};
    }
    ds.d[di++] = {eW0, eW0t_h, eW0t_l, 2 * HID, HID};
    ds.d[di++] = {eW1, eW1t_h, eW1t_l, HID, HID};
    ds.d[di++] = {nW0, nW0t_h, nW0t_l, HID, HID};
    ds.d[di++] = {nW1, nW1t_h, nW1t_l, HID, HID};
    ds.d[di++] = {nW2, nW2t_h, nW2t_l, HID, 64};
    wconv_k<<<14 * 128, 256, 0, stream>>>(ds);
    biascat_k<<<3, 256, 0, stream>>>(gbl, gbr, gblr);

    // ---- CSR build (parallel scan) ----
    zero_k<<<(NN + 255) / 256, 256, 0, stream>>>(counts, NN);
    count_k<<<(NE + 255) / 256, 256, 0, stream>>>(ei, counts);
    scan1_k<<<NB_SCAN, 256, 0, stream>>>(counts, offs, bsum);
    scan2_k<<<1, 256, 0, stream>>>(bsum, bscan, offs);
    scan3_k<<<NB_SCAN, 256, 0, stream>>>(offs, bscan);
    scatter_k<<<(NE + 255) / 256, 256, 0, stream>>>(ei, offs, counts, csrs);

    const int gN = (NN + 63) / 64;
    // ---- encoder MLP ----
    gemm3_k<128, true, false, true, false, 3><<<gN, 256, 0, stream>>>(
        x, nullptr, 64, 64, emb, nullptr, 64, nullptr, nullptr, 128,
        encWt_h[0], encWt_l[0], encB, nullptr, t1h, t1l, nullptr, nullptr, nullptr, NN);
    gemm3_k<128, true, true, true, false, 3><<<gN, 256, 0, stream>>>(
        t1h, t1l, 128, 128, nullptr, nullptr, 0, nullptr, nullptr, 128,
        encWt_h[1], encWt_l[1], encB + 128, nullptr, t2h, t2l, nullptr, nullptr, nullptr, NN);
    gemm3_k<128, false, true, true, false, 3><<<gN, 256, 0, stream>>>(
        t2h, t2l, 128, 128, nullptr, nullptr, 0, nullptr, nullptr, 128,
        encWt_h[2], encWt_l[2], encB + 256, nullptr, hh, hl, nullptr, nullptr, nullptr, NN);

    // ---- 3 GATv2 layers: fused xl||xr GEMM (N=256) + half-wave GAT ----
    const int gGAT = (NN * 64 + 255) / 256;
    for (int l = 0; l < 3; ++l) {
        gemm3_k<256, false, true, false, false, 2><<<gN, 256, 0, stream>>>(
            hh, hl, 128, 128, nullptr, nullptr, 0, nullptr, nullptr, 128,
            glrt_h[l], glrt_l[l], gblr + (size_t)l * 256, xlr, nullptr, nullptr,
            nullptr, nullptr, nullptr, NN);
        gat_half_k<<<gGAT, 256, 0, stream>>>(xlr, gatt + (size_t)l * HID,
                                             offs, csrs, gb + (size_t)l * HID, hh, hl);
    }

    // ---- edge decoder, 2 chunks of 100000 rows, final dot fused ----
    for (int c = 0; c < 2; ++c) {
        const int Mc = 100000;
        const int* i0 = eim + (size_t)c * Mc;
        const int* i1 = eim + NIMAG + (size_t)c * Mc;
        gemm3_k<128, true, true, true, false, 3><<<(Mc + 63) / 64, 256, 0, stream>>>(
            hh, hl, 128, 128, hh, hl, 128, i0, i1, 256,
            eW0t_h, eW0t_l, eb0, nullptr, Ebh, Ebl, nullptr, nullptr, nullptr, Mc);
        gemm3_k<128, true, true, false, true, 3><<<(Mc + 63) / 64, 256, 0, stream>>>(
            Ebh, Ebl, 128, 128, nullptr, nullptr, 0, nullptr, nullptr, 128,
            eW1t_h, eW1t_l, eb1, nullptr, nullptr, nullptr,
            eW2, eb2, out + (size_t)NBLOCK * 64 + (size_t)c * Mc, Mc);
    }

    // ---- node decoder ----
    const int gB = (NBLOCK + 63) / 64;
    gemm3_k<128, true, true, true, false, 3><<<gB, 256, 0, stream>>>(
        hh, hl, 128, 128, nullptr, nullptr, 0, bidx, nullptr, 128,
        nW0t_h, nW0t_l, nb0, nullptr, nb0h, nb0l, nullptr, nullptr, nullptr, NBLOCK);
    gemm3_k<128, true, true, true, false, 3><<<gB, 256, 0, stream>>>(
        nb0h, nb0l, 128, 128, nullptr, nullptr, 0, nullptr, nullptr, 128,
        nW1t_h, nW1t_l, nb1, nullptr, nb1h, nb1l, nullptr, nullptr, nullptr, NBLOCK);
    gemm3_k<64, false, true, false, false, 3><<<gB, 256, 0, stream>>>(
        nb1h, nb1l, 128, 128, nullptr, nullptr, 0, nullptr, nullptr, 128,
        nW2t_h, nW2t_l, nb2, out, nullptr, nullptr, nullptr, nullptr, nullptr, NBLOCK);
}

// Round 8
// 685.746 us; speedup vs baseline: 2.9152x; 1.1858x over previous
//
#include <hip/hip_runtime.h>
#include <hip/hip_bf16.h>
#include <math.h>

#define NN 50000
#define NE 1000000
#define NIMAG 200000
#define NBLOCK 5000
#define HID 128
#define NB_SCAN ((NN + 255) / 256)   // 196

typedef __attribute__((ext_vector_type(8))) short bf16x8;
typedef __attribute__((ext_vector_type(4))) float f32x4;

__device__ inline unsigned short f2bf(float x) {
    unsigned u = __float_as_uint(x);
    unsigned r = u + 0x7fff + ((u >> 16) & 1);   // RNE
    return (unsigned short)(r >> 16);
}
__device__ inline float bf2f(unsigned short b) {
    return __uint_as_float((unsigned)b << 16);
}

// ---------------- zero fill ----------------
__global__ void zero_k(int* __restrict__ p, int n) {
    int i = blockIdx.x * 256 + threadIdx.x;
    if (i < n) p[i] = 0;
}

// ---------------- CSR build ----------------
__global__ void count_k(const int* __restrict__ ei, int* __restrict__ counts) {
    int e = blockIdx.x * 256 + threadIdx.x;
    if (e < NE) atomicAdd(&counts[ei[NE + e]], 1);
}

__global__ void scan1_k(const int* __restrict__ counts, int* __restrict__ offs,
                        int* __restrict__ bsum) {
    __shared__ int sh[256];
    int t = threadIdx.x;
    int i = blockIdx.x * 256 + t;
    int v = (i < NN) ? counts[i] : 0;
    sh[t] = v;
    __syncthreads();
    for (int off = 1; off < 256; off <<= 1) {
        int a = (t >= off) ? sh[t - off] : 0;
        __syncthreads();
        sh[t] += a;
        __syncthreads();
    }
    if (i < NN) offs[i] = sh[t] - v;
    if (t == 255) bsum[blockIdx.x] = sh[255];
}

__global__ void scan2_k(const int* __restrict__ bsum, int* __restrict__ bscan,
                        int* __restrict__ offs) {
    __shared__ int sh[256];
    int t = threadIdx.x;
    int v = (t < NB_SCAN) ? bsum[t] : 0;
    sh[t] = v;
    __syncthreads();
    for (int off = 1; off < 256; off <<= 1) {
        int a = (t >= off) ? sh[t - off] : 0;
        __syncthreads();
        sh[t] += a;
        __syncthreads();
    }
    if (t < NB_SCAN) bscan[t] = sh[t] - v;
    if (t == NB_SCAN - 1) offs[NN] = sh[t];
}

__global__ void scan3_k(int* __restrict__ offs, const int* __restrict__ bscan) {
    int i = blockIdx.x * 256 + threadIdx.x;
    if (i < NN) offs[i] += bscan[blockIdx.x];
}

__global__ void scatter_k(const int* __restrict__ ei, const int* __restrict__ offs,
                          int* __restrict__ counts, int* __restrict__ csr_src) {
    int e = blockIdx.x * 256 + threadIdx.x;
    if (e < NE) {
        int d = ei[NE + e];
        int pos = offs[d] + atomicSub(&counts[d], 1) - 1;
        csr_src[pos] = ei[e];
    }
}

// ---------------- batched W pre-convert: fp32 [K][N] -> split-bf16 [N][K] ----
struct WDesc { const float* src; short* dh; short* dl; int K; int N; };
struct WDescs { WDesc d[14]; };
__global__ __launch_bounds__(256) void wconv_k(WDescs ds) {
    int m = blockIdx.x >> 7;
    int i = (blockIdx.x & 127) * 256 + threadIdx.x;
    WDesc w = ds.d[m];
    int tot = w.K * w.N;
    if (i < tot) {
        int k = i / w.N, n = i - k * w.N;
        float v = w.src[i];
        unsigned short h = f2bf(v);
        w.dh[(size_t)n * w.K + k] = (short)h;
        w.dl[(size_t)n * w.K + k] = (short)f2bf(v - bf2f(h));
    }
}

__global__ void biascat_k(const float* __restrict__ bl, const float* __restrict__ br,
                          float* __restrict__ o) {
    int l = blockIdx.x, t = threadIdx.x;
    o[l * 256 + t] = (t < 128) ? bl[l * 128 + t] : br[l * 128 + (t - 128)];
}

// ---------------- shared MFMA helpers ----------------
template <int NTW>
__device__ inline void stage_mfma(
    const short* __restrict__ Wh, const short* __restrict__ Wl,
    int Kstride, int kb,
    const short (*Ash)[136], const short (*Asl)[136],
    int w, int llo, int lhi, f32x4 (&acc)[4][NTW])
{
#pragma unroll
    for (int ks = 0; ks < 4; ++ks) {
        bf16x8 wf_h[NTW], wf_l[NTW];
#pragma unroll
        for (int nt = 0; nt < NTW; ++nt) {
            int n = (w * NTW + nt) * 16 + llo;
            size_t off = (size_t)n * Kstride + kb + ks * 32 + lhi * 8;
            wf_h[nt] = *(const bf16x8*)(Wh + off);
            wf_l[nt] = *(const bf16x8*)(Wl + off);
        }
        bf16x8 ba_h[4], ba_l[4];
#pragma unroll
        for (int mt = 0; mt < 4; ++mt) {
            int m = mt * 16 + llo;
            ba_h[mt] = *(const bf16x8*)&Ash[m][ks * 32 + lhi * 8];
            ba_l[mt] = *(const bf16x8*)&Asl[m][ks * 32 + lhi * 8];
        }
#pragma unroll
        for (int mt = 0; mt < 4; ++mt)
#pragma unroll
            for (int nt = 0; nt < NTW; ++nt) {
                acc[mt][nt] = __builtin_amdgcn_mfma_f32_16x16x32_bf16(
                    wf_h[nt], ba_h[mt], acc[mt][nt], 0, 0, 0);
                acc[mt][nt] = __builtin_amdgcn_mfma_f32_16x16x32_bf16(
                    wf_h[nt], ba_l[mt], acc[mt][nt], 0, 0, 0);
                acc[mt][nt] = __builtin_amdgcn_mfma_f32_16x16x32_bf16(
                    wf_l[nt], ba_h[mt], acc[mt][nt], 0, 0, 0);
            }
    }
}

// act = relu(acc + bias) -> split-bf16 back into LDS A planes
template <bool RELU>
__device__ inline void act_to_lds(
    f32x4 (&acc)[4][2], const float* __restrict__ bias,
    short (*Ash)[136], short (*Asl)[136], int w, int llo, int lhi)
{
#pragma unroll
    for (int mt = 0; mt < 4; ++mt) {
        int r = mt * 16 + llo;
#pragma unroll
        for (int nt = 0; nt < 2; ++nt) {
            int c0 = (w * 2 + nt) * 16 + lhi * 4;
            short4 h4, l4;
            short* hp = (short*)&h4; short* lp = (short*)&l4;
#pragma unroll
            for (int u = 0; u < 4; ++u) {
                float z = acc[mt][nt][u] + bias[c0 + u];
                if (RELU) z = z > 0.f ? z : 0.f;
                unsigned short hb = f2bf(z);
                hp[u] = (short)hb;
                lp[u] = (short)f2bf(z - bf2f(hb));
            }
            *(short4*)&Ash[r][c0] = h4;
            *(short4*)&Asl[r][c0] = l4;
        }
    }
}

// ---------------- fused MLP chain (2 or 3 MFMA stages in one dispatch) -----
// K1: first-stage K. NSTAGE: 2 (edec: S1,S2+FDOT) or 3 (enc/ndec).
// FINAL: 0 = OUTSPLIT N=128, 1 = FDOT sigmoid scalar out, 2 = fp32 N=NOUT.
template <int K1, int NSTAGE, int NOUT, int FINAL, bool INS>
__global__ __launch_bounds__(256, 2) void mlp_k(
    const void* __restrict__ A0h, const void* __restrict__ A0l, int ld0, int K0,
    const void* __restrict__ A1h, const void* __restrict__ A1l, int ld1,
    const int* __restrict__ idx0, const int* __restrict__ idx1,
    const short* __restrict__ W1h, const short* __restrict__ W1l, const float* __restrict__ b1,
    const short* __restrict__ W2h, const short* __restrict__ W2l, const float* __restrict__ b2,
    const short* __restrict__ W3h, const short* __restrict__ W3l, const float* __restrict__ b3,
    short* __restrict__ Ch, short* __restrict__ Cl, float* __restrict__ Cf,
    const float* __restrict__ Wd, const float* __restrict__ bd, float* __restrict__ outd,
    int M)
{
    __shared__ __align__(16) short As_h[64][136];
    __shared__ __align__(16) short As_l[64][136];
    __shared__ float redf[4][64];

    const int t = threadIdx.x;
    const int w = t >> 6, lane = t & 63;
    const int llo = lane & 15, lhi = lane >> 4;
    const int row0 = blockIdx.x * 64;

    // ---- stage 1 ----
    f32x4 acc1[4][2];
#pragma unroll
    for (int mt = 0; mt < 4; ++mt)
#pragma unroll
        for (int nt = 0; nt < 2; ++nt) { f32x4 z = {0,0,0,0}; acc1[mt][nt] = z; }

    for (int kb = 0; kb < K1; kb += 128) {
        if (kb != 0) __syncthreads();
        if (INS) {
#pragma unroll
            for (int j = 0; j < 4; ++j) {
                int u = j * 256 + t;
                int lr = u >> 4;
                int q  = u & 15;
                int gr = row0 + lr; if (gr >= M) gr = M - 1;
                int kk = kb + q * 8;
                const short *bh, *bl; int ld, lk; const int* idx;
                if (kk < K0) { bh = (const short*)A0h; bl = (const short*)A0l;
                               ld = ld0; lk = kk; idx = idx0; }
                else         { bh = (const short*)A1h; bl = (const short*)A1l;
                               ld = ld1; lk = kk - K0; idx = idx1; }
                int sr = idx ? idx[gr] : gr;
                size_t off = (size_t)sr * ld + lk;
                *(bf16x8*)&As_h[lr][q * 8] = *(const bf16x8*)(bh + off);
                *(bf16x8*)&As_l[lr][q * 8] = *(const bf16x8*)(bl + off);
            }
        } else {
#pragma unroll
            for (int j = 0; j < 8; ++j) {
                int u = j * 256 + t;
                int lr = u >> 5;
                int q  = u & 31;
                int gr = row0 + lr; if (gr >= M) gr = M - 1;
                int kk = kb + q * 4;
                const float* src; int ld, lk; const int* idx;
                if (kk < K0) { src = (const float*)A0h; ld = ld0; lk = kk; idx = idx0; }
                else         { src = (const float*)A1h; ld = ld1; lk = kk - K0; idx = idx1; }
                int sr = idx ? idx[gr] : gr;
                float4 v = *(const float4*)(src + (size_t)sr * ld + lk);
                float xs[4] = {v.x, v.y, v.z, v.w};
                short4 h4, l4;
                short* hp = (short*)&h4; short* lp = (short*)&l4;
#pragma unroll
                for (int i = 0; i < 4; ++i) {
                    unsigned short hb = f2bf(xs[i]);
                    hp[i] = (short)hb;
                    lp[i] = (short)f2bf(xs[i] - bf2f(hb));
                }
                *(short4*)&As_h[lr][q * 4] = h4;
                *(short4*)&As_l[lr][q * 4] = l4;
            }
        }
        __syncthreads();
        stage_mfma<2>(W1h, W1l, K1, kb, As_h, As_l, w, llo, lhi, acc1);
    }
    __syncthreads();                 // all stage-1 LDS reads done
    act_to_lds<true>(acc1, b1, As_h, As_l, w, llo, lhi);
    __syncthreads();

    // ---- stage 2 ----
    f32x4 acc2[4][2];
#pragma unroll
    for (int mt = 0; mt < 4; ++mt)
#pragma unroll
        for (int nt = 0; nt < 2; ++nt) { f32x4 z = {0,0,0,0}; acc2[mt][nt] = z; }
    stage_mfma<2>(W2h, W2l, 128, 0, As_h, As_l, w, llo, lhi, acc2);

    if (NSTAGE == 2) {
        // FDOT epilogue: out[r] = sigmoid(relu(acc2+b2) . Wd + bd)
        const float bdd = bd[0];
        float pd[4] = {0.f, 0.f, 0.f, 0.f};
#pragma unroll
        for (int mt = 0; mt < 4; ++mt)
#pragma unroll
            for (int nt = 0; nt < 2; ++nt) {
                int c0 = (w * 2 + nt) * 16 + lhi * 4;
#pragma unroll
                for (int u = 0; u < 4; ++u) {
                    float z = acc2[mt][nt][u] + b2[c0 + u];
                    z = z > 0.f ? z : 0.f;
                    pd[mt] = fmaf(z, Wd[c0 + u], pd[mt]);
                }
            }
#pragma unroll
        for (int mt = 0; mt < 4; ++mt) {
            pd[mt] += __shfl_xor(pd[mt], 16, 64);
            pd[mt] += __shfl_xor(pd[mt], 32, 64);
        }
        if (lhi == 0) {
#pragma unroll
            for (int mt = 0; mt < 4; ++mt) redf[w][mt * 16 + llo] = pd[mt];
        }
        __syncthreads();
        if (w == 0 && lhi == 0) {
#pragma unroll
            for (int mt = 0; mt < 4; ++mt) {
                int r = row0 + mt * 16 + llo;
                if (r < M) {
                    float d = redf[0][mt * 16 + llo] + redf[1][mt * 16 + llo]
                            + redf[2][mt * 16 + llo] + redf[3][mt * 16 + llo] + bdd;
                    outd[r] = 1.f / (1.f + __expf(-d));
                }
            }
        }
    } else {
        __syncthreads();
        act_to_lds<true>(acc2, b2, As_h, As_l, w, llo, lhi);
        __syncthreads();
        // ---- stage 3 ----
        constexpr int NTWF = NOUT / 64;
        f32x4 acc3[4][NTWF];
#pragma unroll
        for (int mt = 0; mt < 4; ++mt)
#pragma unroll
            for (int nt = 0; nt < NTWF; ++nt) { f32x4 z = {0,0,0,0}; acc3[mt][nt] = z; }
        stage_mfma<NTWF>(W3h, W3l, 128, 0, As_h, As_l, w, llo, lhi, acc3);
#pragma unroll
        for (int mt = 0; mt < 4; ++mt) {
            int r = row0 + mt * 16 + llo;
            if (r < M) {
#pragma unroll
                for (int nt = 0; nt < NTWF; ++nt) {
                    int c0 = (w * NTWF + nt) * 16 + lhi * 4;
                    float v[4];
#pragma unroll
                    for (int u = 0; u < 4; ++u) v[u] = acc3[mt][nt][u] + b3[c0 + u];
                    if (FINAL == 0) {
                        short4 h4, l4;
                        short* hp = (short*)&h4; short* lp = (short*)&l4;
#pragma unroll
                        for (int u = 0; u < 4; ++u) {
                            unsigned short hb = f2bf(v[u]);
                            hp[u] = (short)hb;
                            lp[u] = (short)f2bf(v[u] - bf2f(hb));
                        }
                        *(short4*)(Ch + (size_t)r * NOUT + c0) = h4;
                        *(short4*)(Cl + (size_t)r * NOUT + c0) = l4;
                    } else {
                        float4 o = {v[0], v[1], v[2], v[3]};
                        *(float4*)(Cf + (size_t)r * NOUT + c0) = o;
                    }
                }
            }
        }
    }
}

// ---------------- N=256 GEMM for fused xl||xr (per-ks W register loads) ----
__global__ __launch_bounds__(256, 2) void gemmlr_k(
    const short* __restrict__ Ah, const short* __restrict__ Al,
    const short* __restrict__ Wh, const short* __restrict__ Wl,
    const float* __restrict__ bias, float* __restrict__ C, int M)
{
    __shared__ __align__(16) short As_h[64][136];
    __shared__ __align__(16) short As_l[64][136];
    const int t = threadIdx.x;
    const int w = t >> 6, lane = t & 63;
    const int llo = lane & 15, lhi = lane >> 4;
    const int row0 = blockIdx.x * 64;

    f32x4 acc[4][4];
#pragma unroll
    for (int mt = 0; mt < 4; ++mt)
#pragma unroll
        for (int nt = 0; nt < 4; ++nt) { f32x4 z = {0,0,0,0}; acc[mt][nt] = z; }

#pragma unroll
    for (int j = 0; j < 4; ++j) {
        int u = j * 256 + t;
        int lr = u >> 4;
        int q  = u & 15;
        int gr = row0 + lr; if (gr >= M) gr = M - 1;
        size_t off = (size_t)gr * 128 + q * 8;
        *(bf16x8*)&As_h[lr][q * 8] = *(const bf16x8*)(Ah + off);
        *(bf16x8*)&As_l[lr][q * 8] = *(const bf16x8*)(Al + off);
    }
    __syncthreads();
    stage_mfma<4>(Wh, Wl, 128, 0, As_h, As_l, w, llo, lhi, acc);

#pragma unroll
    for (int mt = 0; mt < 4; ++mt) {
        int r = row0 + mt * 16 + llo;
        if (r < M) {
#pragma unroll
            for (int nt = 0; nt < 4; ++nt) {
                int c0 = (w * 4 + nt) * 16 + lhi * 4;
                float4 o;
                float* op = (float*)&o;
#pragma unroll
                for (int u = 0; u < 4; ++u) op[u] = acc[mt][nt][u] + bias[c0 + u];
                *(float4*)(C + (size_t)r * 256 + c0) = o;
            }
        }
    }
}

// ---------------- GATv2: half-wave per edge, tile-rescaled online softmax ----
#define GPH 4
#define NEGI -1e30f
__global__ __launch_bounds__(256) void gat2_k(
    const float* __restrict__ xlr, const float* __restrict__ att,
    const int* __restrict__ offs, const int* __restrict__ csrs,
    const float* __restrict__ bias,
    short* __restrict__ houth, short* __restrict__ houtl)
{
    const int wid = (blockIdx.x * 256 + threadIdx.x) >> 6;
    const int lane = threadIdx.x & 63;
    const int h = lane >> 5, sub = lane & 31;
    if (wid >= NN) return;
    const int n = wid;
    const int beg = offs[n];
    const int total = (offs[n + 1] - beg) + 1;

    const float4 attv = *(const float4*)(att + sub * 4);
    const float4 xrv  = *(const float4*)(xlr + (size_t)n * 256 + 128 + sub * 4);

    float m = NEGI, s = 0.f;
    float4 acc = {0.f, 0.f, 0.f, 0.f};

    int cs[GPH];
#pragma unroll
    for (int p = 0; p < GPH; ++p) {
        int slot = p * 2 + h;
        cs[p] = (slot < total) ? ((slot == 0) ? n : csrs[beg + slot - 1]) : n;
    }

    for (int base = 0; base < total; base += 2 * GPH) {
        float4 r[GPH];
#pragma unroll
        for (int p = 0; p < GPH; ++p)
            r[p] = *(const float4*)(xlr + (size_t)cs[p] * 256 + sub * 4);
        int ns[GPH];
#pragma unroll
        for (int p = 0; p < GPH; ++p) {
            int nslot = base + 2 * GPH + p * 2 + h;
            ns[p] = (nslot < total) ? csrs[beg + nslot - 1] : n;
        }
        float e[GPH];
#pragma unroll
        for (int p = 0; p < GPH; ++p) {
            float v = 0.f;
#pragma unroll
            for (int j = 0; j < 4; ++j) {
                float mj = ((const float*)&r[p])[j] + ((const float*)&xrv)[j];
                mj = mj > 0.f ? mj : 0.2f * mj;
                v = fmaf(mj, ((const float*)&attv)[j], v);
            }
            v += __int_as_float(__builtin_amdgcn_ds_swizzle(__float_as_int(v), 0x041F));
            v += __int_as_float(__builtin_amdgcn_ds_swizzle(__float_as_int(v), 0x081F));
            v += __int_as_float(__builtin_amdgcn_ds_swizzle(__float_as_int(v), 0x101F));
            v += __int_as_float(__builtin_amdgcn_ds_swizzle(__float_as_int(v), 0x201F));
            v += __int_as_float(__builtin_amdgcn_ds_swizzle(__float_as_int(v), 0x401F));
            e[p] = (base + p * 2 + h < total) ? v : NEGI;
        }
        float tm = fmaxf(fmaxf(e[0], e[1]), fmaxf(e[2], e[3]));
        float mnew = fmaxf(m, tm);
        float sc = __expf(m - mnew);
        s *= sc; acc.x *= sc; acc.y *= sc; acc.z *= sc; acc.w *= sc;
#pragma unroll
        for (int p = 0; p < GPH; ++p) {
            float wj = __expf(e[p] - mnew);
            s += wj;
            acc.x = fmaf(wj, r[p].x, acc.x);
            acc.y = fmaf(wj, r[p].y, acc.y);
            acc.z = fmaf(wj, r[p].z, acc.z);
            acc.w = fmaf(wj, r[p].w, acc.w);
        }
        m = mnew;
#pragma unroll
        for (int p = 0; p < GPH; ++p) cs[p] = ns[p];
    }
    // merge halves
    float om = __shfl_xor(m, 32, 64);
    float os = __shfl_xor(s, 32, 64);
    float4 oacc;
    oacc.x = __shfl_xor(acc.x, 32, 64);
    oacc.y = __shfl_xor(acc.y, 32, 64);
    oacc.z = __shfl_xor(acc.z, 32, 64);
    oacc.w = __shfl_xor(acc.w, 32, 64);
    float M = fmaxf(m, om);
    float a = __expf(m - M), b = __expf(om - M);
    float st = s * a + os * b;
    float inv = 1.f / st;
    if (h == 0) {
        float ov[4];
        ov[0] = (acc.x * a + oacc.x * b) * inv + bias[sub * 4 + 0];
        ov[1] = (acc.y * a + oacc.y * b) * inv + bias[sub * 4 + 1];
        ov[2] = (acc.z * a + oacc.z * b) * inv + bias[sub * 4 + 2];
        ov[3] = (acc.w * a + oacc.w * b) * inv + bias[sub * 4 + 3];
        short4 h4, l4;
        short* hp = (short*)&h4; short* lp = (short*)&l4;
#pragma unroll
        for (int u = 0; u < 4; ++u) {
            unsigned short hb = f2bf(ov[u]);
            hp[u] = (short)hb;
            lp[u] = (short)f2bf(ov[u] - bf2f(hb));
        }
        *(short4*)(houth + (size_t)n * HID + sub * 4) = h4;
        *(short4*)(houtl + (size_t)n * HID + sub * 4) = l4;
    }
}

extern "C" void kernel_launch(void* const* d_in, const int* in_sizes, int n_in,
                              void* d_out, int out_size, void* d_ws, size_t ws_size,
                              hipStream_t stream)
{
    const float* x    = (const float*)d_in[0];
    const float* emb  = (const float*)d_in[1];
    const int*   ei   = (const int*)d_in[2];
    const int*   bidx = (const int*)d_in[3];
    const int*   eim  = (const int*)d_in[4];
    const float* encW = (const float*)d_in[5];
    const float* encB = (const float*)d_in[6];
    const float* gWl  = (const float*)d_in[7];
    const float* gbl  = (const float*)d_in[8];
    const float* gWr  = (const float*)d_in[9];
    const float* gbr  = (const float*)d_in[10];
    const float* gatt = (const float*)d_in[11];
    const float* gb   = (const float*)d_in[12];
    const float* eW0  = (const float*)d_in[13];
    const float* eb0  = (const float*)d_in[14];
    const float* eW1  = (const float*)d_in[15];
    const float* eb1  = (const float*)d_in[16];
    const float* eW2  = (const float*)d_in[17];
    const float* eb2  = (const float*)d_in[18];
    const float* nW0  = (const float*)d_in[19];
    const float* nb0  = (const float*)d_in[20];
    const float* nW1  = (const float*)d_in[21];
    const float* nb1  = (const float*)d_in[22];
    const float* nW2  = (const float*)d_in[23];
    const float* nb2  = (const float*)d_in[24];
    float* out = (float*)d_out;

    char* wptr = (char*)d_ws;
    auto alloc = [&](size_t bytes) {
        char* p = wptr;
        wptr += (bytes + 255) & ~(size_t)255;
        return p;
    };
    short* hh  = (short*)alloc((size_t)NN * HID * 2);
    short* hl  = (short*)alloc((size_t)NN * HID * 2);
    float* xlr = (float*)alloc((size_t)NN * 256 * 4);
    int* counts = (int*)alloc((size_t)NN * 4);
    int* offs   = (int*)alloc((size_t)(NN + 1) * 4);
    int* csrs   = (int*)alloc((size_t)NE * 4);
    int* bsum   = (int*)alloc(256 * 4);
    int* bscan  = (int*)alloc(256 * 4);
    auto wplane = [&](int elems, short*& ph, short*& pl) {
        ph = (short*)alloc((size_t)elems * 2);
        pl = (short*)alloc((size_t)elems * 2);
    };
    short *encWt_h[3], *encWt_l[3];
    for (int i = 0; i < 3; ++i) wplane(HID * HID, encWt_h[i], encWt_l[i]);
    short *glrt_h[3], *glrt_l[3];
    for (int i = 0; i < 3; ++i) wplane(256 * HID, glrt_h[i], glrt_l[i]);
    short *eW0t_h, *eW0t_l, *eW1t_h, *eW1t_l;
    wplane(2 * HID * HID, eW0t_h, eW0t_l);
    wplane(HID * HID, eW1t_h, eW1t_l);
    short *nW0t_h, *nW0t_l, *nW1t_h, *nW1t_l, *nW2t_h, *nW2t_l;
    wplane(HID * HID, nW0t_h, nW0t_l);
    wplane(HID * HID, nW1t_h, nW1t_l);
    wplane(HID * 64, nW2t_h, nW2t_l);
    float* gblr = (float*)alloc(3 * 256 * 4);

    // ---- W pre-conversion ----
    WDescs ds;
    int di = 0;
    for (int i = 0; i < 3; ++i)
        ds.d[di++] = {encW + (size_t)i * HID * HID, encWt_h[i], encWt_l[i], HID, HID};
    for (int i = 0; i < 3; ++i) {
        ds.d[di++] = {gWl + (size_t)i * HID * HID, glrt_h[i], glrt_l[i], HID, HID};
        ds.d[di++] = {gWr + (size_t)i * HID * HID, glrt_h[i] + HID * HID,
                      glrt_l[i] + HID * HID, HID, HID};
    }
    ds.d[di++] = {eW0, eW0t_h, eW0t_l, 2 * HID, HID};
    ds.d[di++] = {eW1, eW1t_h, eW1t_l, HID, HID};
    ds.d[di++] = {nW0, nW0t_h, nW0t_l, HID, HID};
    ds.d[di++] = {nW1, nW1t_h, nW1t_l, HID, HID};
    ds.d[di++] = {nW2, nW2t_h, nW2t_l, HID, 64};
    wconv_k<<<14 * 128, 256, 0, stream>>>(ds);
    biascat_k<<<3, 256, 0, stream>>>(gbl, gbr, gblr);

    // ---- CSR build ----
    zero_k<<<(NN + 255) / 256, 256, 0, stream>>>(counts, NN);
    count_k<<<(NE + 255) / 256, 256, 0, stream>>>(ei, counts);
    scan1_k<<<NB_SCAN, 256, 0, stream>>>(counts, offs, bsum);
    scan2_k<<<1, 256, 0, stream>>>(bsum, bscan, offs);
    scan3_k<<<NB_SCAN, 256, 0, stream>>>(offs, bscan);
    scatter_k<<<(NE + 255) / 256, 256, 0, stream>>>(ei, offs, counts, csrs);

    const int gN = (NN + 63) / 64;
    // ---- encoder MLP: one fused dispatch (3 stages) -> hh/hl ----
    mlp_k<128, 3, 128, 0, false><<<gN, 256, 0, stream>>>(
        x, nullptr, 64, 64, emb, nullptr, 64, nullptr, nullptr,
        encWt_h[0], encWt_l[0], encB,
        encWt_h[1], encWt_l[1], encB + 128,
        encWt_h[2], encWt_l[2], encB + 256,
        hh, hl, nullptr, nullptr, nullptr, nullptr, NN);

    // ---- 3 GATv2 layers ----
    const int gGAT = (NN * 64 + 255) / 256;
    for (int l = 0; l < 3; ++l) {
        gemmlr_k<<<gN, 256, 0, stream>>>(hh, hl, glrt_h[l], glrt_l[l],
                                         gblr + (size_t)l * 256, xlr, NN);
        gat2_k<<<gGAT, 256, 0, stream>>>(xlr, gatt + (size_t)l * HID,
                                         offs, csrs, gb + (size_t)l * HID, hh, hl);
    }

    // ---- edge decoder: single fused dispatch over all 200000 rows ----
    mlp_k<256, 2, 128, 1, true><<<(NIMAG + 63) / 64, 256, 0, stream>>>(
        hh, hl, 128, 128, hh, hl, 128, eim, eim + NIMAG,
        eW0t_h, eW0t_l, eb0,
        eW1t_h, eW1t_l, eb1,
        nullptr, nullptr, nullptr,
        nullptr, nullptr, nullptr,
        eW2, eb2, out + (size_t)NBLOCK * 64, NIMAG);

    // ---- node decoder: one fused dispatch (3 stages) ----
    mlp_k<128, 3, 64, 2, true><<<(NBLOCK + 63) / 64, 256, 0, stream>>>(
        hh, hl, 128, 128, nullptr, nullptr, 0, bidx, nullptr,
        nW0t_h, nW0t_l, nb0,
        nW1t_h, nW1t_l, nb1,
        nW2t_h, nW2t_l, nb2,
        nullptr, nullptr, out, nullptr, nullptr, nullptr, NBLOCK);
}

// Round 9
// 681.428 us; speedup vs baseline: 2.9336x; 1.0063x over previous
//
#include <hip/hip_runtime.h>
#include <hip/hip_bf16.h>
#include <math.h>

#define NN 50000
#define NE 1000000
#define NIMAG 200000
#define NBLOCK 5000
#define HID 128
#define NB_SCAN ((NN + 255) / 256)   // 196

typedef __attribute__((ext_vector_type(8))) short bf16x8;
typedef __attribute__((ext_vector_type(4))) float f32x4;

__device__ inline unsigned short f2bf(float x) {
    unsigned u = __float_as_uint(x);
    unsigned r = u + 0x7fff + ((u >> 16) & 1);   // RNE
    return (unsigned short)(r >> 16);
}
__device__ inline float bf2f(unsigned short b) {
    return __uint_as_float((unsigned)b << 16);
}

// ---------------- zero fill ----------------
__global__ void zero_k(int* __restrict__ p, int n) {
    int i = blockIdx.x * 256 + threadIdx.x;
    if (i < n) p[i] = 0;
}

// ---------------- CSR build ----------------
__global__ void count_k(const int* __restrict__ ei, int* __restrict__ counts) {
    int e = blockIdx.x * 256 + threadIdx.x;
    if (e < NE) atomicAdd(&counts[ei[NE + e]], 1);
}

__global__ void scan1_k(const int* __restrict__ counts, int* __restrict__ offs,
                        int* __restrict__ bsum) {
    __shared__ int sh[256];
    int t = threadIdx.x;
    int i = blockIdx.x * 256 + t;
    int v = (i < NN) ? counts[i] : 0;
    sh[t] = v;
    __syncthreads();
    for (int off = 1; off < 256; off <<= 1) {
        int a = (t >= off) ? sh[t - off] : 0;
        __syncthreads();
        sh[t] += a;
        __syncthreads();
    }
    if (i < NN) offs[i] = sh[t] - v;
    if (t == 255) bsum[blockIdx.x] = sh[255];
}

__global__ void scan2_k(const int* __restrict__ bsum, int* __restrict__ bscan,
                        int* __restrict__ offs) {
    __shared__ int sh[256];
    int t = threadIdx.x;
    int v = (t < NB_SCAN) ? bsum[t] : 0;
    sh[t] = v;
    __syncthreads();
    for (int off = 1; off < 256; off <<= 1) {
        int a = (t >= off) ? sh[t - off] : 0;
        __syncthreads();
        sh[t] += a;
        __syncthreads();
    }
    if (t < NB_SCAN) bscan[t] = sh[t] - v;
    if (t == NB_SCAN - 1) offs[NN] = sh[t];
}

__global__ void scan3_k(int* __restrict__ offs, const int* __restrict__ bscan) {
    int i = blockIdx.x * 256 + threadIdx.x;
    if (i < NN) offs[i] += bscan[blockIdx.x];
}

__global__ void scatter_k(const int* __restrict__ ei, const int* __restrict__ offs,
                          int* __restrict__ counts, int* __restrict__ csr_src) {
    int e = blockIdx.x * 256 + threadIdx.x;
    if (e < NE) {
        int d = ei[NE + e];
        int pos = offs[d] + atomicSub(&counts[d], 1) - 1;
        csr_src[pos] = ei[e];
    }
}

// ---------------- batched W pre-convert: fp32 [K][N] -> split-bf16 [N][K] ----
struct WDesc { const float* src; short* dh; short* dl; int K; int N; };
struct WDescs { WDesc d[14]; };
__global__ __launch_bounds__(256) void wconv_k(WDescs ds) {
    int m = blockIdx.x >> 7;
    int i = (blockIdx.x & 127) * 256 + threadIdx.x;
    WDesc w = ds.d[m];
    int tot = w.K * w.N;
    if (i < tot) {
        int k = i / w.N, n = i - k * w.N;
        float v = w.src[i];
        unsigned short h = f2bf(v);
        w.dh[(size_t)n * w.K + k] = (short)h;
        w.dl[(size_t)n * w.K + k] = (short)f2bf(v - bf2f(h));
    }
}

__global__ void biascat_k(const float* __restrict__ bl, const float* __restrict__ br,
                          float* __restrict__ o) {
    int l = blockIdx.x, t = threadIdx.x;
    o[l * 256 + t] = (t < 128) ? bl[l * 128 + t] : br[l * 128 + (t - 128)];
}

// ---------------- LDS layout: [64][128] shorts, XOR-swizzled 16B chunks ----
// phys offset (shorts) for row r, 16B-chunk c: ((c ^ (r & 15)) << 3)

// ---------------- shared MFMA helpers ----------------
template <int NTW>
__device__ inline void stage_mfma(
    const short* __restrict__ Wh, const short* __restrict__ Wl,
    int Kstride, int kb,
    const short (*Ash)[128], const short (*Asl)[128],
    int w, int llo, int lhi, f32x4 (&acc)[4][NTW])
{
#pragma unroll
    for (int ks = 0; ks < 4; ++ks) {
        bf16x8 wf_h[NTW], wf_l[NTW];
#pragma unroll
        for (int nt = 0; nt < NTW; ++nt) {
            int n = (w * NTW + nt) * 16 + llo;
            size_t off = (size_t)n * Kstride + kb + ks * 32 + lhi * 8;
            wf_h[nt] = *(const bf16x8*)(Wh + off);
            wf_l[nt] = *(const bf16x8*)(Wl + off);
        }
        bf16x8 ba_h[4], ba_l[4];
#pragma unroll
        for (int mt = 0; mt < 4; ++mt) {
            int m = mt * 16 + llo;
            int c = ((4 * ks + lhi) ^ llo) << 3;
            ba_h[mt] = *(const bf16x8*)&Ash[m][c];
            ba_l[mt] = *(const bf16x8*)&Asl[m][c];
        }
#pragma unroll
        for (int mt = 0; mt < 4; ++mt)
#pragma unroll
            for (int nt = 0; nt < NTW; ++nt) {
                acc[mt][nt] = __builtin_amdgcn_mfma_f32_16x16x32_bf16(
                    wf_h[nt], ba_h[mt], acc[mt][nt], 0, 0, 0);
                acc[mt][nt] = __builtin_amdgcn_mfma_f32_16x16x32_bf16(
                    wf_h[nt], ba_l[mt], acc[mt][nt], 0, 0, 0);
                acc[mt][nt] = __builtin_amdgcn_mfma_f32_16x16x32_bf16(
                    wf_l[nt], ba_h[mt], acc[mt][nt], 0, 0, 0);
            }
    }
}

// act = relu(acc + bias) -> split-bf16 back into LDS A planes (swizzled)
__device__ inline void act_to_lds(
    f32x4 (&acc)[4][2], const float* __restrict__ bias,
    short (*Ash)[128], short (*Asl)[128], int w, int llo, int lhi)
{
#pragma unroll
    for (int mt = 0; mt < 4; ++mt) {
        int r = mt * 16 + llo;
#pragma unroll
        for (int nt = 0; nt < 2; ++nt) {
            int c0 = (w * 2 + nt) * 16 + lhi * 4;
            int chunk = c0 >> 3;
            int off = ((chunk ^ llo) << 3) + (c0 & 7);
            short4 h4, l4;
            short* hp = (short*)&h4; short* lp = (short*)&l4;
#pragma unroll
            for (int u = 0; u < 4; ++u) {
                float z = acc[mt][nt][u] + bias[c0 + u];
                z = z > 0.f ? z : 0.f;
                unsigned short hb = f2bf(z);
                hp[u] = (short)hb;
                lp[u] = (short)f2bf(z - bf2f(hb));
            }
            *(short4*)&Ash[r][off] = h4;
            *(short4*)&Asl[r][off] = l4;
        }
    }
}

// per-thread register chunk for pipelined gather staging
struct AChunk { bf16x8 h[4], l[4]; };

template <bool DUAL>
__device__ inline void gather_chunk(
    AChunk& c,
    const short* __restrict__ A0h, const short* __restrict__ A0l, int ld0, int K0,
    const short* __restrict__ A1h, const short* __restrict__ A1l, int ld1,
    const int* __restrict__ idx0, const int* __restrict__ idx1,
    int kb, int row0, int M, int t)
{
#pragma unroll
    for (int j = 0; j < 4; ++j) {
        int u = j * 256 + t;
        int lr = u >> 4, q = u & 15;
        int gr = row0 + lr; if (gr >= M) gr = M - 1;
        int kk = kb + q * 8;
        const short *bh, *bl; int ld, lk; const int* idx;
        if (!DUAL || kk < K0) { bh = A0h; bl = A0l; ld = ld0; lk = kk; idx = idx0; }
        else                  { bh = A1h; bl = A1l; ld = ld1; lk = kk - K0; idx = idx1; }
        int sr = idx ? idx[gr] : gr;
        size_t off = (size_t)sr * ld + lk;
        c.h[j] = *(const bf16x8*)(bh + off);
        c.l[j] = *(const bf16x8*)(bl + off);
    }
}

__device__ inline void write_chunk(const AChunk& c,
                                   short (*Ash)[128], short (*Asl)[128], int t)
{
#pragma unroll
    for (int j = 0; j < 4; ++j) {
        int u = j * 256 + t;
        int lr = u >> 4, q = u & 15;
        int off = (q ^ lr) << 3;       // lr < 64 but q^ (lr&15); lr&15 == lr&15
        off = ((q ^ (lr & 15)) << 3);
        *(bf16x8*)&Ash[lr][off] = c.h[j];
        *(bf16x8*)&Asl[lr][off] = c.l[j];
    }
}

// ---------------- fused MLP chain (2 or 3 MFMA stages in one dispatch) -----
// K1: first-stage K. NSTAGE: 2 (edec: S1,S2+FDOT) or 3 (enc/ndec).
// FINAL: 0 = OUTSPLIT N=128, 1 = FDOT sigmoid scalar out, 2 = fp32 N=NOUT.
template <int K1, int NSTAGE, int NOUT, int FINAL, bool INS>
__global__ __launch_bounds__(256, 2) void mlp_k(
    const void* __restrict__ A0h, const void* __restrict__ A0l, int ld0, int K0,
    const void* __restrict__ A1h, const void* __restrict__ A1l, int ld1,
    const int* __restrict__ idx0, const int* __restrict__ idx1,
    const short* __restrict__ W1h, const short* __restrict__ W1l, const float* __restrict__ b1,
    const short* __restrict__ W2h, const short* __restrict__ W2l, const float* __restrict__ b2,
    const short* __restrict__ W3h, const short* __restrict__ W3l, const float* __restrict__ b3,
    short* __restrict__ Ch, short* __restrict__ Cl, float* __restrict__ Cf,
    const float* __restrict__ Wd, const float* __restrict__ bd, float* __restrict__ outd,
    int M)
{
    __shared__ __align__(16) short As_h[64][128];
    __shared__ __align__(16) short As_l[64][128];
    __shared__ float redf[4][64];

    const int t = threadIdx.x;
    const int w = t >> 6, lane = t & 63;
    const int llo = lane & 15, lhi = lane >> 4;
    const int row0 = blockIdx.x * 64;

    // ---- stage 1 ----
    f32x4 acc1[4][2];
#pragma unroll
    for (int mt = 0; mt < 4; ++mt)
#pragma unroll
        for (int nt = 0; nt < 2; ++nt) { f32x4 z = {0,0,0,0}; acc1[mt][nt] = z; }

    if (INS) {
        if (K1 == 256) {
            // software-pipelined: gather c1 overlaps MFMA on c0
            AChunk c0, c1;
            gather_chunk<true>(c0, (const short*)A0h, (const short*)A0l, ld0, K0,
                               (const short*)A1h, (const short*)A1l, ld1,
                               idx0, idx1, 0, row0, M, t);
            write_chunk(c0, As_h, As_l, t);
            __syncthreads();
            gather_chunk<true>(c1, (const short*)A0h, (const short*)A0l, ld0, K0,
                               (const short*)A1h, (const short*)A1l, ld1,
                               idx0, idx1, 128, row0, M, t);
            stage_mfma<2>(W1h, W1l, K1, 0, As_h, As_l, w, llo, lhi, acc1);
            __syncthreads();
            write_chunk(c1, As_h, As_l, t);
            __syncthreads();
            stage_mfma<2>(W1h, W1l, K1, 128, As_h, As_l, w, llo, lhi, acc1);
        } else {
            AChunk c0;
            gather_chunk<false>(c0, (const short*)A0h, (const short*)A0l, ld0, K0,
                                nullptr, nullptr, 0, idx0, nullptr, 0, row0, M, t);
            write_chunk(c0, As_h, As_l, t);
            __syncthreads();
            stage_mfma<2>(W1h, W1l, K1, 0, As_h, As_l, w, llo, lhi, acc1);
        }
    } else {
        // fp32 A (encoder layer 0): convert during staging, K1=128
#pragma unroll
        for (int j = 0; j < 8; ++j) {
            int u = j * 256 + t;
            int lr = u >> 5;
            int q  = u & 31;
            int gr = row0 + lr; if (gr >= M) gr = M - 1;
            int kk = q * 4;
            const float* src; int ld, lk; const int* idx;
            if (kk < K0) { src = (const float*)A0h; ld = ld0; lk = kk; idx = idx0; }
            else         { src = (const float*)A1h; ld = ld1; lk = kk - K0; idx = idx1; }
            int sr = idx ? idx[gr] : gr;
            float4 v = *(const float4*)(src + (size_t)sr * ld + lk);
            float xs[4] = {v.x, v.y, v.z, v.w};
            short4 h4, l4;
            short* hp = (short*)&h4; short* lp = (short*)&l4;
#pragma unroll
            for (int i = 0; i < 4; ++i) {
                unsigned short hb = f2bf(xs[i]);
                hp[i] = (short)hb;
                lp[i] = (short)f2bf(xs[i] - bf2f(hb));
            }
            int off = (((q >> 1) ^ (lr & 15)) << 3) + (q & 1) * 4;
            *(short4*)&As_h[lr][off] = h4;
            *(short4*)&As_l[lr][off] = l4;
        }
        __syncthreads();
        stage_mfma<2>(W1h, W1l, K1, 0, As_h, As_l, w, llo, lhi, acc1);
    }
    __syncthreads();                 // all stage-1 LDS reads done
    act_to_lds(acc1, b1, As_h, As_l, w, llo, lhi);
    __syncthreads();

    // ---- stage 2 ----
    f32x4 acc2[4][2];
#pragma unroll
    for (int mt = 0; mt < 4; ++mt)
#pragma unroll
        for (int nt = 0; nt < 2; ++nt) { f32x4 z = {0,0,0,0}; acc2[mt][nt] = z; }
    stage_mfma<2>(W2h, W2l, 128, 0, As_h, As_l, w, llo, lhi, acc2);

    if (NSTAGE == 2) {
        // FDOT epilogue: out[r] = sigmoid(relu(acc2+b2) . Wd + bd)
        const float bdd = bd[0];
        float pd[4] = {0.f, 0.f, 0.f, 0.f};
#pragma unroll
        for (int mt = 0; mt < 4; ++mt)
#pragma unroll
            for (int nt = 0; nt < 2; ++nt) {
                int c0 = (w * 2 + nt) * 16 + lhi * 4;
#pragma unroll
                for (int u = 0; u < 4; ++u) {
                    float z = acc2[mt][nt][u] + b2[c0 + u];
                    z = z > 0.f ? z : 0.f;
                    pd[mt] = fmaf(z, Wd[c0 + u], pd[mt]);
                }
            }
#pragma unroll
        for (int mt = 0; mt < 4; ++mt) {
            pd[mt] += __shfl_xor(pd[mt], 16, 64);
            pd[mt] += __shfl_xor(pd[mt], 32, 64);
        }
        if (lhi == 0) {
#pragma unroll
            for (int mt = 0; mt < 4; ++mt) redf[w][mt * 16 + llo] = pd[mt];
        }
        __syncthreads();
        if (w == 0 && lhi == 0) {
#pragma unroll
            for (int mt = 0; mt < 4; ++mt) {
                int r = row0 + mt * 16 + llo;
                if (r < M) {
                    float d = redf[0][mt * 16 + llo] + redf[1][mt * 16 + llo]
                            + redf[2][mt * 16 + llo] + redf[3][mt * 16 + llo] + bdd;
                    outd[r] = 1.f / (1.f + __expf(-d));
                }
            }
        }
    } else {
        __syncthreads();
        act_to_lds(acc2, b2, As_h, As_l, w, llo, lhi);
        __syncthreads();
        // ---- stage 3 ----
        constexpr int NTWF = NOUT / 64;
        f32x4 acc3[4][NTWF];
#pragma unroll
        for (int mt = 0; mt < 4; ++mt)
#pragma unroll
            for (int nt = 0; nt < NTWF; ++nt) { f32x4 z = {0,0,0,0}; acc3[mt][nt] = z; }
        stage_mfma<NTWF>(W3h, W3l, 128, 0, As_h, As_l, w, llo, lhi, acc3);
#pragma unroll
        for (int mt = 0; mt < 4; ++mt) {
            int r = row0 + mt * 16 + llo;
            if (r < M) {
#pragma unroll
                for (int nt = 0; nt < NTWF; ++nt) {
                    int c0 = (w * NTWF + nt) * 16 + lhi * 4;
                    float v[4];
#pragma unroll
                    for (int u = 0; u < 4; ++u) v[u] = acc3[mt][nt][u] + b3[c0 + u];
                    if (FINAL == 0) {
                        short4 h4, l4;
                        short* hp = (short*)&h4; short* lp = (short*)&l4;
#pragma unroll
                        for (int u = 0; u < 4; ++u) {
                            unsigned short hb = f2bf(v[u]);
                            hp[u] = (short)hb;
                            lp[u] = (short)f2bf(v[u] - bf2f(hb));
                        }
                        *(short4*)(Ch + (size_t)r * NOUT + c0) = h4;
                        *(short4*)(Cl + (size_t)r * NOUT + c0) = l4;
                    } else {
                        float4 o = {v[0], v[1], v[2], v[3]};
                        *(float4*)(Cf + (size_t)r * NOUT + c0) = o;
                    }
                }
            }
        }
    }
}

// ---------------- N=256 GEMM for fused xl||xr ----------------
__global__ __launch_bounds__(256, 2) void gemmlr_k(
    const short* __restrict__ Ah, const short* __restrict__ Al,
    const short* __restrict__ Wh, const short* __restrict__ Wl,
    const float* __restrict__ bias, float* __restrict__ C, int M)
{
    __shared__ __align__(16) short As_h[64][128];
    __shared__ __align__(16) short As_l[64][128];
    const int t = threadIdx.x;
    const int w = t >> 6, lane = t & 63;
    const int llo = lane & 15, lhi = lane >> 4;
    const int row0 = blockIdx.x * 64;

    f32x4 acc[4][4];
#pragma unroll
    for (int mt = 0; mt < 4; ++mt)
#pragma unroll
        for (int nt = 0; nt < 4; ++nt) { f32x4 z = {0,0,0,0}; acc[mt][nt] = z; }

#pragma unroll
    for (int j = 0; j < 4; ++j) {
        int u = j * 256 + t;
        int lr = u >> 4;
        int q  = u & 15;
        int gr = row0 + lr; if (gr >= M) gr = M - 1;
        size_t off = (size_t)gr * 128 + q * 8;
        int loff = ((q ^ (lr & 15)) << 3);
        *(bf16x8*)&As_h[lr][loff] = *(const bf16x8*)(Ah + off);
        *(bf16x8*)&As_l[lr][loff] = *(const bf16x8*)(Al + off);
    }
    __syncthreads();
    stage_mfma<4>(Wh, Wl, 128, 0, As_h, As_l, w, llo, lhi, acc);

#pragma unroll
    for (int mt = 0; mt < 4; ++mt) {
        int r = row0 + mt * 16 + llo;
        if (r < M) {
#pragma unroll
            for (int nt = 0; nt < 4; ++nt) {
                int c0 = (w * 4 + nt) * 16 + lhi * 4;
                float4 o;
                float* op = (float*)&o;
#pragma unroll
                for (int u = 0; u < 4; ++u) op[u] = acc[mt][nt][u] + bias[c0 + u];
                *(float4*)(C + (size_t)r * 256 + c0) = o;
            }
        }
    }
}

// ---------------- GATv2: half-wave per edge, DPP logit reduction ----------
#define GPH 4
#define NEGI -1e30f
#define DPPADD(v, ctrl) \
    v += __int_as_float(__builtin_amdgcn_update_dpp(0, __float_as_int(v), ctrl, 0xf, 0xf, true))

__device__ inline float red32_bcast(float v) {
    DPPADD(v, 0x111);   // row_shr:1
    DPPADD(v, 0x112);   // row_shr:2
    DPPADD(v, 0x114);   // row_shr:4
    DPPADD(v, 0x118);   // row_shr:8  -> lane15/31 hold 16-sums
    DPPADD(v, 0x142);   // row_bcast15 -> lane31 holds 32-sum
    // broadcast lane31 (per 32-group) to all lanes of the group
    return __int_as_float(__builtin_amdgcn_ds_swizzle(__float_as_int(v), 0x03E0));
}

__global__ __launch_bounds__(256) void gat2_k(
    const float* __restrict__ xlr, const float* __restrict__ att,
    const int* __restrict__ offs, const int* __restrict__ csrs,
    const float* __restrict__ bias,
    short* __restrict__ houth, short* __restrict__ houtl)
{
    const int wid = (blockIdx.x * 256 + threadIdx.x) >> 6;
    const int lane = threadIdx.x & 63;
    const int h = lane >> 5, sub = lane & 31;
    if (wid >= NN) return;
    const int n = wid;
    const int beg = offs[n];
    const int total = (offs[n + 1] - beg) + 1;

    const float4 attv = *(const float4*)(att + sub * 4);
    const float4 xrv  = *(const float4*)(xlr + (size_t)n * 256 + 128 + sub * 4);

    float m = NEGI, s = 0.f;
    float4 acc = {0.f, 0.f, 0.f, 0.f};

    int cs[GPH];
#pragma unroll
    for (int p = 0; p < GPH; ++p) {
        int slot = p * 2 + h;
        cs[p] = (slot < total) ? ((slot == 0) ? n : csrs[beg + slot - 1]) : n;
    }

    for (int base = 0; base < total; base += 2 * GPH) {
        float4 r[GPH];
#pragma unroll
        for (int p = 0; p < GPH; ++p)
            r[p] = *(const float4*)(xlr + (size_t)cs[p] * 256 + sub * 4);
        int ns[GPH];
#pragma unroll
        for (int p = 0; p < GPH; ++p) {
            int nslot = base + 2 * GPH + p * 2 + h;
            ns[p] = (nslot < total) ? csrs[beg + nslot - 1] : n;
        }
        float e[GPH];
#pragma unroll
        for (int p = 0; p < GPH; ++p) {
            float v = 0.f;
#pragma unroll
            for (int j = 0; j < 4; ++j) {
                float mj = ((const float*)&r[p])[j] + ((const float*)&xrv)[j];
                mj = mj > 0.f ? mj : 0.2f * mj;
                v = fmaf(mj, ((const float*)&attv)[j], v);
            }
            v = red32_bcast(v);
            e[p] = (base + p * 2 + h < total) ? v : NEGI;
        }
        float tm = fmaxf(fmaxf(e[0], e[1]), fmaxf(e[2], e[3]));
        float mnew = fmaxf(m, tm);
        float sc = __expf(m - mnew);
        s *= sc; acc.x *= sc; acc.y *= sc; acc.z *= sc; acc.w *= sc;
#pragma unroll
        for (int p = 0; p < GPH; ++p) {
            float wj = __expf(e[p] - mnew);
            s += wj;
            acc.x = fmaf(wj, r[p].x, acc.x);
            acc.y = fmaf(wj, r[p].y, acc.y);
            acc.z = fmaf(wj, r[p].z, acc.z);
            acc.w = fmaf(wj, r[p].w, acc.w);
        }
        m = mnew;
#pragma unroll
        for (int p = 0; p < GPH; ++p) cs[p] = ns[p];
    }
    // merge halves
    float om = __shfl_xor(m, 32, 64);
    float os = __shfl_xor(s, 32, 64);
    float4 oacc;
    oacc.x = __shfl_xor(acc.x, 32, 64);
    oacc.y = __shfl_xor(acc.y, 32, 64);
    oacc.z = __shfl_xor(acc.z, 32, 64);
    oacc.w = __shfl_xor(acc.w, 32, 64);
    float M = fmaxf(m, om);
    float a = __expf(m - M), b = __expf(om - M);
    float st = s * a + os * b;
    float inv = 1.f / st;
    if (h == 0) {
        float ov[4];
        ov[0] = (acc.x * a + oacc.x * b) * inv + bias[sub * 4 + 0];
        ov[1] = (acc.y * a + oacc.y * b) * inv + bias[sub * 4 + 1];
        ov[2] = (acc.z * a + oacc.z * b) * inv + bias[sub * 4 + 2];
        ov[3] = (acc.w * a + oacc.w * b) * inv + bias[sub * 4 + 3];
        short4 h4, l4;
        short* hp = (short*)&h4; short* lp = (short*)&l4;
#pragma unroll
        for (int u = 0; u < 4; ++u) {
            unsigned short hb = f2bf(ov[u]);
            hp[u] = (short)hb;
            lp[u] = (short)f2bf(ov[u] - bf2f(hb));
        }
        *(short4*)(houth + (size_t)n * HID + sub * 4) = h4;
        *(short4*)(houtl + (size_t)n * HID + sub * 4) = l4;
    }
}

extern "C" void kernel_launch(void* const* d_in, const int* in_sizes, int n_in,
                              void* d_out, int out_size, void* d_ws, size_t ws_size,
                              hipStream_t stream)
{
    const float* x    = (const float*)d_in[0];
    const float* emb  = (const float*)d_in[1];
    const int*   ei   = (const int*)d_in[2];
    const int*   bidx = (const int*)d_in[3];
    const int*   eim  = (const int*)d_in[4];
    const float* encW = (const float*)d_in[5];
    const float* encB = (const float*)d_in[6];
    const float* gWl  = (const float*)d_in[7];
    const float* gbl  = (const float*)d_in[8];
    const float* gWr  = (const float*)d_in[9];
    const float* gbr  = (const float*)d_in[10];
    const float* gatt = (const float*)d_in[11];
    const float* gb   = (const float*)d_in[12];
    const float* eW0  = (const float*)d_in[13];
    const float* eb0  = (const float*)d_in[14];
    const float* eW1  = (const float*)d_in[15];
    const float* eb1  = (const float*)d_in[16];
    const float* eW2  = (const float*)d_in[17];
    const float* eb2  = (const float*)d_in[18];
    const float* nW0  = (const float*)d_in[19];
    const float* nb0  = (const float*)d_in[20];
    const float* nW1  = (const float*)d_in[21];
    const float* nb1  = (const float*)d_in[22];
    const float* nW2  = (const float*)d_in[23];
    const float* nb2  = (const float*)d_in[24];
    float* out = (float*)d_out;

    char* wptr = (char*)d_ws;
    auto alloc = [&](size_t bytes) {
        char* p = wptr;
        wptr += (bytes + 255) & ~(size_t)255;
        return p;
    };
    short* hh  = (short*)alloc((size_t)NN * HID * 2);
    short* hl  = (short*)alloc((size_t)NN * HID * 2);
    float* xlr = (float*)alloc((size_t)NN * 256 * 4);
    int* counts = (int*)alloc((size_t)NN * 4);
    int* offs   = (int*)alloc((size_t)(NN + 1) * 4);
    int* csrs   = (int*)alloc((size_t)NE * 4);
    int* bsum   = (int*)alloc(256 * 4);
    int* bscan  = (int*)alloc(256 * 4);
    auto wplane = [&](int elems, short*& ph, short*& pl) {
        ph = (short*)alloc((size_t)elems * 2);
        pl = (short*)alloc((size_t)elems * 2);
    };
    short *encWt_h[3], *encWt_l[3];
    for (int i = 0; i < 3; ++i) wplane(HID * HID, encWt_h[i], encWt_l[i]);
    short *glrt_h[3], *glrt_l[3];
    for (int i = 0; i < 3; ++i) wplane(256 * HID, glrt_h[i], glrt_l[i]);
    short *eW0t_h, *eW0t_l, *eW1t_h, *eW1t_l;
    wplane(2 * HID * HID, eW0t_h, eW0t_l);
    wplane(HID * HID, eW1t_h, eW1t_l);
    short *nW0t_h, *nW0t_l, *nW1t_h, *nW1t_l, *nW2t_h, *nW2t_l;
    wplane(HID * HID, nW0t_h, nW0t_l);
    wplane(HID * HID, nW1t_h, nW1t_l);
    wplane(HID * 64, nW2t_h, nW2t_l);
    float* gblr = (float*)alloc(3 * 256 * 4);

    // ---- W pre-conversion ----
    WDescs ds;
    int di = 0;
    for (int i = 0; i < 3; ++i)
        ds.d[di++] = {encW + (size_t)i * HID * HID, encWt_h[i], encWt_l[i], HID, HID};
    for (int i = 0; i < 3; ++i) {
        ds.d[di++] = {gWl + (size_t)i * HID * HID, glrt_h[i], glrt_l[i], HID, HID};
        ds.d[di++] = {gWr + (size_t)i * HID * HID, glrt_h[i] + HID * HID,
                      glrt_l[i] + HID * HID, HID, HID};
    }
    ds.d[di++] = {eW0, eW0t_h, eW0t_l, 2 * HID, HID};
    ds.d[di++] = {eW1, eW1t_h, eW1t_l, HID, HID};
    ds.d[di++] = {nW0, nW0t_h, nW0t_l, HID, HID};
    ds.d[di++] = {nW1, nW1t_h, nW1t_l, HID, HID};
    ds.d[di++] = {nW2, nW2t_h, nW2t_l, HID, 64};
    wconv_k<<<14 * 128, 256, 0, stream>>>(ds);
    biascat_k<<<3, 256, 0, stream>>>(gbl, gbr, gblr);

    // ---- CSR build ----
    zero_k<<<(NN + 255) / 256, 256, 0, stream>>>(counts, NN);
    count_k<<<(NE + 255) / 256, 256, 0, stream>>>(ei, counts);
    scan1_k<<<NB_SCAN, 256, 0, stream>>>(counts, offs, bsum);
    scan2_k<<<1, 256, 0, stream>>>(bsum, bscan, offs);
    scan3_k<<<NB_SCAN, 256, 0, stream>>>(offs, bscan);
    scatter_k<<<(NE + 255) / 256, 256, 0, stream>>>(ei, offs, counts, csrs);

    const int gN = (NN + 63) / 64;
    // ---- encoder MLP: one fused dispatch (3 stages) -> hh/hl ----
    mlp_k<128, 3, 128, 0, false><<<gN, 256, 0, stream>>>(
        x, nullptr, 64, 64, emb, nullptr, 64, nullptr, nullptr,
        encWt_h[0], encWt_l[0], encB,
        encWt_h[1], encWt_l[1], encB + 128,
        encWt_h[2], encWt_l[2], encB + 256,
        hh, hl, nullptr, nullptr, nullptr, nullptr, NN);

    // ---- 3 GATv2 layers ----
    const int gGAT = (NN * 64 + 255) / 256;
    for (int l = 0; l < 3; ++l) {
        gemmlr_k<<<gN, 256, 0, stream>>>(hh, hl, glrt_h[l], glrt_l[l],
                                         gblr + (size_t)l * 256, xlr, NN);
        gat2_k<<<gGAT, 256, 0, stream>>>(xlr, gatt + (size_t)l * HID,
                                         offs, csrs, gb + (size_t)l * HID, hh, hl);
    }

    // ---- edge decoder: single fused dispatch over all 200000 rows ----
    mlp_k<256, 2, 128, 1, true><<<(NIMAG + 63) / 64, 256, 0, stream>>>(
        hh, hl, 128, 128, hh, hl, 128, eim, eim + NIMAG,
        eW0t_h, eW0t_l, eb0,
        eW1t_h, eW1t_l, eb1,
        nullptr, nullptr, nullptr,
        nullptr, nullptr, nullptr,
        eW2, eb2, out + (size_t)NBLOCK * 64, NIMAG);

    // ---- node decoder: one fused dispatch (3 stages) ----
    mlp_k<128, 3, 64, 2, true><<<(NBLOCK + 63) / 64, 256, 0, stream>>>(
        hh, hl, 128, 128, nullptr, nullptr, 0, bidx, nullptr,
        nW0t_h, nW0t_l, nb0,
        nW1t_h, nW1t_l, nb1,
        nW2t_h, nW2t_l, nb2,
        nullptr, nullptr, out, nullptr, nullptr, nullptr, NBLOCK);
}

// Round 10
// 613.116 us; speedup vs baseline: 3.2605x; 1.1114x over previous
//
#include <hip/hip_runtime.h>
#include <hip/hip_bf16.h>
#include <math.h>

#define NN 50000
#define NE 1000000
#define NIMAG 200000
#define NBLOCK 5000
#define HID 128
#define NB_SCAN ((NN + 255) / 256)   // 196

typedef __attribute__((ext_vector_type(8))) short bf16x8;
typedef __attribute__((ext_vector_type(4))) float f32x4;

__device__ inline unsigned short f2bf(float x) {
    unsigned u = __float_as_uint(x);
    unsigned r = u + 0x7fff + ((u >> 16) & 1);   // RNE
    return (unsigned short)(r >> 16);
}
__device__ inline float bf2f(unsigned short b) {
    return __uint_as_float((unsigned)b << 16);
}
// load 4 bf16 (8B) -> float4
__device__ inline float4 ld_bf4(const short* p) {
    uint2 d = *(const uint2*)p;
    float4 o;
    o.x = __uint_as_float(d.x << 16);
    o.y = __uint_as_float(d.x & 0xffff0000u);
    o.z = __uint_as_float(d.y << 16);
    o.w = __uint_as_float(d.y & 0xffff0000u);
    return o;
}

// ---------------- zero fill ----------------
__global__ void zero_k(int* __restrict__ p, int n) {
    int i = blockIdx.x * 256 + threadIdx.x;
    if (i < n) p[i] = 0;
}

// ---------------- CSR build ----------------
__global__ void count_k(const int* __restrict__ ei, int* __restrict__ counts) {
    int e = blockIdx.x * 256 + threadIdx.x;
    if (e < NE) atomicAdd(&counts[ei[NE + e]], 1);
}

__global__ void scan1_k(const int* __restrict__ counts, int* __restrict__ offs,
                        int* __restrict__ bsum) {
    __shared__ int sh[256];
    int t = threadIdx.x;
    int i = blockIdx.x * 256 + t;
    int v = (i < NN) ? counts[i] : 0;
    sh[t] = v;
    __syncthreads();
    for (int off = 1; off < 256; off <<= 1) {
        int a = (t >= off) ? sh[t - off] : 0;
        __syncthreads();
        sh[t] += a;
        __syncthreads();
    }
    if (i < NN) offs[i] = sh[t] - v;
    if (t == 255) bsum[blockIdx.x] = sh[255];
}

__global__ void scan2_k(const int* __restrict__ bsum, int* __restrict__ bscan,
                        int* __restrict__ offs) {
    __shared__ int sh[256];
    int t = threadIdx.x;
    int v = (t < NB_SCAN) ? bsum[t] : 0;
    sh[t] = v;
    __syncthreads();
    for (int off = 1; off < 256; off <<= 1) {
        int a = (t >= off) ? sh[t - off] : 0;
        __syncthreads();
        sh[t] += a;
        __syncthreads();
    }
    if (t < NB_SCAN) bscan[t] = sh[t] - v;
    if (t == NB_SCAN - 1) offs[NN] = sh[t];
}

__global__ void scan3_k(int* __restrict__ offs, const int* __restrict__ bscan) {
    int i = blockIdx.x * 256 + threadIdx.x;
    if (i < NN) offs[i] += bscan[blockIdx.x];
}

__global__ void scatter_k(const int* __restrict__ ei, const int* __restrict__ offs,
                          int* __restrict__ counts, int* __restrict__ csr_src) {
    int e = blockIdx.x * 256 + threadIdx.x;
    if (e < NE) {
        int d = ei[NE + e];
        int pos = offs[d] + atomicSub(&counts[d], 1) - 1;
        csr_src[pos] = ei[e];
    }
}

// ---------------- batched W pre-convert: fp32 [K][N] -> split-bf16 [N][K] ----
struct WDesc { const float* src; short* dh; short* dl; int K; int N; };
struct WDescs { WDesc d[14]; };
__global__ __launch_bounds__(256) void wconv_k(WDescs ds) {
    int m = blockIdx.x >> 7;
    int i = (blockIdx.x & 127) * 256 + threadIdx.x;
    WDesc w = ds.d[m];
    int tot = w.K * w.N;
    if (i < tot) {
        int k = i / w.N, n = i - k * w.N;
        float v = w.src[i];
        unsigned short h = f2bf(v);
        w.dh[(size_t)n * w.K + k] = (short)h;
        w.dl[(size_t)n * w.K + k] = (short)f2bf(v - bf2f(h));
    }
}

__global__ void biascat_k(const float* __restrict__ bl, const float* __restrict__ br,
                          float* __restrict__ o) {
    int l = blockIdx.x, t = threadIdx.x;
    o[l * 256 + t] = (t < 128) ? bl[l * 128 + t] : br[l * 128 + (t - 128)];
}

// ---------------- LDS layout: [64][128] shorts, XOR-swizzled 16B chunks ----
template <int NTW>
__device__ inline void stage_mfma(
    const short* __restrict__ Wh, const short* __restrict__ Wl,
    int Kstride, int kb,
    const short (*Ash)[128], const short (*Asl)[128],
    int w, int llo, int lhi, f32x4 (&acc)[4][NTW])
{
#pragma unroll
    for (int ks = 0; ks < 4; ++ks) {
        bf16x8 wf_h[NTW], wf_l[NTW];
#pragma unroll
        for (int nt = 0; nt < NTW; ++nt) {
            int n = (w * NTW + nt) * 16 + llo;
            size_t off = (size_t)n * Kstride + kb + ks * 32 + lhi * 8;
            wf_h[nt] = *(const bf16x8*)(Wh + off);
            wf_l[nt] = *(const bf16x8*)(Wl + off);
        }
        bf16x8 ba_h[4], ba_l[4];
#pragma unroll
        for (int mt = 0; mt < 4; ++mt) {
            int m = mt * 16 + llo;
            int c = ((4 * ks + lhi) ^ llo) << 3;
            ba_h[mt] = *(const bf16x8*)&Ash[m][c];
            ba_l[mt] = *(const bf16x8*)&Asl[m][c];
        }
#pragma unroll
        for (int mt = 0; mt < 4; ++mt)
#pragma unroll
            for (int nt = 0; nt < NTW; ++nt) {
                acc[mt][nt] = __builtin_amdgcn_mfma_f32_16x16x32_bf16(
                    wf_h[nt], ba_h[mt], acc[mt][nt], 0, 0, 0);
                acc[mt][nt] = __builtin_amdgcn_mfma_f32_16x16x32_bf16(
                    wf_h[nt], ba_l[mt], acc[mt][nt], 0, 0, 0);
                acc[mt][nt] = __builtin_amdgcn_mfma_f32_16x16x32_bf16(
                    wf_l[nt], ba_h[mt], acc[mt][nt], 0, 0, 0);
            }
    }
}

// act = relu(acc + bias) -> split-bf16 back into LDS A planes (swizzled)
__device__ inline void act_to_lds(
    f32x4 (&acc)[4][2], const float* __restrict__ bias,
    short (*Ash)[128], short (*Asl)[128], int w, int llo, int lhi)
{
#pragma unroll
    for (int mt = 0; mt < 4; ++mt) {
        int r = mt * 16 + llo;
#pragma unroll
        for (int nt = 0; nt < 2; ++nt) {
            int c0 = (w * 2 + nt) * 16 + lhi * 4;
            int chunk = c0 >> 3;
            int off = ((chunk ^ llo) << 3) + (c0 & 7);
            short4 h4, l4;
            short* hp = (short*)&h4; short* lp = (short*)&l4;
#pragma unroll
            for (int u = 0; u < 4; ++u) {
                float z = acc[mt][nt][u] + bias[c0 + u];
                z = z > 0.f ? z : 0.f;
                unsigned short hb = f2bf(z);
                hp[u] = (short)hb;
                lp[u] = (short)f2bf(z - bf2f(hb));
            }
            *(short4*)&Ash[r][off] = h4;
            *(short4*)&Asl[r][off] = l4;
        }
    }
}

// per-thread register chunk for gather staging (regs -> LDS, max outstanding loads)
struct AChunk { bf16x8 h[4], l[4]; };

template <bool DUAL>
__device__ inline void gather_chunk(
    AChunk& c,
    const short* __restrict__ A0h, const short* __restrict__ A0l, int ld0, int K0,
    const short* __restrict__ A1h, const short* __restrict__ A1l, int ld1,
    const int* __restrict__ idx0, const int* __restrict__ idx1,
    int kb, int row0, int M, int t)
{
#pragma unroll
    for (int j = 0; j < 4; ++j) {
        int u = j * 256 + t;
        int lr = u >> 4, q = u & 15;
        int gr = row0 + lr; if (gr >= M) gr = M - 1;
        int kk = kb + q * 8;
        const short *bh, *bl; int ld, lk; const int* idx;
        if (!DUAL || kk < K0) { bh = A0h; bl = A0l; ld = ld0; lk = kk; idx = idx0; }
        else                  { bh = A1h; bl = A1l; ld = ld1; lk = kk - K0; idx = idx1; }
        int sr = idx ? idx[gr] : gr;
        size_t off = (size_t)sr * ld + lk;
        c.h[j] = *(const bf16x8*)(bh + off);
        c.l[j] = *(const bf16x8*)(bl + off);
    }
}

__device__ inline void write_chunk(const AChunk& c,
                                   short (*Ash)[128], short (*Asl)[128], int t)
{
#pragma unroll
    for (int j = 0; j < 4; ++j) {
        int u = j * 256 + t;
        int lr = u >> 4, q = u & 15;
        int off = ((q ^ (lr & 15)) << 3);
        *(bf16x8*)&Ash[lr][off] = c.h[j];
        *(bf16x8*)&Asl[lr][off] = c.l[j];
    }
}

// ---------------- fused MLP chain (2 or 3 MFMA stages in one dispatch) -----
// h activations live interleaved: row stride 256 shorts, hi at +0, lo at +128.
// FINAL: 0 = write interleaved split rows (stride 256), 1 = FDOT sigmoid, 2 = fp32 NOUT.
template <int K1, int NSTAGE, int NOUT, int FINAL, bool INS>
__global__ __launch_bounds__(256, 2) void mlp_k(
    const void* __restrict__ A0h, const void* __restrict__ A0l, int ld0, int K0,
    const void* __restrict__ A1h, const void* __restrict__ A1l, int ld1,
    const int* __restrict__ idx0, const int* __restrict__ idx1,
    const short* __restrict__ W1h, const short* __restrict__ W1l, const float* __restrict__ b1,
    const short* __restrict__ W2h, const short* __restrict__ W2l, const float* __restrict__ b2,
    const short* __restrict__ W3h, const short* __restrict__ W3l, const float* __restrict__ b3,
    short* __restrict__ Ch, short* __restrict__ Cl, float* __restrict__ Cf,
    const float* __restrict__ Wd, const float* __restrict__ bd, float* __restrict__ outd,
    int M)
{
    __shared__ __align__(16) short As_h[64][128];
    __shared__ __align__(16) short As_l[64][128];
    __shared__ float redf[4][64];

    const int t = threadIdx.x;
    const int w = t >> 6, lane = t & 63;
    const int llo = lane & 15, lhi = lane >> 4;
    const int row0 = blockIdx.x * 64;

    // ---- stage 1 ----
    f32x4 acc1[4][2];
#pragma unroll
    for (int mt = 0; mt < 4; ++mt)
#pragma unroll
        for (int nt = 0; nt < 2; ++nt) { f32x4 z = {0,0,0,0}; acc1[mt][nt] = z; }

    if (INS) {
        AChunk c;
        gather_chunk<(K1 == 256)>(c, (const short*)A0h, (const short*)A0l, ld0, K0,
                                  (const short*)A1h, (const short*)A1l, ld1,
                                  idx0, idx1, 0, row0, M, t);
        write_chunk(c, As_h, As_l, t);
        __syncthreads();
        stage_mfma<2>(W1h, W1l, K1, 0, As_h, As_l, w, llo, lhi, acc1);
        if (K1 == 256) {
            __syncthreads();    // WAR guard
            gather_chunk<true>(c, (const short*)A0h, (const short*)A0l, ld0, K0,
                               (const short*)A1h, (const short*)A1l, ld1,
                               idx0, idx1, 128, row0, M, t);
            write_chunk(c, As_h, As_l, t);
            __syncthreads();
            stage_mfma<2>(W1h, W1l, K1, 128, As_h, As_l, w, llo, lhi, acc1);
        }
    } else {
        // fp32 A (encoder layer 0): convert during staging, K1=128
#pragma unroll
        for (int j = 0; j < 8; ++j) {
            int u = j * 256 + t;
            int lr = u >> 5;
            int q  = u & 31;
            int gr = row0 + lr; if (gr >= M) gr = M - 1;
            int kk = q * 4;
            const float* src; int ld, lk; const int* idx;
            if (kk < K0) { src = (const float*)A0h; ld = ld0; lk = kk; idx = idx0; }
            else         { src = (const float*)A1h; ld = ld1; lk = kk - K0; idx = idx1; }
            int sr = idx ? idx[gr] : gr;
            float4 v = *(const float4*)(src + (size_t)sr * ld + lk);
            float xs[4] = {v.x, v.y, v.z, v.w};
            short4 h4, l4;
            short* hp = (short*)&h4; short* lp = (short*)&l4;
#pragma unroll
            for (int i = 0; i < 4; ++i) {
                unsigned short hb = f2bf(xs[i]);
                hp[i] = (short)hb;
                lp[i] = (short)f2bf(xs[i] - bf2f(hb));
            }
            int off = (((q >> 1) ^ (lr & 15)) << 3) + (q & 1) * 4;
            *(short4*)&As_h[lr][off] = h4;
            *(short4*)&As_l[lr][off] = l4;
        }
        __syncthreads();
        stage_mfma<2>(W1h, W1l, K1, 0, As_h, As_l, w, llo, lhi, acc1);
    }
    __syncthreads();                 // all stage-1 LDS reads done
    act_to_lds(acc1, b1, As_h, As_l, w, llo, lhi);
    __syncthreads();

    // ---- stage 2 ----
    f32x4 acc2[4][2];
#pragma unroll
    for (int mt = 0; mt < 4; ++mt)
#pragma unroll
        for (int nt = 0; nt < 2; ++nt) { f32x4 z = {0,0,0,0}; acc2[mt][nt] = z; }
    stage_mfma<2>(W2h, W2l, 128, 0, As_h, As_l, w, llo, lhi, acc2);

    if (NSTAGE == 2) {
        // FDOT epilogue: out[r] = sigmoid(relu(acc2+b2) . Wd + bd)
        const float bdd = bd[0];
        float pd[4] = {0.f, 0.f, 0.f, 0.f};
#pragma unroll
        for (int mt = 0; mt < 4; ++mt)
#pragma unroll
            for (int nt = 0; nt < 2; ++nt) {
                int c0 = (w * 2 + nt) * 16 + lhi * 4;
#pragma unroll
                for (int u = 0; u < 4; ++u) {
                    float z = acc2[mt][nt][u] + b2[c0 + u];
                    z = z > 0.f ? z : 0.f;
                    pd[mt] = fmaf(z, Wd[c0 + u], pd[mt]);
                }
            }
#pragma unroll
        for (int mt = 0; mt < 4; ++mt) {
            pd[mt] += __shfl_xor(pd[mt], 16, 64);
            pd[mt] += __shfl_xor(pd[mt], 32, 64);
        }
        if (lhi == 0) {
#pragma unroll
            for (int mt = 0; mt < 4; ++mt) redf[w][mt * 16 + llo] = pd[mt];
        }
        __syncthreads();
        if (w == 0 && lhi == 0) {
#pragma unroll
            for (int mt = 0; mt < 4; ++mt) {
                int r = row0 + mt * 16 + llo;
                if (r < M) {
                    float d = redf[0][mt * 16 + llo] + redf[1][mt * 16 + llo]
                            + redf[2][mt * 16 + llo] + redf[3][mt * 16 + llo] + bdd;
                    outd[r] = 1.f / (1.f + __expf(-d));
                }
            }
        }
    } else {
        __syncthreads();
        act_to_lds(acc2, b2, As_h, As_l, w, llo, lhi);
        __syncthreads();
        // ---- stage 3 ----
        constexpr int NTWF = NOUT / 64;
        f32x4 acc3[4][NTWF];
#pragma unroll
        for (int mt = 0; mt < 4; ++mt)
#pragma unroll
            for (int nt = 0; nt < NTWF; ++nt) { f32x4 z = {0,0,0,0}; acc3[mt][nt] = z; }
        stage_mfma<NTWF>(W3h, W3l, 128, 0, As_h, As_l, w, llo, lhi, acc3);
#pragma unroll
        for (int mt = 0; mt < 4; ++mt) {
            int r = row0 + mt * 16 + llo;
            if (r < M) {
#pragma unroll
                for (int nt = 0; nt < NTWF; ++nt) {
                    int c0 = (w * NTWF + nt) * 16 + lhi * 4;
                    float v[4];
#pragma unroll
                    for (int u = 0; u < 4; ++u) v[u] = acc3[mt][nt][u] + b3[c0 + u];
                    if (FINAL == 0) {
                        short4 h4, l4;
                        short* hp = (short*)&h4; short* lp = (short*)&l4;
#pragma unroll
                        for (int u = 0; u < 4; ++u) {
                            unsigned short hb = f2bf(v[u]);
                            hp[u] = (short)hb;
                            lp[u] = (short)f2bf(v[u] - bf2f(hb));
                        }
                        *(short4*)(Ch + (size_t)r * 256 + c0) = h4;   // interleaved rows
                        *(short4*)(Cl + (size_t)r * 256 + c0) = l4;   // Cl = Ch + 128
                    } else {
                        float4 o = {v[0], v[1], v[2], v[3]};
                        *(float4*)(Cf + (size_t)r * NOUT + c0) = o;
                    }
                }
            }
        }
    }
}

// ---------------- N=256 GEMM for fused xl||xr -> bf16 rows [NN][256] -------
__global__ __launch_bounds__(256, 2) void gemmlr_k(
    const short* __restrict__ h,     // interleaved split rows, stride 256
    const short* __restrict__ Wh, const short* __restrict__ Wl,
    const float* __restrict__ bias, short* __restrict__ C, int M)
{
    __shared__ __align__(16) short As_h[64][128];
    __shared__ __align__(16) short As_l[64][128];
    const int t = threadIdx.x;
    const int w = t >> 6, lane = t & 63;
    const int llo = lane & 15, lhi = lane >> 4;
    const int row0 = blockIdx.x * 64;

    f32x4 acc[4][4];
#pragma unroll
    for (int mt = 0; mt < 4; ++mt)
#pragma unroll
        for (int nt = 0; nt < 4; ++nt) { f32x4 z = {0,0,0,0}; acc[mt][nt] = z; }

#pragma unroll
    for (int j = 0; j < 4; ++j) {
        int u = j * 256 + t;
        int lr = u >> 4;
        int q  = u & 15;
        int gr = row0 + lr; if (gr >= M) gr = M - 1;
        size_t off = (size_t)gr * 256 + q * 8;
        int loff = ((q ^ (lr & 15)) << 3);
        *(bf16x8*)&As_h[lr][loff] = *(const bf16x8*)(h + off);
        *(bf16x8*)&As_l[lr][loff] = *(const bf16x8*)(h + off + 128);
    }
    __syncthreads();
    stage_mfma<4>(Wh, Wl, 128, 0, As_h, As_l, w, llo, lhi, acc);

#pragma unroll
    for (int mt = 0; mt < 4; ++mt) {
        int r = row0 + mt * 16 + llo;
        if (r < M) {
#pragma unroll
            for (int nt = 0; nt < 4; ++nt) {
                int c0 = (w * 4 + nt) * 16 + lhi * 4;
                short4 o;
                short* op = (short*)&o;
#pragma unroll
                for (int u = 0; u < 4; ++u)
                    op[u] = (short)f2bf(acc[mt][nt][u] + bias[c0 + u]);
                *(short4*)(C + (size_t)r * 256 + c0) = o;
            }
        }
    }
}

// ---------------- GATv2: half-wave per edge, bf16 rows, DPP logit reduce ---
#define GPH 4
#define NEGI -1e30f
#define DPPADD(v, ctrl) \
    v += __int_as_float(__builtin_amdgcn_update_dpp(0, __float_as_int(v), ctrl, 0xf, 0xf, true))

__device__ inline float red32_bcast(float v) {
    DPPADD(v, 0x111);   // row_shr:1
    DPPADD(v, 0x112);   // row_shr:2
    DPPADD(v, 0x114);   // row_shr:4
    DPPADD(v, 0x118);   // row_shr:8
    DPPADD(v, 0x142);   // row_bcast15 -> lane31 holds 32-sum
    return __int_as_float(__builtin_amdgcn_ds_swizzle(__float_as_int(v), 0x03E0));
}

__global__ __launch_bounds__(256) void gat2_k(
    const short* __restrict__ xlr,   // bf16 rows [NN][256]: xl | xr
    const float* __restrict__ att,
    const int* __restrict__ offs, const int* __restrict__ csrs,
    const float* __restrict__ bias,
    short* __restrict__ hout)        // interleaved split rows, stride 256
{
    const int wid = (blockIdx.x * 256 + threadIdx.x) >> 6;
    const int lane = threadIdx.x & 63;
    const int h = lane >> 5, sub = lane & 31;
    if (wid >= NN) return;
    const int n = wid;
    const int beg = offs[n];
    const int total = (offs[n + 1] - beg) + 1;

    const float4 attv = *(const float4*)(att + sub * 4);
    const float4 xrv  = ld_bf4(xlr + (size_t)n * 256 + 128 + sub * 4);

    float m = NEGI, s = 0.f;
    float4 acc = {0.f, 0.f, 0.f, 0.f};

    int cs[GPH];
#pragma unroll
    for (int p = 0; p < GPH; ++p) {
        int slot = p * 2 + h;
        cs[p] = (slot < total) ? ((slot == 0) ? n : csrs[beg + slot - 1]) : n;
    }

    for (int base = 0; base < total; base += 2 * GPH) {
        float4 r[GPH];
#pragma unroll
        for (int p = 0; p < GPH; ++p)
            r[p] = ld_bf4(xlr + (size_t)cs[p] * 256 + sub * 4);
        int ns[GPH];
#pragma unroll
        for (int p = 0; p < GPH; ++p) {
            int nslot = base + 2 * GPH + p * 2 + h;
            ns[p] = (nslot < total) ? csrs[beg + nslot - 1] : n;
        }
        float e[GPH];
#pragma unroll
        for (int p = 0; p < GPH; ++p) {
            float v = 0.f;
#pragma unroll
            for (int j = 0; j < 4; ++j) {
                float mj = ((const float*)&r[p])[j] + ((const float*)&xrv)[j];
                mj = mj > 0.f ? mj : 0.2f * mj;
                v = fmaf(mj, ((const float*)&attv)[j], v);
            }
            v = red32_bcast(v);
            e[p] = (base + p * 2 + h < total) ? v : NEGI;
        }
        float tm = fmaxf(fmaxf(e[0], e[1]), fmaxf(e[2], e[3]));
        float mnew = fmaxf(m, tm);
        float sc = __expf(m - mnew);
        s *= sc; acc.x *= sc; acc.y *= sc; acc.z *= sc; acc.w *= sc;
#pragma unroll
        for (int p = 0; p < GPH; ++p) {
            float wj = __expf(e[p] - mnew);
            s += wj;
            acc.x = fmaf(wj, r[p].x, acc.x);
            acc.y = fmaf(wj, r[p].y, acc.y);
            acc.z = fmaf(wj, r[p].z, acc.z);
            acc.w = fmaf(wj, r[p].w, acc.w);
        }
        m = mnew;
#pragma unroll
        for (int p = 0; p < GPH; ++p) cs[p] = ns[p];
    }
    // merge halves
    float om = __shfl_xor(m, 32, 64);
    float os = __shfl_xor(s, 32, 64);
    float4 oacc;
    oacc.x = __shfl_xor(acc.x, 32, 64);
    oacc.y = __shfl_xor(acc.y, 32, 64);
    oacc.z = __shfl_xor(acc.z, 32, 64);
    oacc.w = __shfl_xor(acc.w, 32, 64);
    float M = fmaxf(m, om);
    float a = __expf(m - M), b = __expf(om - M);
    float st = s * a + os * b;
    float inv = 1.f / st;
    if (h == 0) {
        float ov[4];
        ov[0] = (acc.x * a + oacc.x * b) * inv + bias[sub * 4 + 0];
        ov[1] = (acc.y * a + oacc.y * b) * inv + bias[sub * 4 + 1];
        ov[2] = (acc.z * a + oacc.z * b) * inv + bias[sub * 4 + 2];
        ov[3] = (acc.w * a + oacc.w * b) * inv + bias[sub * 4 + 3];
        short4 h4, l4;
        short* hp = (short*)&h4; short* lp = (short*)&l4;
#pragma unroll
        for (int u = 0; u < 4; ++u) {
            unsigned short hb = f2bf(ov[u]);
            hp[u] = (short)hb;
            lp[u] = (short)f2bf(ov[u] - bf2f(hb));
        }
        *(short4*)(hout + (size_t)n * 256 + sub * 4) = h4;
        *(short4*)(hout + (size_t)n * 256 + 128 + sub * 4) = l4;
    }
}

extern "C" void kernel_launch(void* const* d_in, const int* in_sizes, int n_in,
                              void* d_out, int out_size, void* d_ws, size_t ws_size,
                              hipStream_t stream)
{
    const float* x    = (const float*)d_in[0];
    const float* emb  = (const float*)d_in[1];
    const int*   ei   = (const int*)d_in[2];
    const int*   bidx = (const int*)d_in[3];
    const int*   eim  = (const int*)d_in[4];
    const float* encW = (const float*)d_in[5];
    const float* encB = (const float*)d_in[6];
    const float* gWl  = (const float*)d_in[7];
    const float* gbl  = (const float*)d_in[8];
    const float* gWr  = (const float*)d_in[9];
    const float* gbr  = (const float*)d_in[10];
    const float* gatt = (const float*)d_in[11];
    const float* gb   = (const float*)d_in[12];
    const float* eW0  = (const float*)d_in[13];
    const float* eb0  = (const float*)d_in[14];
    const float* eW1  = (const float*)d_in[15];
    const float* eb1  = (const float*)d_in[16];
    const float* eW2  = (const float*)d_in[17];
    const float* eb2  = (const float*)d_in[18];
    const float* nW0  = (const float*)d_in[19];
    const float* nb0  = (const float*)d_in[20];
    const float* nW1  = (const float*)d_in[21];
    const float* nb1  = (const float*)d_in[22];
    const float* nW2  = (const float*)d_in[23];
    const float* nb2  = (const float*)d_in[24];
    float* out = (float*)d_out;

    char* wptr = (char*)d_ws;
    auto alloc = [&](size_t bytes) {
        char* p = wptr;
        wptr += (bytes + 255) & ~(size_t)255;
        return p;
    };
    short* h    = (short*)alloc((size_t)NN * 256 * 2);   // interleaved hi|lo rows
    short* xlrb = (short*)alloc((size_t)NN * 256 * 2);   // bf16 xl|xr rows
    int* counts = (int*)alloc((size_t)NN * 4);
    int* offs   = (int*)alloc((size_t)(NN + 1) * 4);
    int* csrs   = (int*)alloc((size_t)NE * 4);
    int* bsum   = (int*)alloc(256 * 4);
    int* bscan  = (int*)alloc(256 * 4);
    auto wplane = [&](int elems, short*& ph, short*& pl) {
        ph = (short*)alloc((size_t)elems * 2);
        pl = (short*)alloc((size_t)elems * 2);
    };
    short *encWt_h[3], *encWt_l[3];
    for (int i = 0; i < 3; ++i) wplane(HID * HID, encWt_h[i], encWt_l[i]);
    short *glrt_h[3], *glrt_l[3];
    for (int i = 0; i < 3; ++i) wplane(256 * HID, glrt_h[i], glrt_l[i]);
    short *eW0t_h, *eW0t_l, *eW1t_h, *eW1t_l;
    wplane(2 * HID * HID, eW0t_h, eW0t_l);
    wplane(HID * HID, eW1t_h, eW1t_l);
    short *nW0t_h, *nW0t_l, *nW1t_h, *nW1t_l, *nW2t_h, *nW2t_l;
    wplane(HID * HID, nW0t_h, nW0t_l);
    wplane(HID * HID, nW1t_h, nW1t_l);
    wplane(HID * 64, nW2t_h, nW2t_l);
    float* gblr = (float*)alloc(3 * 256 * 4);

    // ---- W pre-conversion ----
    WDescs ds;
    int di = 0;
    for (int i = 0; i < 3; ++i)
        ds.d[di++] = {encW + (size_t)i * HID * HID, encWt_h[i], encWt_l[i], HID, HID};
    for (int i = 0; i < 3; ++i) {
        ds.d[di++] = {gWl + (size_t)i * HID * HID, glrt_h[i], glrt_l[i], HID, HID};
        ds.d[di++] = {gWr + (size_t)i * HID * HID, glrt_h[i] + HID * HID,
                      glrt_l[i] + HID * HID, HID, HID};
    }
    ds.d[di++] = {eW0, eW0t_h, eW0t_l, 2 * HID, HID};
    ds.d[di++] = {eW1, eW1t_h, eW1t_l, HID, HID};
    ds.d[di++] = {nW0, nW0t_h, nW0t_l, HID, HID};
    ds.d[di++] = {nW1, nW1t_h, nW1t_l, HID, HID};
    ds.d[di++] = {nW2, nW2t_h, nW2t_l, HID, 64};
    wconv_k<<<14 * 128, 256, 0, stream>>>(ds);
    biascat_k<<<3, 256, 0, stream>>>(gbl, gbr, gblr);

    // ---- CSR build ----
    zero_k<<<(NN + 255) / 256, 256, 0, stream>>>(counts, NN);
    count_k<<<(NE + 255) / 256, 256, 0, stream>>>(ei, counts);
    scan1_k<<<NB_SCAN, 256, 0, stream>>>(counts, offs, bsum);
    scan2_k<<<1, 256, 0, stream>>>(bsum, bscan, offs);
    scan3_k<<<NB_SCAN, 256, 0, stream>>>(offs, bscan);
    scatter_k<<<(NE + 255) / 256, 256, 0, stream>>>(ei, offs, counts, csrs);

    const int gN = (NN + 63) / 64;
    // ---- encoder MLP: one fused dispatch (3 stages) -> interleaved h ----
    mlp_k<128, 3, 128, 0, false><<<gN, 256, 0, stream>>>(
        x, nullptr, 64, 64, emb, nullptr, 64, nullptr, nullptr,
        encWt_h[0], encWt_l[0], encB,
        encWt_h[1], encWt_l[1], encB + 128,
        encWt_h[2], encWt_l[2], encB + 256,
        h, h + 128, nullptr, nullptr, nullptr, nullptr, NN);

    // ---- 3 GATv2 layers ----
    const int gGAT = (NN * 64 + 255) / 256;
    for (int l = 0; l < 3; ++l) {
        gemmlr_k<<<gN, 256, 0, stream>>>(h, glrt_h[l], glrt_l[l],
                                         gblr + (size_t)l * 256, xlrb, NN);
        gat2_k<<<gGAT, 256, 0, stream>>>(xlrb, gatt + (size_t)l * HID,
                                         offs, csrs, gb + (size_t)l * HID, h);
    }

    // ---- edge decoder: single fused dispatch over all 200000 rows ----
    mlp_k<256, 2, 128, 1, true><<<(NIMAG + 63) / 64, 256, 0, stream>>>(
        h, h + 128, 256, 128, h, h + 128, 256, eim, eim + NIMAG,
        eW0t_h, eW0t_l, eb0,
        eW1t_h, eW1t_l, eb1,
        nullptr, nullptr, nullptr,
        nullptr, nullptr, nullptr,
        eW2, eb2, out + (size_t)NBLOCK * 64, NIMAG);

    // ---- node decoder: one fused dispatch (3 stages) ----
    mlp_k<128, 3, 64, 2, true><<<(NBLOCK + 63) / 64, 256, 0, stream>>>(
        h, h + 128, 256, 128, nullptr, nullptr, 0, bidx, nullptr,
        nW0t_h, nW0t_l, nb0,
        nW1t_h, nW1t_l, nb1,
        nW2t_h, nW2t_l, nb2,
        nullptr, nullptr, out, nullptr, nullptr, nullptr, NBLOCK);
}